// Round 5
// baseline (747.406 us; speedup 1.0000x reference)
//
#include <hip/hip_runtime.h>
#include <cstddef>

// ---------------------------------------------------------------------------
// SpiralAutoencoder on MI355X — round 15:
//  * Round-14 post-mortem: c3 conv_wmfma FETCH=77MB vs ~21MB ideal — linear
//    dispatch sprays same-batch blocks across all 8 XCDs, each XCD's L2
//    re-fetches every batch slice. Add chunked XCD swizzle to conv_wmfma
//    (c3/c4 only): XCD k owns 8 contiguous batches (2.6MB, L2-resident).
//    Bijective remap over disjoint stores -> bitwise-identical output.
// ---------------------------------------------------------------------------

#define BATCH 64
#define SPK 12  // spiral length

typedef __attribute__((ext_vector_type(8))) short bf16x8;
typedef __attribute__((ext_vector_type(4))) short bf16x4;
typedef __attribute__((ext_vector_type(4))) float f32x4;

__device__ __forceinline__ unsigned short f2bf(float x) {
    union { float f; unsigned int u; } v; v.f = x;
    unsigned int r = v.u + 0x7FFF + ((v.u >> 16) & 1);  // RNE
    return (unsigned short)(r >> 16);
}

// ---------------------------------------------------------------------------
// Flat fp32 -> bf16 convert (8 elems/thread).
// ---------------------------------------------------------------------------
__global__ __launch_bounds__(256) void f32_to_bf16_kernel(
    const float* __restrict__ in, unsigned short* __restrict__ out, int n8)
{
    int i = blockIdx.x * 256 + threadIdx.x;
    if (i < n8) {
        const float* p = in + (size_t)i * 8;
        bf16x8 r;
#pragma unroll
        for (int j = 0; j < 8; ++j) r[j] = (short)f2bf(p[j]);
        *(bf16x8*)(out + (size_t)i * 8) = r;
    }
}

// ---------------------------------------------------------------------------
// fp32 [M][K] -> bf16 [Mp][Kp] with zero padding (rows >= M, cols >= K).
// ---------------------------------------------------------------------------
__global__ __launch_bounds__(256) void a_bf16_pad_kernel(
    const float* __restrict__ A, unsigned short* __restrict__ Ap,
    int M, int K, int Kp, int total)
{
    int i = blockIdx.x * 256 + threadIdx.x;
    if (i >= total) return;
    int kp8 = Kp >> 3;
    int m = i / kp8;
    int k0 = (i - m * kp8) * 8;
    bf16x8 r;
    if (m < M) {
        const float* src = A + (size_t)m * K + k0;
#pragma unroll
        for (int j = 0; j < 8; ++j) {
            float v = (k0 + j < K) ? src[j] : 0.f;
            r[j] = (short)f2bf(v);
        }
    } else {
#pragma unroll
        for (int j = 0; j < 8; ++j) r[j] = 0;
    }
    *(bf16x8*)(Ap + (size_t)m * Kp + k0) = r;
}

// ---------------------------------------------------------------------------
// conv_wmfma: one wave computes a 16-row x 16-out tile, K fully in-register.
// A-frag: direct bf16x8 gather (lane l15 = row, quad*8 = k-offset). B-frag:
// bf16 W row load. Grid: (ceil(Nv/16), O/16, BATCH), block = 64.
// swz: chunked XCD swizzle (large-Nv launches; total blocks % 8 == 0) —
// each XCD owns a contiguous batch range so its slice stays L2-resident.
// e2/e3/c0/c1/c3/c4.
// ---------------------------------------------------------------------------
template<int LOGF, int OBF16>
__global__ __launch_bounds__(64) void conv_wmfma_kernel(
    const unsigned short* __restrict__ x, const int* __restrict__ S,
    const unsigned short* __restrict__ Wb, const float* __restrict__ bias,
    void* __restrict__ yv, int Nv, int O, int elu_flag, int swz)
{
    constexpr int F  = 1 << LOGF;
    constexpr int KF = SPK * F;
    constexpr int NS = KF / 32;
    const int lane = threadIdx.x;
    const int l15  = lane & 15;
    const int quad = lane >> 4;

    int bx = blockIdx.x, by = blockIdx.y, bz = blockIdx.z;
    if (swz) {
        const int gx = gridDim.x, gy = gridDim.y;
        const int total = gx * gy * gridDim.z;
        int bid = bx + gx * (by + gy * bz);
        const int chunk = total >> 3;
        int sid = (bid & 7) * chunk + (bid >> 3);
        bx = sid % gx; sid /= gx;
        by = sid % gy;
        bz = sid / gy;
    }

    const int n0   = bx * 16;
    const int o    = by * 16 + l15;
    const int b    = bz;
    const size_t xb = (size_t)b * Nv;

    const int n  = n0 + l15;
    const int ng = (n < Nv) ? n : 0;
    const unsigned short* wrow = Wb + (size_t)o * KF;

    f32x4 acc0 = (f32x4){0.f, 0.f, 0.f, 0.f};
    f32x4 acc1 = (f32x4){0.f, 0.f, 0.f, 0.f};
#pragma unroll
    for (int s = 0; s < NS; ++s) {
        int kf  = s * 32 + quad * 8;
        int k   = kf >> LOGF;
        int f   = kf & (F - 1);
        int src = S[ng * SPK + k];
        bf16x8 a = *(const bf16x8*)(x + ((xb + src) << LOGF) + f);
        bf16x8 w = *(const bf16x8*)(wrow + kf);
        if (s & 1) acc1 = __builtin_amdgcn_mfma_f32_16x16x32_bf16(a, w, acc1, 0, 0, 0);
        else       acc0 = __builtin_amdgcn_mfma_f32_16x16x32_bf16(a, w, acc0, 0, 0, 0);
    }
    float bv = bias[o];
#pragma unroll
    for (int reg = 0; reg < 4; ++reg) {
        int nn = n0 + quad * 4 + reg;
        if (nn >= Nv) continue;
        float v = acc0[reg] + acc1[reg] + bv;
        if (elu_flag && v <= 0.f) v = expm1f(v);
        if (nn == Nv - 1) v = 0.f;
        size_t off = ((size_t)b * Nv + nn) * O + o;
        if (OBF16) ((unsigned short*)yv)[off] = f2bf(v);
        else       ((float*)yv)[off] = v;
    }
}

// ---------------------------------------------------------------------------
// conv_mfma32: O=32 spiral conv via MFMA. W pre-converted bf16. e1/c2.
// ---------------------------------------------------------------------------
template<int LOGF>
__global__ __launch_bounds__(256) void conv_mfma32_kernel(
    const unsigned short* __restrict__ x, const int* __restrict__ S,
    const unsigned short* __restrict__ Wb, const float* __restrict__ bias,
    float* __restrict__ y, int Nv, int KF, int elu_flag)
{
    constexpr int PAD = 40;
    __shared__ unsigned short Gs[2][256 * PAD];

    const int b    = blockIdx.x;
    const int n0   = blockIdx.y * 256;
    const int tid  = threadIdx.x;
    const int lane = tid & 63;
    const int wave = tid >> 6;
    const int wm   = wave * 64;
    const int l15  = lane & 15;
    const int quad = lane >> 4;
    const size_t xb = (size_t)b * Nv;
    const int nslab = KF >> 5;

    f32x4 acc[4][2];
#pragma unroll
    for (int t = 0; t < 4; ++t)
#pragma unroll
        for (int o = 0; o < 2; ++o) acc[t][o] = (f32x4){0.f, 0.f, 0.f, 0.f};

    auto gath = [&](int k0, bf16x8* g) {
        int n = n0 + tid;
        if (n < Nv) {
#pragma unroll
            for (int j = 0; j < 4; ++j) {
                int kf  = k0 + j * 8;
                int k   = kf >> LOGF;
                int f   = kf & ((1 << LOGF) - 1);
                int src = S[n * SPK + k];
                g[j] = *(const bf16x8*)(x + ((xb + src) << LOGF) + f);
            }
        } else {
#pragma unroll
            for (int j = 0; j < 4; ++j)
#pragma unroll
                for (int e = 0; e < 8; ++e) g[j][e] = 0;
        }
    };
    auto put = [&](int buf, const bf16x8* g) {
#pragma unroll
        for (int j = 0; j < 4; ++j)
            *(bf16x8*)&Gs[buf][tid * PAD + j * 8] = g[j];
    };
    auto wfrag = [&](int k0, int o16) {
        return *(const bf16x8*)(Wb + (size_t)(o16 * 16 + l15) * KF + k0 + quad * 8);
    };

    bf16x8 gcur[4], gnext[4];
    gath(0, gcur);
    put(0, gcur);
    __syncthreads();

    for (int s = 0; s < nslab; ++s) {
        const int cur = s & 1;
        const bool more = (s + 1) < nslab;
        if (more) gath((s + 1) * 32, gnext);
        bf16x8 wf0 = wfrag(s * 32, 0);
        bf16x8 wf1 = wfrag(s * 32, 1);
#pragma unroll
        for (int t = 0; t < 4; ++t) {
            bf16x8 a = *(const bf16x8*)&Gs[cur][(wm + t * 16 + l15) * PAD + quad * 8];
            acc[t][0] = __builtin_amdgcn_mfma_f32_16x16x32_bf16(a, wf0, acc[t][0], 0, 0, 0);
            acc[t][1] = __builtin_amdgcn_mfma_f32_16x16x32_bf16(a, wf1, acc[t][1], 0, 0, 0);
        }
        if (more) {
            put(cur ^ 1, gnext);
            __syncthreads();
        }
    }

    float bv0 = bias[l15];
    float bv1 = bias[16 + l15];
#pragma unroll
    for (int t = 0; t < 4; ++t)
#pragma unroll
        for (int reg = 0; reg < 4; ++reg) {
            int n = n0 + wm + t * 16 + quad * 4 + reg;
            if (n >= Nv) continue;
            float v0 = acc[t][0][reg] + bv0;
            float v1 = acc[t][1][reg] + bv1;
            if (elu_flag) {
                if (v0 <= 0.f) v0 = expm1f(v0);
                if (v1 <= 0.f) v1 = expm1f(v1);
            }
            if (n == Nv - 1) { v0 = 0.f; v1 = 0.f; }
            size_t off = ((size_t)b * Nv + n) * 32 + l15;
            y[off]      = v0;
            y[off + 16] = v1;
        }
}

// ---------------------------------------------------------------------------
// dsamp_mfma3: 128x128 tile MFMA resample, both operands bf16 pre-padded.
// swz: chunked XCD swizzle (z-split launches only). D0/U0.
// ---------------------------------------------------------------------------
__global__ __launch_bounds__(256) void dsamp_mfma3_kernel(
    const unsigned short* __restrict__ Ab, const unsigned short* __restrict__ Xt,
    float* __restrict__ Y, int M, int Kp, int logF, int kchunk,
    int atomic_flag, int swz)
{
    constexpr int PAD = 40;
    __shared__ unsigned short As[2][128 * PAD];
    __shared__ unsigned short Bs[2][128 * PAD];

    int bx = blockIdx.x, by = blockIdx.y, bz = blockIdx.z;
    if (swz) {
        const int gx = gridDim.x, gy = gridDim.y;
        const int total = gx * gy * gridDim.z;
        int bid = bx + gx * (by + gy * bz);
        const int chunk = total >> 3;
        int sid = (bid & 7) * chunk + (bid >> 3);
        bx = sid % gx; sid /= gx;
        by = sid % gy;
        bz = sid / gy;
    }

    const int fmask = (1 << logF) - 1;
    const int m0   = bx * 128;
    const int c0   = by * 128;
    const int kbeg = bz * kchunk;
    int kend = kbeg + kchunk; if (kend > Kp) kend = Kp;
    const int nslab = (kend - kbeg + 31) >> 5;

    const int tid  = threadIdx.x;
    const int lane = tid & 63;
    const int wave = tid >> 6;
    const int wm   = (wave >> 1) * 64;
    const int wn   = (wave & 1) * 64;
    const int l15  = lane & 15;
    const int quad = lane >> 4;

    const int s_row = tid >> 2;        // 0..63
    const int s_k8  = (tid & 3) * 8;   // 0/8/16/24

    f32x4 acc[4][4];
#pragma unroll
    for (int i = 0; i < 4; ++i)
#pragma unroll
        for (int j = 0; j < 4; ++j) acc[i][j] = (f32x4){0.f, 0.f, 0.f, 0.f};

    bf16x8 apre[2], bpre[2];

    auto loadAB = [&](int ko) {
        apre[0] = *(const bf16x8*)(Ab + (size_t)(m0 + s_row)      * Kp + ko + s_k8);
        apre[1] = *(const bf16x8*)(Ab + (size_t)(m0 + s_row + 64) * Kp + ko + s_k8);
        bpre[0] = *(const bf16x8*)(Xt + (size_t)(c0 + s_row)      * Kp + ko + s_k8);
        bpre[1] = *(const bf16x8*)(Xt + (size_t)(c0 + s_row + 64) * Kp + ko + s_k8);
    };
    auto stage = [&](int buf) {
        *(bf16x8*)&As[buf][s_row * PAD + s_k8]        = apre[0];
        *(bf16x8*)&As[buf][(s_row + 64) * PAD + s_k8] = apre[1];
        *(bf16x8*)&Bs[buf][s_row * PAD + s_k8]        = bpre[0];
        *(bf16x8*)&Bs[buf][(s_row + 64) * PAD + s_k8] = bpre[1];
    };

    loadAB(kbeg);
    stage(0);
    __syncthreads();

    for (int s = 0; s < nslab; ++s) {
        const int cur = s & 1;
        const bool more = (s + 1) < nslab;
        if (more) loadAB(kbeg + (s + 1) * 32);

        bf16x8 af[4], bfr[4];
#pragma unroll
        for (int t = 0; t < 4; ++t) {
            af[t]  = *(const bf16x8*)&As[cur][(wm + t * 16 + l15) * PAD + quad * 8];
            bfr[t] = *(const bf16x8*)&Bs[cur][(wn + t * 16 + l15) * PAD + quad * 8];
        }
#pragma unroll
        for (int tm = 0; tm < 4; ++tm)
#pragma unroll
            for (int tn = 0; tn < 4; ++tn)
                acc[tm][tn] = __builtin_amdgcn_mfma_f32_16x16x32_bf16(af[tm], bfr[tn], acc[tm][tn], 0, 0, 0);

        if (more) { stage(cur ^ 1); __syncthreads(); }
    }

#pragma unroll
    for (int tm = 0; tm < 4; ++tm)
#pragma unroll
        for (int tn = 0; tn < 4; ++tn)
#pragma unroll
            for (int reg = 0; reg < 4; ++reg) {
                int m  = m0 + wm + tm * 16 + quad * 4 + reg;
                int cc = c0 + wn + tn * 16 + l15;
                if (m < M) {
                    int bb = cc >> logF, f = cc & fmask;
                    float* dst = Y + (((size_t)bb * M + m) << logF) + f;
                    if (atomic_flag) atomicAdd(dst, acc[tm][tn][reg]);
                    else *dst = acc[tm][tn][reg];
                }
            }
}

// ---------------------------------------------------------------------------
// dsamp_mfma2: A pre-converted bf16 [Mp][Kp]; X fp32 staged to LDS. D1/U1.
// ---------------------------------------------------------------------------
__global__ __launch_bounds__(256) void dsamp_mfma2_kernel(
    const unsigned short* __restrict__ Ap, const float* __restrict__ X,
    float* __restrict__ Y, int M, int K, int Kp, int logF, int kchunk,
    int atomic_flag)
{
    constexpr int PAD = 40;
    __shared__ unsigned short Xs[2][64 * PAD];

    const int fmask = (1 << logF) - 1;
    const int m0   = blockIdx.x * 64;
    const int c0   = blockIdx.y * 64;
    const int kbeg = blockIdx.z * kchunk;
    int kend = kbeg + kchunk; if (kend > K) kend = K;
    const int nslab = (kend - kbeg + 31) >> 5;

    const int tid  = threadIdx.x;
    const int lane = tid & 63;
    const int wave = tid >> 6;
    const int wm   = (wave >> 1) * 32;
    const int wn   = (wave & 1) * 32;
    const int l15  = lane & 15;
    const int quad = lane >> 4;

    const int skk  = tid >> 4;
    const int scg  = (tid & 15) * 4;
    const int cB   = c0 + scg;
    const int xbb  = cB >> logF;
    const int xf   = cB & fmask;
    const size_t xrowbase = (((size_t)xbb * K) << logF) + xf;

    const int mA0 = m0 + wm + l15;
    const int mA1 = mA0 + 16;
    const int kaoff = quad * 8;

    f32x4 acc[2][2];
    acc[0][0] = acc[0][1] = acc[1][0] = acc[1][1] = (f32x4){0.f, 0.f, 0.f, 0.f};

    float4 xn0, xn1;
    bf16x8 ac0, ac1, an0, an1;

    {
        int k = kbeg + skk;
        xn0 = make_float4(0.f, 0.f, 0.f, 0.f);
        if (k < kend) xn0 = *(const float4*)(X + xrowbase + ((size_t)k << logF));
        k = kbeg + 16 + skk;
        xn1 = make_float4(0.f, 0.f, 0.f, 0.f);
        if (k < kend) xn1 = *(const float4*)(X + xrowbase + ((size_t)k << logF));
        int ka = kbeg + kaoff;
        ac0 = *(const bf16x8*)(Ap + (size_t)mA0 * Kp + ka);
        ac1 = *(const bf16x8*)(Ap + (size_t)mA1 * Kp + ka);
        unsigned short* p = &Xs[0][0];
        p[(scg + 0) * PAD + skk] = f2bf(xn0.x);
        p[(scg + 1) * PAD + skk] = f2bf(xn0.y);
        p[(scg + 2) * PAD + skk] = f2bf(xn0.z);
        p[(scg + 3) * PAD + skk] = f2bf(xn0.w);
        int kk1 = 16 + skk;
        p[(scg + 0) * PAD + kk1] = f2bf(xn1.x);
        p[(scg + 1) * PAD + kk1] = f2bf(xn1.y);
        p[(scg + 2) * PAD + kk1] = f2bf(xn1.z);
        p[(scg + 3) * PAD + kk1] = f2bf(xn1.w);
    }
    __syncthreads();

    for (int s = 0; s < nslab; ++s) {
        const int cur = s & 1;
        const bool more = (s + 1 < nslab);
        if (more) {
            int k0 = kbeg + (s + 1) * 32;
            int k = k0 + skk;
            xn0 = make_float4(0.f, 0.f, 0.f, 0.f);
            if (k < kend) xn0 = *(const float4*)(X + xrowbase + ((size_t)k << logF));
            k = k0 + 16 + skk;
            xn1 = make_float4(0.f, 0.f, 0.f, 0.f);
            if (k < kend) xn1 = *(const float4*)(X + xrowbase + ((size_t)k << logF));
            int ka = k0 + kaoff;
            an0 = *(const bf16x8*)(Ap + (size_t)mA0 * Kp + ka);
            an1 = *(const bf16x8*)(Ap + (size_t)mA1 * Kp + ka);
        }
        {
            const unsigned short* p = &Xs[cur][0];
            bf16x8 b0 = *(const bf16x8*)&p[(wn +      l15) * PAD + quad * 8];
            bf16x8 b1 = *(const bf16x8*)&p[(wn + 16 + l15) * PAD + quad * 8];
            acc[0][0] = __builtin_amdgcn_mfma_f32_16x16x32_bf16(ac0, b0, acc[0][0], 0, 0, 0);
            acc[0][1] = __builtin_amdgcn_mfma_f32_16x16x32_bf16(ac0, b1, acc[0][1], 0, 0, 0);
            acc[1][0] = __builtin_amdgcn_mfma_f32_16x16x32_bf16(ac1, b0, acc[1][0], 0, 0, 0);
            acc[1][1] = __builtin_amdgcn_mfma_f32_16x16x32_bf16(ac1, b1, acc[1][1], 0, 0, 0);
        }
        if (more) {
            unsigned short* q = &Xs[cur ^ 1][0];
            q[(scg + 0) * PAD + skk] = f2bf(xn0.x);
            q[(scg + 1) * PAD + skk] = f2bf(xn0.y);
            q[(scg + 2) * PAD + skk] = f2bf(xn0.z);
            q[(scg + 3) * PAD + skk] = f2bf(xn0.w);
            int kk1 = 16 + skk;
            q[(scg + 0) * PAD + kk1] = f2bf(xn1.x);
            q[(scg + 1) * PAD + kk1] = f2bf(xn1.y);
            q[(scg + 2) * PAD + kk1] = f2bf(xn1.z);
            q[(scg + 3) * PAD + kk1] = f2bf(xn1.w);
            __syncthreads();
            ac0 = an0; ac1 = an1;
        }
    }

#pragma unroll
    for (int tm = 0; tm < 2; ++tm)
#pragma unroll
        for (int tn = 0; tn < 2; ++tn)
#pragma unroll
            for (int reg = 0; reg < 4; ++reg) {
                int m  = m0 + wm + tm * 16 + quad * 4 + reg;
                int cc = c0 + wn + tn * 16 + l15;
                if (m < M) {
                    int bb = cc >> logF, f = cc & fmask;
                    float* dst = Y + (((size_t)bb * M + m) << logF) + f;
                    if (atomic_flag) atomicAdd(dst, acc[tm][tn][reg]);
                    else *dst = acc[tm][tn][reg];
                }
            }
}

// ---------------------------------------------------------------------------
// conv_gemm (fp32 gather). e0 only. Grid: (batch, mtile).
// ---------------------------------------------------------------------------
template<int MT, int OT>
__global__ __launch_bounds__(256) void conv_gemm_kernel(
    const float* __restrict__ x, const int* __restrict__ S,
    const float* __restrict__ W, const float* __restrict__ bias,
    float* __restrict__ y, int Nv, int logF, int O, int KF, int KFr,
    int elu_flag)
{
    constexpr int CT = OT / 4;
    constexpr int RT = 256 / CT;
    static_assert(RT * 4 == MT, "tile shape");
    __shared__ float Gs[32][MT];
    __shared__ float Ws[32][OT];

    const int b   = blockIdx.x;
    const int n0  = blockIdx.y * MT;
    const int tid = threadIdx.x;
    const int cx  = tid % CT;
    const int ry  = tid / CT;
    const int r0  = ry * 4;
    const int o0  = cx * 4;
    const int fmask = (1 << logF) - 1;
    const size_t xb = (size_t)b * Nv;

    float acc[4][4];
#pragma unroll
    for (int i = 0; i < 4; ++i)
#pragma unroll
        for (int j = 0; j < 4; ++j) acc[i][j] = 0.f;

    for (int k0 = 0; k0 < KF; k0 += 32) {
        constexpr int GSLOTS = MT * 8;
#pragma unroll
        for (int i = 0; i < GSLOTS / 256; ++i) {
            int idx = tid + i * 256;
            int r   = idx & (MT - 1);
            int jg  = idx / MT;
            int j0  = jg * 4;
            int n   = n0 + r;
            int kf  = k0 + j0;
            float4 v = make_float4(0.f, 0.f, 0.f, 0.f);
            if (n < Nv && kf < KFr) {
                int k   = kf >> logF;
                int f   = kf & fmask;
                int src = S[n * SPK + k];
                v = *(const float4*)(x + ((xb + src) << logF) + f);
            }
            Gs[j0 + 0][r] = v.x; Gs[j0 + 1][r] = v.y;
            Gs[j0 + 2][r] = v.z; Gs[j0 + 3][r] = v.w;
        }
        constexpr int WSLOTS = OT * 8;
#pragma unroll
        for (int i = 0; i < (WSLOTS + 255) / 256; ++i) {
            int idx = tid + i * 256;
            if (WSLOTS >= 256 || idx < WSLOTS) {
                int o  = idx & (OT - 1);
                int jg = idx / OT;
                int j0 = jg * 4;
                float4 v = *(const float4*)(W + (size_t)o * KF + k0 + j0);
                Ws[j0 + 0][o] = v.x; Ws[j0 + 1][o] = v.y;
                Ws[j0 + 2][o] = v.z; Ws[j0 + 3][o] = v.w;
            }
        }
        __syncthreads();
#pragma unroll
        for (int kk = 0; kk < 32; ++kk) {
            float4 g = *(const float4*)&Gs[kk][r0];
            float4 w = *(const float4*)&Ws[kk][o0];
            acc[0][0] += g.x * w.x; acc[0][1] += g.x * w.y; acc[0][2] += g.x * w.z; acc[0][3] += g.x * w.w;
            acc[1][0] += g.y * w.x; acc[1][1] += g.y * w.y; acc[1][2] += g.y * w.z; acc[1][3] += g.y * w.w;
            acc[2][0] += g.z * w.x; acc[2][1] += g.z * w.y; acc[2][2] += g.z * w.z; acc[2][3] += g.z * w.w;
            acc[3][0] += g.w * w.x; acc[3][1] += g.w * w.y; acc[3][2] += g.w * w.z; acc[3][3] += g.w * w.w;
        }
        __syncthreads();
    }

    float4 bv = *(const float4*)(bias + o0);
#pragma unroll
    for (int i = 0; i < 4; ++i) {
        int n = n0 + r0 + i;
        if (n >= Nv) continue;
        float v0 = acc[i][0] + bv.x;
        float v1 = acc[i][1] + bv.y;
        float v2 = acc[i][2] + bv.z;
        float v3 = acc[i][3] + bv.w;
        if (elu_flag) {
            v0 = v0 > 0.f ? v0 : expm1f(v0);
            v1 = v1 > 0.f ? v1 : expm1f(v1);
            v2 = v2 > 0.f ? v2 : expm1f(v2);
            v3 = v3 > 0.f ? v3 : expm1f(v3);
        }
        if (n == Nv - 1) { v0 = v1 = v2 = v3 = 0.f; }
        *(float4*)(y + ((size_t)b * Nv + n) * O + o0) = make_float4(v0, v1, v2, v3);
    }
}

// ---------------------------------------------------------------------------
// VALU down/up-sample (tiny levels 2-3 only). OBF16: emit bf16 output.
// ---------------------------------------------------------------------------
template<int OBF16>
__global__ __launch_bounds__(256) void dsamp_kernel(
    const float* __restrict__ A, const float* __restrict__ X,
    void* __restrict__ Yv, int M, int N, int F)
{
    __shared__ float As[16][68];
    __shared__ float Xs[16][64];

    const int m0  = blockIdx.x * 64;
    const int c0  = blockIdx.y * 64;
    const int tid = threadIdx.x;
    const int tx  = tid & 15;
    const int ty  = tid >> 4;

    float acc[4][4];
#pragma unroll
    for (int i = 0; i < 4; ++i)
#pragma unroll
        for (int j = 0; j < 4; ++j) acc[i][j] = 0.f;

    for (int k0 = 0; k0 < N; k0 += 16) {
#pragma unroll
        for (int p = 0; p < 4; ++p) {
            int r  = (tid >> 4) + p * 16;
            int kk = tid & 15;
            int m  = m0 + r;
            int n  = k0 + kk;
            float v = 0.f;
            if (m < M && n < N) v = A[(size_t)m * N + n];
            As[kk][r] = v;
        }
        {
            int kk = tid >> 4;
            int cc = (tid & 15) * 4;
            int n  = k0 + kk;
            float4 v = make_float4(0.f, 0.f, 0.f, 0.f);
            if (n < N) {
                int c  = c0 + cc;
                int bb = c / F;
                int f  = c - bb * F;
                v = *(const float4*)(X + ((size_t)bb * N + n) * F + f);
            }
            *(float4*)&Xs[kk][cc] = v;
        }
        __syncthreads();
#pragma unroll
        for (int kk = 0; kk < 16; ++kk) {
            float4 av = *(const float4*)&As[kk][ty * 4];
            float4 xv = *(const float4*)&Xs[kk][tx * 4];
            acc[0][0] += av.x * xv.x; acc[0][1] += av.x * xv.y; acc[0][2] += av.x * xv.z; acc[0][3] += av.x * xv.w;
            acc[1][0] += av.y * xv.x; acc[1][1] += av.y * xv.y; acc[1][2] += av.y * xv.z; acc[1][3] += av.y * xv.w;
            acc[2][0] += av.z * xv.x; acc[2][1] += av.z * xv.y; acc[2][2] += av.z * xv.z; acc[2][3] += av.z * xv.w;
            acc[3][0] += av.w * xv.x; acc[3][1] += av.w * xv.y; acc[3][2] += av.w * xv.z; acc[3][3] += av.w * xv.w;
        }
        __syncthreads();
    }

    const int cbase = c0 + tx * 4;
    const int bb = cbase / F;
    const int f  = cbase - bb * F;
#pragma unroll
    for (int i = 0; i < 4; ++i) {
        int m = m0 + ty * 4 + i;
        if (m < M) {
            size_t off = ((size_t)bb * M + m) * F + f;
            if (OBF16) {
                bf16x4 v;
                v[0] = (short)f2bf(acc[i][0]); v[1] = (short)f2bf(acc[i][1]);
                v[2] = (short)f2bf(acc[i][2]); v[3] = (short)f2bf(acc[i][3]);
                *(bf16x4*)((unsigned short*)Yv + off) = v;
            } else {
                *(float4*)((float*)Yv + off) =
                    make_float4(acc[i][0], acc[i][1], acc[i][2], acc[i][3]);
            }
        }
    }
}

// ---------------------------------------------------------------------------
// fc_wave: one 64-lane wave per output element.
// ---------------------------------------------------------------------------
__global__ __launch_bounds__(256) void fc_wave_kernel(
    const float* __restrict__ in, const float* __restrict__ W,
    const float* __restrict__ bias, float* __restrict__ out,
    int In, int O, int dup)
{
    const int gw   = blockIdx.x * 4 + (threadIdx.x >> 6);
    const int lane = threadIdx.x & 63;
    const int b = gw / O;
    const int o = gw - b * O;
    const float* xr = in + (size_t)b * In;
    float acc = 0.f;
    if (dup) {
        const float* wr = W + (size_t)o * (2 * In);
        for (int k = lane; k < In; k += 64)
            acc += xr[k] * (wr[k] + wr[In + k]);
    } else {
        const float* wr = W + (size_t)o * In;
        for (int k = lane; k < In; k += 64)
            acc += xr[k] * wr[k];
    }
#pragma unroll
    for (int off = 32; off > 0; off >>= 1)
        acc += __shfl_down(acc, off, 64);
    if (lane == 0) out[(size_t)b * O + o] = acc + bias[o];
}

// ---------------------------------------------------------------------------
// Transpose-convert: x [b][k][f] fp32 -> xt [c][k] bf16, c = b*F+f, stride Kp.
// ---------------------------------------------------------------------------
__global__ __launch_bounds__(256) void xpose_bf16_kernel(
    const float* __restrict__ x, unsigned short* __restrict__ xt,
    int K, int Kp, int logF)
{
    const int c  = blockIdx.y * 256 + threadIdx.x;
    const int k0 = blockIdx.x * 8;
    const int bb = c >> logF;
    const int f  = c & ((1 << logF) - 1);
    const float* src = x + (((size_t)bb * K) << logF) + f;
    bf16x8 r;
#pragma unroll
    for (int j = 0; j < 8; ++j) {
        int k = k0 + j;
        float v = (k < K) ? src[(size_t)k << logF] : 0.f;
        r[j] = (short)f2bf(v);
    }
    *(bf16x8*)(xt + (size_t)c * Kp + k0) = r;
}

// ---------------------------------------------------------------------------
// Padding / extraction helpers.
// ---------------------------------------------------------------------------
__global__ __launch_bounds__(256) void pad_e0_w_kernel(
    const float* __restrict__ w, float* __restrict__ wp)
{
    int i = blockIdx.x * 256 + threadIdx.x;
    if (i < 1024) {
        int o = i >> 6, kf = i & 63;
        int k = kf >> 2, f = kf & 3;
        wp[i] = (f < 3 && k < 12) ? w[o * 36 + k * 3 + f] : 0.f;
    }
}
__global__ __launch_bounds__(256) void pad_x4_kernel(
    const float* __restrict__ x, float* __restrict__ xp, int n)
{
    int i = blockIdx.x * 256 + threadIdx.x;
    if (i < n) {
        int f = i & 3, nb = i >> 2;
        xp[i] = (f < 3) ? x[nb * 3 + f] : 0.f;
    }
}
__global__ __launch_bounds__(256) void pad_c4_w_kernel(
    const float* __restrict__ w, const float* __restrict__ b,
    float* __restrict__ wp, float* __restrict__ bp)
{
    int i = blockIdx.x * 256 + threadIdx.x;
    if (i < 3072) {
        int o = i / 192;
        wp[i] = (o < 3) ? w[i] : 0.f;
    }
    if (i < 16) bp[i] = (i < 3) ? b[i] : 0.f;
}
__global__ __launch_bounds__(256) void extract_add_kernel(
    const float* __restrict__ cp, const float* __restrict__ t,
    float* __restrict__ o0, float* __restrict__ o1, int n)
{
    int i = blockIdx.x * 256 + threadIdx.x;
    if (i < n) {
        int f = i % 3, nb = i / 3;
        float v = cp[(size_t)nb * 16 + f];
        o0[i] = v;
        o1[i] = v + t[i];
    }
}

// ---------------------------------------------------------------------------

static inline int ilog2(int v) { int l = 0; while ((1 << l) < v) ++l; return l; }

static inline void a_bf16_launch(const float* A, unsigned short* Ap, int M, int K,
                                 int Mp, int Kp, hipStream_t s)
{
    int total = Mp * (Kp >> 3);
    a_bf16_pad_kernel<<<(total + 255) / 256, 256, 0, s>>>(A, Ap, M, K, Kp, total);
}

static inline void dsamp_mfma2_launch(const unsigned short* Ap, const float* X,
                                      float* Y, int M, int K, int Kp, int F,
                                      int ks, hipStream_t s)
{
    int kchunk = (K + ks - 1) / ks;
    kchunk = (kchunk + 31) & ~31;
    int ksz = (K + kchunk - 1) / kchunk;
    dim3 grid((M + 63) / 64, F, ksz);
    dsamp_mfma2_kernel<<<grid, 256, 0, s>>>(Ap, X, Y, M, K, Kp, ilog2(F), kchunk,
                                            ksz > 1 ? 1 : 0);
}

static inline void dsamp_mfma3_launch(const unsigned short* Ab, const unsigned short* Xt,
                                      float* Y, int M, int Kp, int F,
                                      int ks, hipStream_t s)
{
    int slabs = Kp >> 5;
    int kchunk = ((slabs + ks - 1) / ks) * 32;
    int ksz = (Kp + kchunk - 1) / kchunk;
    int gx = (M + 127) / 128, gy = (BATCH * F) / 128;
    int total = gx * gy * ksz;
    int swz = (ksz > 1 && (total & 7) == 0) ? 1 : 0;
    dim3 grid(gx, gy, ksz);
    dsamp_mfma3_kernel<<<grid, 256, 0, s>>>(Ab, Xt, Y, M, Kp, ilog2(F), kchunk,
                                            ksz > 1 ? 1 : 0, swz);
}

template<int OBF16>
static inline void dsamp_launch(const float* A, const float* X, void* Y,
                                int M, int N, int F, hipStream_t s)
{
    dim3 grid((M + 63) / 64, F);
    dsamp_kernel<OBF16><<<grid, 256, 0, s>>>(A, X, Y, M, N, F);
}

extern "C" void kernel_launch(void* const* d_in, const int* in_sizes, int n_in,
                              void* d_out, int out_size, void* d_ws, size_t ws_size,
                              hipStream_t stream)
{
    const float* x_talking = (const float*)d_in[0];
    const float* templ     = (const float*)d_in[1];
    const float* D0 = (const float*)d_in[2];
    const float* U0 = (const float*)d_in[3];
    const float* D1 = (const float*)d_in[4];
    const float* U1 = (const float*)d_in[5];
    const float* D2 = (const float*)d_in[6];
    const float* U2 = (const float*)d_in[7];
    const float* D3 = (const float*)d_in[8];
    const float* U3 = (const float*)d_in[9];
    const float* enc_w0 = (const float*)d_in[10]; const float* enc_b0 = (const float*)d_in[11];
    const float* enc_w1 = (const float*)d_in[12]; const float* enc_b1 = (const float*)d_in[13];
    const float* enc_w2 = (const float*)d_in[14]; const float* enc_b2 = (const float*)d_in[15];
    const float* enc_w3 = (const float*)d_in[16]; const float* enc_b3 = (const float*)d_in[17];
    const float* fc_enc_w = (const float*)d_in[18]; const float* fc_enc_b = (const float*)d_in[19];
    const float* fc_dec_w = (const float*)d_in[20]; const float* fc_dec_b = (const float*)d_in[21];
    const float* dec_w0 = (const float*)d_in[22]; const float* dec_b0 = (const float*)d_in[23];
    const float* dec_w1 = (const float*)d_in[24]; const float* dec_b1 = (const float*)d_in[25];
    const float* dec_w2 = (const float*)d_in[26]; const float* dec_b2 = (const float*)d_in[27];
    const float* dec_w3 = (const float*)d_in[28]; const float* dec_b3 = (const float*)d_in[29];
    const float* dec_w4 = (const float*)d_in[30]; const float* dec_b4 = (const float*)d_in[31];
    const int* S0 = (const int*)d_in[32];
    const int* S1 = (const int*)d_in[33];
    const int* S2 = (const int*)d_in[34];
    const int* S3 = (const int*)d_in[35];

    float* bufA = (float*)d_ws;            // 10,289,152 floats (41.2 MB)
    float* bufB = bufA + 10289152;         // 5,144,576 floats (20.6 MB)

    float* out0 = (float*)d_out;           // 964,608 floats
    float* out1 = out0 + 964608;

    // ---- workspace aliases (lifetimes audited) ----
    unsigned short* Xt_e0 = (unsigned short*)(bufB + 1290240);
    unsigned short* Xt_c2 = (unsigned short*)bufB;
    unsigned short* U0b   = (unsigned short*)(bufB + 1400000);
    unsigned short* Wb_e2 = (unsigned short*)(bufB + 4700000);
    unsigned short* Wb_e3 = (unsigned short*)(bufB + 4715000);
    unsigned short* Wb_c0 = (unsigned short*)(bufB + 4765000);
    unsigned short* Wb_c1 = (unsigned short*)(bufB + 4815000);
    float* xpad   = bufA + 5200000;   // e0 fp32 input padded to F=4 (dead after e0)
    float* WpE0   = bufA + 6600000;   // e0 W fp32 padded [16][64]
    unsigned short* D0b   = (unsigned short*)(bufA + 6700000);
    unsigned short* D1b   = (unsigned short*)(bufA + 9950000);
    unsigned short* U1b   = (unsigned short*)(bufA + 4000000);
    unsigned short* Wb_e1 = (unsigned short*)(bufA + 10160000);
    unsigned short* Wb_c2 = (unsigned short*)(bufA + 10170000);
    unsigned short* Xb_e1   = (unsigned short*)(bufA + 5200000);
    unsigned short* Xb_e2   = (unsigned short*)(bufA + 2000000);
    unsigned short* Xb_c2in = (unsigned short*)(bufA + 2600000);
    unsigned short* Xb_c3 = (unsigned short*)bufB;
    unsigned short* Xb_c4 = (unsigned short*)(bufA + 5200000);
    unsigned short* Wb_c3 = (unsigned short*)bufA;   // written post-u0-convert
    float* WpC4   = bufA + 10000;
    float* BpC4   = bufA + 13500;
    unsigned short* Wb_c4 = (unsigned short*)(bufA + 14000);

    // Zero only d0's atomic-accumulation target.
    hipMemsetAsync(bufB, 0, (size_t)1287168 * sizeof(float), stream);

    // ---- input-only pre-conversions ----
    pad_e0_w_kernel<<<4, 256, 0, stream>>>(enc_w0, WpE0);
    pad_x4_kernel<<<5024, 256, 0, stream>>>(x_talking, xpad, 1286144);
    a_bf16_launch(D0, D0b, 1257, 5024, 1280, 5024, stream);
    a_bf16_launch(D1, D1b, 315, 1257, 320, 1280, stream);
    f32_to_bf16_kernel<<<3, 256, 0, stream>>>(enc_w1, Wb_e1, 768);
    f32_to_bf16_kernel<<<6, 256, 0, stream>>>(dec_w2, Wb_c2, 1536);
    f32_to_bf16_kernel<<<12, 256, 0, stream>>>(enc_w2, Wb_e2, 3072);
    f32_to_bf16_kernel<<<48, 256, 0, stream>>>(enc_w3, Wb_e3, 12288);
    f32_to_bf16_kernel<<<48, 256, 0, stream>>>(dec_w0, Wb_c0, 12288);
    f32_to_bf16_kernel<<<12, 256, 0, stream>>>(dec_w1, Wb_c1, 3072);

    // ---- encoder ----
    {   // e0: F=4(pad), KF=64 (KFr=48), O=16, fp32 (first-layer precision)
        dim3 grid(BATCH, (5024 + 255) / 256);
        conv_gemm_kernel<256, 16><<<grid, 256, 0, stream>>>(
            xpad, S0, WpE0, enc_b0, bufA, 5024, 2, 16, 64, 48, 1);
    }
    xpose_bf16_kernel<<<dim3(628, 4), 256, 0, stream>>>(bufA, Xt_e0, 5024, 5024, 4);
    dsamp_mfma3_launch(D0b, Xt_e0, bufB, 1257, 5024, 16, 8, stream);            // d0 [atomic ks=8, XCD-swz]
    f32_to_bf16_kernel<<<629, 256, 0, stream>>>(bufB, Xb_e1, 160896);           // d0-out -> bf16
    a_bf16_launch(U0, U0b, 5024, 1257, 5120, 1280, stream);
    a_bf16_launch(U1, U1b, 1257, 315, 1280, 320, stream);
    {   // e1: MFMA conv, F=16, O=32, ELU -> bufA [64,1257,32]
        dim3 grid(BATCH, (1257 + 255) / 256);
        conv_mfma32_kernel<4><<<grid, 256, 0, stream>>>(
            Xb_e1, S1, Wb_e1, enc_b1, bufA, 1257, 192, 1);
    }
    hipMemsetAsync(bufB, 0, (size_t)645120 * sizeof(float), stream);            // zero d1 target
    dsamp_mfma2_launch(D1b, bufA, bufB, 315, 1257, 1280, 32, 8, stream);        // d1 [atomic ks=8]
    f32_to_bf16_kernel<<<315, 256, 0, stream>>>(bufB, Xb_e2, 80640);            // d1-out -> bf16
    {   // e2: wave-MFMA conv, F=32, O=64 -> bufA fp32 [64,315,64]
        dim3 grid((315 + 15) / 16, 64 / 16, BATCH);
        conv_wmfma_kernel<5, 0><<<grid, 64, 0, stream>>>(
            Xb_e2, S2, Wb_e2, enc_b2, bufA, 315, 64, 1, 0);
    }
    dsamp_launch<1>(D2, bufA, bufB, 80, 315, 64, stream);                       // d2 -> bf16
    {   // e3: wave-MFMA conv, F=64, O=128 -> bufA fp32 [64,80,128]
        dim3 grid((80 + 15) / 16, 128 / 16, BATCH);
        conv_wmfma_kernel<6, 0><<<grid, 64, 0, stream>>>(
            (const unsigned short*)bufB, S3, Wb_e3, enc_b3, bufA, 80, 128, 1, 0);
    }
    dsamp_launch<0>(D3, bufA, bufB, 21, 80, 128, stream);                       // d3 fp32

    fc_wave_kernel<<<dim3((BATCH * 128) / 4), 256, 0, stream>>>(bufB, fc_enc_w, fc_enc_b, bufA, 2688, 128, 0);
    fc_wave_kernel<<<dim3((BATCH * 2688) / 4), 256, 0, stream>>>(bufA, fc_dec_w, fc_dec_b, bufB, 128, 2688, 1);

    // ---- decoder ----
    dsamp_launch<1>(U3, bufB, bufA, 80, 21, 128, stream);                       // u3 -> bf16
    {   // c0: wave-MFMA conv, F=128, O=64 -> bufB fp32 [64,80,64]
        dim3 grid((80 + 15) / 16, 64 / 16, BATCH);
        conv_wmfma_kernel<7, 0><<<grid, 64, 0, stream>>>(
            (const unsigned short*)bufA, S3, Wb_c0, dec_b0, bufB, 80, 64, 1, 0);
    }
    dsamp_launch<1>(U2, bufB, bufA, 315, 80, 64, stream);                       // u2 -> bf16
    {   // c1: wave-MFMA conv, F=64, O=32 -> bufB fp32 [64,315,32]
        dim3 grid((315 + 15) / 16, 32 / 16, BATCH);
        conv_wmfma_kernel<6, 0><<<grid, 64, 0, stream>>>(
            (const unsigned short*)bufA, S2, Wb_c1, dec_b1, bufB, 315, 32, 1, 0);
    }
    dsamp_mfma2_launch(U1b, bufB, bufA, 1257, 315, 320, 32, 1, stream);         // u1 -> bufA [64,1257,32]
    f32_to_bf16_kernel<<<1257, 256, 0, stream>>>(bufA, Xb_c2in, 321792);        // u1-out -> bf16
    {   // c2: MFMA conv, F=32, O=32, ELU -> bufA [64,1257,32]
        dim3 grid(BATCH, (1257 + 255) / 256);
        conv_mfma32_kernel<5><<<grid, 256, 0, stream>>>(
            Xb_c2in, S1, Wb_c2, dec_b2, bufA, 1257, 384, 1);
    }
    xpose_bf16_kernel<<<dim3(160, 8), 256, 0, stream>>>(bufA, Xt_c2, 1257, 1280, 5);
    dsamp_mfma3_launch(U0b, Xt_c2, bufA, 5024, 1280, 32, 1, stream);            // u0 [ks=1, plain stores]

    // u0-out (bufA fp32 [64,5024,32]) -> bf16 (all of bufB)
    f32_to_bf16_kernel<<<5024, 256, 0, stream>>>(bufA, Xb_c3, 1286144);
    // c3/c4 weight conversions (bufA dead after Xb_c3 convert)
    f32_to_bf16_kernel<<<3, 256, 0, stream>>>(dec_w3, Wb_c3, 768);
    pad_c4_w_kernel<<<12, 256, 0, stream>>>(dec_w4, dec_b4, WpC4, BpC4);
    f32_to_bf16_kernel<<<2, 256, 0, stream>>>(WpC4, Wb_c4, 384);
    {   // c3: wave-MFMA conv, F=32, O=16, ELU; bf16 out -> Xb_c4 [XCD-swz]
        dim3 grid((5024 + 15) / 16, 1, BATCH);
        conv_wmfma_kernel<5, 1><<<grid, 64, 0, stream>>>(
            Xb_c3, S0, Wb_c3, dec_b3, (void*)Xb_c4, 5024, 16, 1, 1);
    }
    {   // c4: wave-MFMA conv, F=16, O=16(pad), identity -> bufB [XCD-swz]
        dim3 grid((5024 + 15) / 16, 1, BATCH);
        conv_wmfma_kernel<4, 0><<<grid, 64, 0, stream>>>(
            Xb_c4, S0, Wb_c4, BpC4, (void*)bufB, 5024, 16, 0, 1);
    }
    extract_add_kernel<<<(964608 + 255) / 256, 256, 0, stream>>>(bufB, templ, out0, out1, 964608);
}

// Round 6
// 716.992 us; speedup vs baseline: 1.0424x; 1.0424x over previous
//
#include <hip/hip_runtime.h>
#include <cstddef>

// ---------------------------------------------------------------------------
// SpiralAutoencoder on MI355X — round 16:
//  * Round-15 post-mortem: c3 FETCH 77->11MB but dur flat at 65us — bound by
//    scattered-address (TA) throughput: adjacent lanes gather unrelated rows,
//    64 divergent 16B addrs/instr, 4x L2 sector waste. New conv_cmfma for
//    c3/c4: row-coalesced gather (adjacent lanes read consecutive 16B of the
//    same spiral row) -> LDS -> ds_read MFMA frags; W pre-swizzled to frag
//    order (dense 1KB load). Bitwise-identical numerics to round-15 path.
// ---------------------------------------------------------------------------

#define BATCH 64
#define SPK 12  // spiral length

typedef __attribute__((ext_vector_type(8))) short bf16x8;
typedef __attribute__((ext_vector_type(4))) short bf16x4;
typedef __attribute__((ext_vector_type(4))) float f32x4;

__device__ __forceinline__ unsigned short f2bf(float x) {
    union { float f; unsigned int u; } v; v.f = x;
    unsigned int r = v.u + 0x7FFF + ((v.u >> 16) & 1);  // RNE
    return (unsigned short)(r >> 16);
}

// ---------------------------------------------------------------------------
// Flat fp32 -> bf16 convert (8 elems/thread).
// ---------------------------------------------------------------------------
__global__ __launch_bounds__(256) void f32_to_bf16_kernel(
    const float* __restrict__ in, unsigned short* __restrict__ out, int n8)
{
    int i = blockIdx.x * 256 + threadIdx.x;
    if (i < n8) {
        const float* p = in + (size_t)i * 8;
        bf16x8 r;
#pragma unroll
        for (int j = 0; j < 8; ++j) r[j] = (short)f2bf(p[j]);
        *(bf16x8*)(out + (size_t)i * 8) = r;
    }
}

// ---------------------------------------------------------------------------
// fp32 [M][K] -> bf16 [Mp][Kp] with zero padding (rows >= M, cols >= K).
// ---------------------------------------------------------------------------
__global__ __launch_bounds__(256) void a_bf16_pad_kernel(
    const float* __restrict__ A, unsigned short* __restrict__ Ap,
    int M, int K, int Kp, int total)
{
    int i = blockIdx.x * 256 + threadIdx.x;
    if (i >= total) return;
    int kp8 = Kp >> 3;
    int m = i / kp8;
    int k0 = (i - m * kp8) * 8;
    bf16x8 r;
    if (m < M) {
        const float* src = A + (size_t)m * K + k0;
#pragma unroll
        for (int j = 0; j < 8; ++j) {
            float v = (k0 + j < K) ? src[j] : 0.f;
            r[j] = (short)f2bf(v);
        }
    } else {
#pragma unroll
        for (int j = 0; j < 8; ++j) r[j] = 0;
    }
    *(bf16x8*)(Ap + (size_t)m * Kp + k0) = r;
}

// ---------------------------------------------------------------------------
// W frag pre-swizzle for O=16 convs: Wfs[(s*64+lane)*8+j] =
// Wb[l15*KF + s*32 + quad*8 + j]. Makes per-slab W-frag loads fully dense.
// ---------------------------------------------------------------------------
__global__ __launch_bounds__(256) void w_frag16_kernel(
    const unsigned short* __restrict__ Wb, unsigned short* __restrict__ Wfs,
    int KF, int total)
{
    int i = blockIdx.x * 256 + threadIdx.x;
    if (i >= total) return;
    int j    = i & 7;
    int lane = (i >> 3) & 63;
    int s    = i >> 9;
    int l15  = lane & 15;
    int quad = (lane >> 4) & 3;
    Wfs[i] = Wb[l15 * KF + s * 32 + quad * 8 + j];
}

// ---------------------------------------------------------------------------
// conv_cmfma: O=16 spiral conv, one wave per 16-row tile, row-COALESCED
// gather. Lanes cooperate to read full spiral rows (adjacent lanes =
// consecutive 16B chunks) into padded LDS; MFMA A-frags via ds_read_b128;
// W pre-swizzled to frag order (dense load). Numerically identical to the
// conv_wmfma path (same MFMA order, same acc split). c3/c4 (Nv=5024).
// ---------------------------------------------------------------------------
template<int LOGF, int OBF16>
__global__ __launch_bounds__(64, 4) void conv_cmfma_kernel(
    const unsigned short* __restrict__ x, const int* __restrict__ S,
    const unsigned short* __restrict__ Wfs, const float* __restrict__ bias,
    void* __restrict__ yv, int Nv, int elu_flag, int swz)
{
    constexpr int F     = 1 << LOGF;
    constexpr int KF    = SPK * F;                 // 384 (c3) / 192 (c4)
    constexpr int NS    = KF / 32;                 // 12 / 6
    constexpr int RPADu = (LOGF == 5) ? 40 : 24;   // LDS row pitch (ushorts)
    __shared__ unsigned short Gs[12 * 16 * RPADu];

    const int lane = threadIdx.x;
    const int l15  = lane & 15;
    const int quad = (lane >> 4) & 3;

    int bx = blockIdx.x, bz = blockIdx.z;
    if (swz) {
        const int gx = gridDim.x;
        const int total = gx * gridDim.z;
        int bid = bx + gx * bz;
        const int chunk = total >> 3;
        int sid = (bid & 7) * chunk + (bid >> 3);
        bx = sid % gx;
        bz = sid / gx;
    }
    const int n0 = bx * 16;
    const int b  = bz;
    const size_t xb = (size_t)b * Nv;

    // S indices: lane g*16+r holds S[n0+r][g*4 .. g*4+3] as int4.
    int4 sv;
    {
        int g = lane >> 4; if (g > 2) g = 2;
        int n = n0 + l15; if (n >= Nv) n = 0;
        sv = *(const int4*)(S + n * SPK + g * 4);
    }

    // Row-coalesced gathers -> LDS.
    if constexpr (LOGF == 5) {
        // one k per instr: row = lane>>2 (16 rows x 64B), chunk = lane&3
        const int grow = lane >> 2, gchk = lane & 3;
#pragma unroll
        for (int k = 0; k < 12; ++k) {
            int sel = ((k >> 2) << 4) | grow;
            int comp = k & 3;
            int src = (comp == 0) ? __shfl(sv.x, sel)
                    : (comp == 1) ? __shfl(sv.y, sel)
                    : (comp == 2) ? __shfl(sv.z, sel)
                                  : __shfl(sv.w, sel);
            bf16x8 v = *(const bf16x8*)(x + ((xb + src) << 5) + gchk * 8);
            *(bf16x8*)&Gs[k * 16 * RPADu + grow * RPADu + gchk * 8] = v;
        }
    } else {
        // two k per instr: kk = 2g+(lane>>5), row = (lane>>1)&15, chunk = lane&1
        const int khalf = lane >> 5, grow = (lane >> 1) & 15, gchk = lane & 1;
#pragma unroll
        for (int g = 0; g < 6; ++g) {
            int k0 = 2 * g;
            int sel0 = ((k0 >> 2) << 4) | grow;
            int sel1 = (((k0 + 1) >> 2) << 4) | grow;
            int s0 = ((k0 & 3) == 0) ? __shfl(sv.x, sel0) : __shfl(sv.z, sel0);
            int s1 = (((k0 + 1) & 3) == 1) ? __shfl(sv.y, sel1) : __shfl(sv.w, sel1);
            int src = khalf ? s1 : s0;
            int k   = k0 + khalf;
            bf16x8 v = *(const bf16x8*)(x + ((xb + src) << 4) + gchk * 8);
            *(bf16x8*)&Gs[k * 16 * RPADu + grow * RPADu + gchk * 8] = v;
        }
    }

    // MFMA chain: A-frags from LDS, W-frags dense (frag-order, L1-shared).
    f32x4 acc0 = (f32x4){0.f, 0.f, 0.f, 0.f};
    f32x4 acc1 = (f32x4){0.f, 0.f, 0.f, 0.f};
#pragma unroll
    for (int s = 0; s < NS; ++s) {
        int kf = s * 32 + quad * 8;
        int k  = kf >> LOGF;
        int f  = kf & (F - 1);
        bf16x8 a = *(const bf16x8*)&Gs[k * 16 * RPADu + l15 * RPADu + f];
        bf16x8 w = *(const bf16x8*)(Wfs + (s * 64 + lane) * 8);
        if (s & 1) acc1 = __builtin_amdgcn_mfma_f32_16x16x32_bf16(a, w, acc1, 0, 0, 0);
        else       acc0 = __builtin_amdgcn_mfma_f32_16x16x32_bf16(a, w, acc0, 0, 0, 0);
    }

    float bv = bias[l15];
#pragma unroll
    for (int reg = 0; reg < 4; ++reg) {
        int nn = n0 + quad * 4 + reg;
        if (nn >= Nv) continue;
        float v = acc0[reg] + acc1[reg] + bv;
        if (elu_flag && v <= 0.f) v = expm1f(v);
        if (nn == Nv - 1) v = 0.f;
        size_t off = ((size_t)b * Nv + nn) * 16 + l15;
        if (OBF16) ((unsigned short*)yv)[off] = f2bf(v);
        else       ((float*)yv)[off] = v;
    }
}

// ---------------------------------------------------------------------------
// conv_wmfma: direct-gather wave kernel (small levels). e2/e3/c0/c1.
// ---------------------------------------------------------------------------
template<int LOGF, int OBF16>
__global__ __launch_bounds__(64) void conv_wmfma_kernel(
    const unsigned short* __restrict__ x, const int* __restrict__ S,
    const unsigned short* __restrict__ Wb, const float* __restrict__ bias,
    void* __restrict__ yv, int Nv, int O, int elu_flag, int swz)
{
    constexpr int F  = 1 << LOGF;
    constexpr int KF = SPK * F;
    constexpr int NS = KF / 32;
    const int lane = threadIdx.x;
    const int l15  = lane & 15;
    const int quad = lane >> 4;

    int bx = blockIdx.x, by = blockIdx.y, bz = blockIdx.z;
    if (swz) {
        const int gx = gridDim.x, gy = gridDim.y;
        const int total = gx * gy * gridDim.z;
        int bid = bx + gx * (by + gy * bz);
        const int chunk = total >> 3;
        int sid = (bid & 7) * chunk + (bid >> 3);
        bx = sid % gx; sid /= gx;
        by = sid % gy;
        bz = sid / gy;
    }

    const int n0   = bx * 16;
    const int o    = by * 16 + l15;
    const int b    = bz;
    const size_t xb = (size_t)b * Nv;

    const int n  = n0 + l15;
    const int ng = (n < Nv) ? n : 0;
    const unsigned short* wrow = Wb + (size_t)o * KF;

    f32x4 acc0 = (f32x4){0.f, 0.f, 0.f, 0.f};
    f32x4 acc1 = (f32x4){0.f, 0.f, 0.f, 0.f};
#pragma unroll
    for (int s = 0; s < NS; ++s) {
        int kf  = s * 32 + quad * 8;
        int k   = kf >> LOGF;
        int f   = kf & (F - 1);
        int src = S[ng * SPK + k];
        bf16x8 a = *(const bf16x8*)(x + ((xb + src) << LOGF) + f);
        bf16x8 w = *(const bf16x8*)(wrow + kf);
        if (s & 1) acc1 = __builtin_amdgcn_mfma_f32_16x16x32_bf16(a, w, acc1, 0, 0, 0);
        else       acc0 = __builtin_amdgcn_mfma_f32_16x16x32_bf16(a, w, acc0, 0, 0, 0);
    }
    float bv = bias[o];
#pragma unroll
    for (int reg = 0; reg < 4; ++reg) {
        int nn = n0 + quad * 4 + reg;
        if (nn >= Nv) continue;
        float v = acc0[reg] + acc1[reg] + bv;
        if (elu_flag && v <= 0.f) v = expm1f(v);
        if (nn == Nv - 1) v = 0.f;
        size_t off = ((size_t)b * Nv + nn) * O + o;
        if (OBF16) ((unsigned short*)yv)[off] = f2bf(v);
        else       ((float*)yv)[off] = v;
    }
}

// ---------------------------------------------------------------------------
// conv_mfma32: O=32 spiral conv via MFMA. W pre-converted bf16. e1/c2.
// ---------------------------------------------------------------------------
template<int LOGF>
__global__ __launch_bounds__(256) void conv_mfma32_kernel(
    const unsigned short* __restrict__ x, const int* __restrict__ S,
    const unsigned short* __restrict__ Wb, const float* __restrict__ bias,
    float* __restrict__ y, int Nv, int KF, int elu_flag)
{
    constexpr int PAD = 40;
    __shared__ unsigned short Gs[2][256 * PAD];

    const int b    = blockIdx.x;
    const int n0   = blockIdx.y * 256;
    const int tid  = threadIdx.x;
    const int lane = tid & 63;
    const int wave = tid >> 6;
    const int wm   = wave * 64;
    const int l15  = lane & 15;
    const int quad = lane >> 4;
    const size_t xb = (size_t)b * Nv;
    const int nslab = KF >> 5;

    f32x4 acc[4][2];
#pragma unroll
    for (int t = 0; t < 4; ++t)
#pragma unroll
        for (int o = 0; o < 2; ++o) acc[t][o] = (f32x4){0.f, 0.f, 0.f, 0.f};

    auto gath = [&](int k0, bf16x8* g) {
        int n = n0 + tid;
        if (n < Nv) {
#pragma unroll
            for (int j = 0; j < 4; ++j) {
                int kf  = k0 + j * 8;
                int k   = kf >> LOGF;
                int f   = kf & ((1 << LOGF) - 1);
                int src = S[n * SPK + k];
                g[j] = *(const bf16x8*)(x + ((xb + src) << LOGF) + f);
            }
        } else {
#pragma unroll
            for (int j = 0; j < 4; ++j)
#pragma unroll
                for (int e = 0; e < 8; ++e) g[j][e] = 0;
        }
    };
    auto put = [&](int buf, const bf16x8* g) {
#pragma unroll
        for (int j = 0; j < 4; ++j)
            *(bf16x8*)&Gs[buf][tid * PAD + j * 8] = g[j];
    };
    auto wfrag = [&](int k0, int o16) {
        return *(const bf16x8*)(Wb + (size_t)(o16 * 16 + l15) * KF + k0 + quad * 8);
    };

    bf16x8 gcur[4], gnext[4];
    gath(0, gcur);
    put(0, gcur);
    __syncthreads();

    for (int s = 0; s < nslab; ++s) {
        const int cur = s & 1;
        const bool more = (s + 1) < nslab;
        if (more) gath((s + 1) * 32, gnext);
        bf16x8 wf0 = wfrag(s * 32, 0);
        bf16x8 wf1 = wfrag(s * 32, 1);
#pragma unroll
        for (int t = 0; t < 4; ++t) {
            bf16x8 a = *(const bf16x8*)&Gs[cur][(wm + t * 16 + l15) * PAD + quad * 8];
            acc[t][0] = __builtin_amdgcn_mfma_f32_16x16x32_bf16(a, wf0, acc[t][0], 0, 0, 0);
            acc[t][1] = __builtin_amdgcn_mfma_f32_16x16x32_bf16(a, wf1, acc[t][1], 0, 0, 0);
        }
        if (more) {
            put(cur ^ 1, gnext);
            __syncthreads();
        }
    }

    float bv0 = bias[l15];
    float bv1 = bias[16 + l15];
#pragma unroll
    for (int t = 0; t < 4; ++t)
#pragma unroll
        for (int reg = 0; reg < 4; ++reg) {
            int n = n0 + wm + t * 16 + quad * 4 + reg;
            if (n >= Nv) continue;
            float v0 = acc[t][0][reg] + bv0;
            float v1 = acc[t][1][reg] + bv1;
            if (elu_flag) {
                if (v0 <= 0.f) v0 = expm1f(v0);
                if (v1 <= 0.f) v1 = expm1f(v1);
            }
            if (n == Nv - 1) { v0 = 0.f; v1 = 0.f; }
            size_t off = ((size_t)b * Nv + n) * 32 + l15;
            y[off]      = v0;
            y[off + 16] = v1;
        }
}

// ---------------------------------------------------------------------------
// dsamp_mfma3: 128x128 tile MFMA resample, both operands bf16 pre-padded.
// swz: chunked XCD swizzle (z-split launches only). D0/U0.
// ---------------------------------------------------------------------------
__global__ __launch_bounds__(256) void dsamp_mfma3_kernel(
    const unsigned short* __restrict__ Ab, const unsigned short* __restrict__ Xt,
    float* __restrict__ Y, int M, int Kp, int logF, int kchunk,
    int atomic_flag, int swz)
{
    constexpr int PAD = 40;
    __shared__ unsigned short As[2][128 * PAD];
    __shared__ unsigned short Bs[2][128 * PAD];

    int bx = blockIdx.x, by = blockIdx.y, bz = blockIdx.z;
    if (swz) {
        const int gx = gridDim.x, gy = gridDim.y;
        const int total = gx * gy * gridDim.z;
        int bid = bx + gx * (by + gy * bz);
        const int chunk = total >> 3;
        int sid = (bid & 7) * chunk + (bid >> 3);
        bx = sid % gx; sid /= gx;
        by = sid % gy;
        bz = sid / gy;
    }

    const int fmask = (1 << logF) - 1;
    const int m0   = bx * 128;
    const int c0   = by * 128;
    const int kbeg = bz * kchunk;
    int kend = kbeg + kchunk; if (kend > Kp) kend = Kp;
    const int nslab = (kend - kbeg + 31) >> 5;

    const int tid  = threadIdx.x;
    const int lane = tid & 63;
    const int wave = tid >> 6;
    const int wm   = (wave >> 1) * 64;
    const int wn   = (wave & 1) * 64;
    const int l15  = lane & 15;
    const int quad = lane >> 4;

    const int s_row = tid >> 2;        // 0..63
    const int s_k8  = (tid & 3) * 8;   // 0/8/16/24

    f32x4 acc[4][4];
#pragma unroll
    for (int i = 0; i < 4; ++i)
#pragma unroll
        for (int j = 0; j < 4; ++j) acc[i][j] = (f32x4){0.f, 0.f, 0.f, 0.f};

    bf16x8 apre[2], bpre[2];

    auto loadAB = [&](int ko) {
        apre[0] = *(const bf16x8*)(Ab + (size_t)(m0 + s_row)      * Kp + ko + s_k8);
        apre[1] = *(const bf16x8*)(Ab + (size_t)(m0 + s_row + 64) * Kp + ko + s_k8);
        bpre[0] = *(const bf16x8*)(Xt + (size_t)(c0 + s_row)      * Kp + ko + s_k8);
        bpre[1] = *(const bf16x8*)(Xt + (size_t)(c0 + s_row + 64) * Kp + ko + s_k8);
    };
    auto stage = [&](int buf) {
        *(bf16x8*)&As[buf][s_row * PAD + s_k8]        = apre[0];
        *(bf16x8*)&As[buf][(s_row + 64) * PAD + s_k8] = apre[1];
        *(bf16x8*)&Bs[buf][s_row * PAD + s_k8]        = bpre[0];
        *(bf16x8*)&Bs[buf][(s_row + 64) * PAD + s_k8] = bpre[1];
    };

    loadAB(kbeg);
    stage(0);
    __syncthreads();

    for (int s = 0; s < nslab; ++s) {
        const int cur = s & 1;
        const bool more = (s + 1) < nslab;
        if (more) loadAB(kbeg + (s + 1) * 32);

        bf16x8 af[4], bfr[4];
#pragma unroll
        for (int t = 0; t < 4; ++t) {
            af[t]  = *(const bf16x8*)&As[cur][(wm + t * 16 + l15) * PAD + quad * 8];
            bfr[t] = *(const bf16x8*)&Bs[cur][(wn + t * 16 + l15) * PAD + quad * 8];
        }
#pragma unroll
        for (int tm = 0; tm < 4; ++tm)
#pragma unroll
            for (int tn = 0; tn < 4; ++tn)
                acc[tm][tn] = __builtin_amdgcn_mfma_f32_16x16x32_bf16(af[tm], bfr[tn], acc[tm][tn], 0, 0, 0);

        if (more) { stage(cur ^ 1); __syncthreads(); }
    }

#pragma unroll
    for (int tm = 0; tm < 4; ++tm)
#pragma unroll
        for (int tn = 0; tn < 4; ++tn)
#pragma unroll
            for (int reg = 0; reg < 4; ++reg) {
                int m  = m0 + wm + tm * 16 + quad * 4 + reg;
                int cc = c0 + wn + tn * 16 + l15;
                if (m < M) {
                    int bb = cc >> logF, f = cc & fmask;
                    float* dst = Y + (((size_t)bb * M + m) << logF) + f;
                    if (atomic_flag) atomicAdd(dst, acc[tm][tn][reg]);
                    else *dst = acc[tm][tn][reg];
                }
            }
}

// ---------------------------------------------------------------------------
// dsamp_mfma2: A pre-converted bf16 [Mp][Kp]; X fp32 staged to LDS. D1/U1.
// ---------------------------------------------------------------------------
__global__ __launch_bounds__(256) void dsamp_mfma2_kernel(
    const unsigned short* __restrict__ Ap, const float* __restrict__ X,
    float* __restrict__ Y, int M, int K, int Kp, int logF, int kchunk,
    int atomic_flag)
{
    constexpr int PAD = 40;
    __shared__ unsigned short Xs[2][64 * PAD];

    const int fmask = (1 << logF) - 1;
    const int m0   = blockIdx.x * 64;
    const int c0   = blockIdx.y * 64;
    const int kbeg = blockIdx.z * kchunk;
    int kend = kbeg + kchunk; if (kend > K) kend = K;
    const int nslab = (kend - kbeg + 31) >> 5;

    const int tid  = threadIdx.x;
    const int lane = tid & 63;
    const int wave = tid >> 6;
    const int wm   = (wave >> 1) * 32;
    const int wn   = (wave & 1) * 32;
    const int l15  = lane & 15;
    const int quad = lane >> 4;

    const int skk  = tid >> 4;
    const int scg  = (tid & 15) * 4;
    const int cB   = c0 + scg;
    const int xbb  = cB >> logF;
    const int xf   = cB & fmask;
    const size_t xrowbase = (((size_t)xbb * K) << logF) + xf;

    const int mA0 = m0 + wm + l15;
    const int mA1 = mA0 + 16;
    const int kaoff = quad * 8;

    f32x4 acc[2][2];
    acc[0][0] = acc[0][1] = acc[1][0] = acc[1][1] = (f32x4){0.f, 0.f, 0.f, 0.f};

    float4 xn0, xn1;
    bf16x8 ac0, ac1, an0, an1;

    {
        int k = kbeg + skk;
        xn0 = make_float4(0.f, 0.f, 0.f, 0.f);
        if (k < kend) xn0 = *(const float4*)(X + xrowbase + ((size_t)k << logF));
        k = kbeg + 16 + skk;
        xn1 = make_float4(0.f, 0.f, 0.f, 0.f);
        if (k < kend) xn1 = *(const float4*)(X + xrowbase + ((size_t)k << logF));
        int ka = kbeg + kaoff;
        ac0 = *(const bf16x8*)(Ap + (size_t)mA0 * Kp + ka);
        ac1 = *(const bf16x8*)(Ap + (size_t)mA1 * Kp + ka);
        unsigned short* p = &Xs[0][0];
        p[(scg + 0) * PAD + skk] = f2bf(xn0.x);
        p[(scg + 1) * PAD + skk] = f2bf(xn0.y);
        p[(scg + 2) * PAD + skk] = f2bf(xn0.z);
        p[(scg + 3) * PAD + skk] = f2bf(xn0.w);
        int kk1 = 16 + skk;
        p[(scg + 0) * PAD + kk1] = f2bf(xn1.x);
        p[(scg + 1) * PAD + kk1] = f2bf(xn1.y);
        p[(scg + 2) * PAD + kk1] = f2bf(xn1.z);
        p[(scg + 3) * PAD + kk1] = f2bf(xn1.w);
    }
    __syncthreads();

    for (int s = 0; s < nslab; ++s) {
        const int cur = s & 1;
        const bool more = (s + 1 < nslab);
        if (more) {
            int k0 = kbeg + (s + 1) * 32;
            int k = k0 + skk;
            xn0 = make_float4(0.f, 0.f, 0.f, 0.f);
            if (k < kend) xn0 = *(const float4*)(X + xrowbase + ((size_t)k << logF));
            k = k0 + 16 + skk;
            xn1 = make_float4(0.f, 0.f, 0.f, 0.f);
            if (k < kend) xn1 = *(const float4*)(X + xrowbase + ((size_t)k << logF));
            int ka = k0 + kaoff;
            an0 = *(const bf16x8*)(Ap + (size_t)mA0 * Kp + ka);
            an1 = *(const bf16x8*)(Ap + (size_t)mA1 * Kp + ka);
        }
        {
            const unsigned short* p = &Xs[cur][0];
            bf16x8 b0 = *(const bf16x8*)&p[(wn +      l15) * PAD + quad * 8];
            bf16x8 b1 = *(const bf16x8*)&p[(wn + 16 + l15) * PAD + quad * 8];
            acc[0][0] = __builtin_amdgcn_mfma_f32_16x16x32_bf16(ac0, b0, acc[0][0], 0, 0, 0);
            acc[0][1] = __builtin_amdgcn_mfma_f32_16x16x32_bf16(ac0, b1, acc[0][1], 0, 0, 0);
            acc[1][0] = __builtin_amdgcn_mfma_f32_16x16x32_bf16(ac1, b0, acc[1][0], 0, 0, 0);
            acc[1][1] = __builtin_amdgcn_mfma_f32_16x16x32_bf16(ac1, b1, acc[1][1], 0, 0, 0);
        }
        if (more) {
            unsigned short* q = &Xs[cur ^ 1][0];
            q[(scg + 0) * PAD + skk] = f2bf(xn0.x);
            q[(scg + 1) * PAD + skk] = f2bf(xn0.y);
            q[(scg + 2) * PAD + skk] = f2bf(xn0.z);
            q[(scg + 3) * PAD + skk] = f2bf(xn0.w);
            int kk1 = 16 + skk;
            q[(scg + 0) * PAD + kk1] = f2bf(xn1.x);
            q[(scg + 1) * PAD + kk1] = f2bf(xn1.y);
            q[(scg + 2) * PAD + kk1] = f2bf(xn1.z);
            q[(scg + 3) * PAD + kk1] = f2bf(xn1.w);
            __syncthreads();
            ac0 = an0; ac1 = an1;
        }
    }

#pragma unroll
    for (int tm = 0; tm < 2; ++tm)
#pragma unroll
        for (int tn = 0; tn < 2; ++tn)
#pragma unroll
            for (int reg = 0; reg < 4; ++reg) {
                int m  = m0 + wm + tm * 16 + quad * 4 + reg;
                int cc = c0 + wn + tn * 16 + l15;
                if (m < M) {
                    int bb = cc >> logF, f = cc & fmask;
                    float* dst = Y + (((size_t)bb * M + m) << logF) + f;
                    if (atomic_flag) atomicAdd(dst, acc[tm][tn][reg]);
                    else *dst = acc[tm][tn][reg];
                }
            }
}

// ---------------------------------------------------------------------------
// conv_gemm (fp32 gather). e0 only. Grid: (batch, mtile).
// ---------------------------------------------------------------------------
template<int MT, int OT>
__global__ __launch_bounds__(256) void conv_gemm_kernel(
    const float* __restrict__ x, const int* __restrict__ S,
    const float* __restrict__ W, const float* __restrict__ bias,
    float* __restrict__ y, int Nv, int logF, int O, int KF, int KFr,
    int elu_flag)
{
    constexpr int CT = OT / 4;
    constexpr int RT = 256 / CT;
    static_assert(RT * 4 == MT, "tile shape");
    __shared__ float Gs[32][MT];
    __shared__ float Ws[32][OT];

    const int b   = blockIdx.x;
    const int n0  = blockIdx.y * MT;
    const int tid = threadIdx.x;
    const int cx  = tid % CT;
    const int ry  = tid / CT;
    const int r0  = ry * 4;
    const int o0  = cx * 4;
    const int fmask = (1 << logF) - 1;
    const size_t xb = (size_t)b * Nv;

    float acc[4][4];
#pragma unroll
    for (int i = 0; i < 4; ++i)
#pragma unroll
        for (int j = 0; j < 4; ++j) acc[i][j] = 0.f;

    for (int k0 = 0; k0 < KF; k0 += 32) {
        constexpr int GSLOTS = MT * 8;
#pragma unroll
        for (int i = 0; i < GSLOTS / 256; ++i) {
            int idx = tid + i * 256;
            int r   = idx & (MT - 1);
            int jg  = idx / MT;
            int j0  = jg * 4;
            int n   = n0 + r;
            int kf  = k0 + j0;
            float4 v = make_float4(0.f, 0.f, 0.f, 0.f);
            if (n < Nv && kf < KFr) {
                int k   = kf >> logF;
                int f   = kf & fmask;
                int src = S[n * SPK + k];
                v = *(const float4*)(x + ((xb + src) << logF) + f);
            }
            Gs[j0 + 0][r] = v.x; Gs[j0 + 1][r] = v.y;
            Gs[j0 + 2][r] = v.z; Gs[j0 + 3][r] = v.w;
        }
        constexpr int WSLOTS = OT * 8;
#pragma unroll
        for (int i = 0; i < (WSLOTS + 255) / 256; ++i) {
            int idx = tid + i * 256;
            if (WSLOTS >= 256 || idx < WSLOTS) {
                int o  = idx & (OT - 1);
                int jg = idx / OT;
                int j0 = jg * 4;
                float4 v = *(const float4*)(W + (size_t)o * KF + k0 + j0);
                Ws[j0 + 0][o] = v.x; Ws[j0 + 1][o] = v.y;
                Ws[j0 + 2][o] = v.z; Ws[j0 + 3][o] = v.w;
            }
        }
        __syncthreads();
#pragma unroll
        for (int kk = 0; kk < 32; ++kk) {
            float4 g = *(const float4*)&Gs[kk][r0];
            float4 w = *(const float4*)&Ws[kk][o0];
            acc[0][0] += g.x * w.x; acc[0][1] += g.x * w.y; acc[0][2] += g.x * w.z; acc[0][3] += g.x * w.w;
            acc[1][0] += g.y * w.x; acc[1][1] += g.y * w.y; acc[1][2] += g.y * w.z; acc[1][3] += g.y * w.w;
            acc[2][0] += g.z * w.x; acc[2][1] += g.z * w.y; acc[2][2] += g.z * w.z; acc[2][3] += g.z * w.w;
            acc[3][0] += g.w * w.x; acc[3][1] += g.w * w.y; acc[3][2] += g.w * w.z; acc[3][3] += g.w * w.w;
        }
        __syncthreads();
    }

    float4 bv = *(const float4*)(bias + o0);
#pragma unroll
    for (int i = 0; i < 4; ++i) {
        int n = n0 + r0 + i;
        if (n >= Nv) continue;
        float v0 = acc[i][0] + bv.x;
        float v1 = acc[i][1] + bv.y;
        float v2 = acc[i][2] + bv.z;
        float v3 = acc[i][3] + bv.w;
        if (elu_flag) {
            v0 = v0 > 0.f ? v0 : expm1f(v0);
            v1 = v1 > 0.f ? v1 : expm1f(v1);
            v2 = v2 > 0.f ? v2 : expm1f(v2);
            v3 = v3 > 0.f ? v3 : expm1f(v3);
        }
        if (n == Nv - 1) { v0 = v1 = v2 = v3 = 0.f; }
        *(float4*)(y + ((size_t)b * Nv + n) * O + o0) = make_float4(v0, v1, v2, v3);
    }
}

// ---------------------------------------------------------------------------
// VALU down/up-sample (tiny levels 2-3 only). OBF16: emit bf16 output.
// ---------------------------------------------------------------------------
template<int OBF16>
__global__ __launch_bounds__(256) void dsamp_kernel(
    const float* __restrict__ A, const float* __restrict__ X,
    void* __restrict__ Yv, int M, int N, int F)
{
    __shared__ float As[16][68];
    __shared__ float Xs[16][64];

    const int m0  = blockIdx.x * 64;
    const int c0  = blockIdx.y * 64;
    const int tid = threadIdx.x;
    const int tx  = tid & 15;
    const int ty  = tid >> 4;

    float acc[4][4];
#pragma unroll
    for (int i = 0; i < 4; ++i)
#pragma unroll
        for (int j = 0; j < 4; ++j) acc[i][j] = 0.f;

    for (int k0 = 0; k0 < N; k0 += 16) {
#pragma unroll
        for (int p = 0; p < 4; ++p) {
            int r  = (tid >> 4) + p * 16;
            int kk = tid & 15;
            int m  = m0 + r;
            int n  = k0 + kk;
            float v = 0.f;
            if (m < M && n < N) v = A[(size_t)m * N + n];
            As[kk][r] = v;
        }
        {
            int kk = tid >> 4;
            int cc = (tid & 15) * 4;
            int n  = k0 + kk;
            float4 v = make_float4(0.f, 0.f, 0.f, 0.f);
            if (n < N) {
                int c  = c0 + cc;
                int bb = c / F;
                int f  = c - bb * F;
                v = *(const float4*)(X + ((size_t)bb * N + n) * F + f);
            }
            *(float4*)&Xs[kk][cc] = v;
        }
        __syncthreads();
#pragma unroll
        for (int kk = 0; kk < 16; ++kk) {
            float4 av = *(const float4*)&As[kk][ty * 4];
            float4 xv = *(const float4*)&Xs[kk][tx * 4];
            acc[0][0] += av.x * xv.x; acc[0][1] += av.x * xv.y; acc[0][2] += av.x * xv.z; acc[0][3] += av.x * xv.w;
            acc[1][0] += av.y * xv.x; acc[1][1] += av.y * xv.y; acc[1][2] += av.y * xv.z; acc[1][3] += av.y * xv.w;
            acc[2][0] += av.z * xv.x; acc[2][1] += av.z * xv.y; acc[2][2] += av.z * xv.z; acc[2][3] += av.z * xv.w;
            acc[3][0] += av.w * xv.x; acc[3][1] += av.w * xv.y; acc[3][2] += av.w * xv.z; acc[3][3] += av.w * xv.w;
        }
        __syncthreads();
    }

    const int cbase = c0 + tx * 4;
    const int bb = cbase / F;
    const int f  = cbase - bb * F;
#pragma unroll
    for (int i = 0; i < 4; ++i) {
        int m = m0 + ty * 4 + i;
        if (m < M) {
            size_t off = ((size_t)bb * M + m) * F + f;
            if (OBF16) {
                bf16x4 v;
                v[0] = (short)f2bf(acc[i][0]); v[1] = (short)f2bf(acc[i][1]);
                v[2] = (short)f2bf(acc[i][2]); v[3] = (short)f2bf(acc[i][3]);
                *(bf16x4*)((unsigned short*)Yv + off) = v;
            } else {
                *(float4*)((float*)Yv + off) =
                    make_float4(acc[i][0], acc[i][1], acc[i][2], acc[i][3]);
            }
        }
    }
}

// ---------------------------------------------------------------------------
// fc_wave: one 64-lane wave per output element.
// ---------------------------------------------------------------------------
__global__ __launch_bounds__(256) void fc_wave_kernel(
    const float* __restrict__ in, const float* __restrict__ W,
    const float* __restrict__ bias, float* __restrict__ out,
    int In, int O, int dup)
{
    const int gw   = blockIdx.x * 4 + (threadIdx.x >> 6);
    const int lane = threadIdx.x & 63;
    const int b = gw / O;
    const int o = gw - b * O;
    const float* xr = in + (size_t)b * In;
    float acc = 0.f;
    if (dup) {
        const float* wr = W + (size_t)o * (2 * In);
        for (int k = lane; k < In; k += 64)
            acc += xr[k] * (wr[k] + wr[In + k]);
    } else {
        const float* wr = W + (size_t)o * In;
        for (int k = lane; k < In; k += 64)
            acc += xr[k] * wr[k];
    }
#pragma unroll
    for (int off = 32; off > 0; off >>= 1)
        acc += __shfl_down(acc, off, 64);
    if (lane == 0) out[(size_t)b * O + o] = acc + bias[o];
}

// ---------------------------------------------------------------------------
// Transpose-convert: x [b][k][f] fp32 -> xt [c][k] bf16, c = b*F+f, stride Kp.
// ---------------------------------------------------------------------------
__global__ __launch_bounds__(256) void xpose_bf16_kernel(
    const float* __restrict__ x, unsigned short* __restrict__ xt,
    int K, int Kp, int logF)
{
    const int c  = blockIdx.y * 256 + threadIdx.x;
    const int k0 = blockIdx.x * 8;
    const int bb = c >> logF;
    const int f  = c & ((1 << logF) - 1);
    const float* src = x + (((size_t)bb * K) << logF) + f;
    bf16x8 r;
#pragma unroll
    for (int j = 0; j < 8; ++j) {
        int k = k0 + j;
        float v = (k < K) ? src[(size_t)k << logF] : 0.f;
        r[j] = (short)f2bf(v);
    }
    *(bf16x8*)(xt + (size_t)c * Kp + k0) = r;
}

// ---------------------------------------------------------------------------
// Padding / extraction helpers.
// ---------------------------------------------------------------------------
__global__ __launch_bounds__(256) void pad_e0_w_kernel(
    const float* __restrict__ w, float* __restrict__ wp)
{
    int i = blockIdx.x * 256 + threadIdx.x;
    if (i < 1024) {
        int o = i >> 6, kf = i & 63;
        int k = kf >> 2, f = kf & 3;
        wp[i] = (f < 3 && k < 12) ? w[o * 36 + k * 3 + f] : 0.f;
    }
}
__global__ __launch_bounds__(256) void pad_x4_kernel(
    const float* __restrict__ x, float* __restrict__ xp, int n)
{
    int i = blockIdx.x * 256 + threadIdx.x;
    if (i < n) {
        int f = i & 3, nb = i >> 2;
        xp[i] = (f < 3) ? x[nb * 3 + f] : 0.f;
    }
}
__global__ __launch_bounds__(256) void pad_c4_w_kernel(
    const float* __restrict__ w, const float* __restrict__ b,
    float* __restrict__ wp, float* __restrict__ bp)
{
    int i = blockIdx.x * 256 + threadIdx.x;
    if (i < 3072) {
        int o = i / 192;
        wp[i] = (o < 3) ? w[i] : 0.f;
    }
    if (i < 16) bp[i] = (i < 3) ? b[i] : 0.f;
}
__global__ __launch_bounds__(256) void extract_add_kernel(
    const float* __restrict__ cp, const float* __restrict__ t,
    float* __restrict__ o0, float* __restrict__ o1, int n)
{
    int i = blockIdx.x * 256 + threadIdx.x;
    if (i < n) {
        int f = i % 3, nb = i / 3;
        float v = cp[(size_t)nb * 16 + f];
        o0[i] = v;
        o1[i] = v + t[i];
    }
}

// ---------------------------------------------------------------------------

static inline int ilog2(int v) { int l = 0; while ((1 << l) < v) ++l; return l; }

static inline void a_bf16_launch(const float* A, unsigned short* Ap, int M, int K,
                                 int Mp, int Kp, hipStream_t s)
{
    int total = Mp * (Kp >> 3);
    a_bf16_pad_kernel<<<(total + 255) / 256, 256, 0, s>>>(A, Ap, M, K, Kp, total);
}

static inline void dsamp_mfma2_launch(const unsigned short* Ap, const float* X,
                                      float* Y, int M, int K, int Kp, int F,
                                      int ks, hipStream_t s)
{
    int kchunk = (K + ks - 1) / ks;
    kchunk = (kchunk + 31) & ~31;
    int ksz = (K + kchunk - 1) / kchunk;
    dim3 grid((M + 63) / 64, F, ksz);
    dsamp_mfma2_kernel<<<grid, 256, 0, s>>>(Ap, X, Y, M, K, Kp, ilog2(F), kchunk,
                                            ksz > 1 ? 1 : 0);
}

static inline void dsamp_mfma3_launch(const unsigned short* Ab, const unsigned short* Xt,
                                      float* Y, int M, int Kp, int F,
                                      int ks, hipStream_t s)
{
    int slabs = Kp >> 5;
    int kchunk = ((slabs + ks - 1) / ks) * 32;
    int ksz = (Kp + kchunk - 1) / kchunk;
    int gx = (M + 127) / 128, gy = (BATCH * F) / 128;
    int total = gx * gy * ksz;
    int swz = (ksz > 1 && (total & 7) == 0) ? 1 : 0;
    dim3 grid(gx, gy, ksz);
    dsamp_mfma3_kernel<<<grid, 256, 0, s>>>(Ab, Xt, Y, M, Kp, ilog2(F), kchunk,
                                            ksz > 1 ? 1 : 0, swz);
}

template<int OBF16>
static inline void dsamp_launch(const float* A, const float* X, void* Y,
                                int M, int N, int F, hipStream_t s)
{
    dim3 grid((M + 63) / 64, F);
    dsamp_kernel<OBF16><<<grid, 256, 0, s>>>(A, X, Y, M, N, F);
}

extern "C" void kernel_launch(void* const* d_in, const int* in_sizes, int n_in,
                              void* d_out, int out_size, void* d_ws, size_t ws_size,
                              hipStream_t stream)
{
    const float* x_talking = (const float*)d_in[0];
    const float* templ     = (const float*)d_in[1];
    const float* D0 = (const float*)d_in[2];
    const float* U0 = (const float*)d_in[3];
    const float* D1 = (const float*)d_in[4];
    const float* U1 = (const float*)d_in[5];
    const float* D2 = (const float*)d_in[6];
    const float* U2 = (const float*)d_in[7];
    const float* D3 = (const float*)d_in[8];
    const float* U3 = (const float*)d_in[9];
    const float* enc_w0 = (const float*)d_in[10]; const float* enc_b0 = (const float*)d_in[11];
    const float* enc_w1 = (const float*)d_in[12]; const float* enc_b1 = (const float*)d_in[13];
    const float* enc_w2 = (const float*)d_in[14]; const float* enc_b2 = (const float*)d_in[15];
    const float* enc_w3 = (const float*)d_in[16]; const float* enc_b3 = (const float*)d_in[17];
    const float* fc_enc_w = (const float*)d_in[18]; const float* fc_enc_b = (const float*)d_in[19];
    const float* fc_dec_w = (const float*)d_in[20]; const float* fc_dec_b = (const float*)d_in[21];
    const float* dec_w0 = (const float*)d_in[22]; const float* dec_b0 = (const float*)d_in[23];
    const float* dec_w1 = (const float*)d_in[24]; const float* dec_b1 = (const float*)d_in[25];
    const float* dec_w2 = (const float*)d_in[26]; const float* dec_b2 = (const float*)d_in[27];
    const float* dec_w3 = (const float*)d_in[28]; const float* dec_b3 = (const float*)d_in[29];
    const float* dec_w4 = (const float*)d_in[30]; const float* dec_b4 = (const float*)d_in[31];
    const int* S0 = (const int*)d_in[32];
    const int* S1 = (const int*)d_in[33];
    const int* S2 = (const int*)d_in[34];
    const int* S3 = (const int*)d_in[35];

    float* bufA = (float*)d_ws;            // 10,289,152 floats (41.2 MB)
    float* bufB = bufA + 10289152;         // 5,144,576 floats (20.6 MB)

    float* out0 = (float*)d_out;           // 964,608 floats
    float* out1 = out0 + 964608;

    // ---- workspace aliases (lifetimes audited) ----
    unsigned short* Xt_e0 = (unsigned short*)(bufB + 1290240);
    unsigned short* Xt_c2 = (unsigned short*)bufB;
    unsigned short* U0b   = (unsigned short*)(bufB + 1400000);
    unsigned short* Wb_e2 = (unsigned short*)(bufB + 4700000);
    unsigned short* Wb_e3 = (unsigned short*)(bufB + 4715000);
    unsigned short* Wb_c0 = (unsigned short*)(bufB + 4765000);
    unsigned short* Wb_c1 = (unsigned short*)(bufB + 4815000);
    float* xpad   = bufA + 5200000;   // e0 fp32 input padded to F=4 (dead after e0)
    float* WpE0   = bufA + 6600000;   // e0 W fp32 padded [16][64]
    unsigned short* D0b   = (unsigned short*)(bufA + 6700000);
    unsigned short* D1b   = (unsigned short*)(bufA + 9950000);
    unsigned short* U1b   = (unsigned short*)(bufA + 4000000);
    unsigned short* Wb_e1 = (unsigned short*)(bufA + 10160000);
    unsigned short* Wb_c2 = (unsigned short*)(bufA + 10170000);
    unsigned short* Xb_e1   = (unsigned short*)(bufA + 5200000);
    unsigned short* Xb_e2   = (unsigned short*)(bufA + 2000000);
    unsigned short* Xb_c2in = (unsigned short*)(bufA + 2600000);
    unsigned short* Xb_c3 = (unsigned short*)bufB;
    unsigned short* Xb_c4 = (unsigned short*)(bufA + 5200000);
    unsigned short* Wb_c3 = (unsigned short*)bufA;   // written post-u0-convert
    float* WpC4   = bufA + 10000;
    float* BpC4   = bufA + 13500;
    unsigned short* Wb_c4  = (unsigned short*)(bufA + 14000);
    unsigned short* Wfs_c3 = (unsigned short*)(bufA + 16000);  // 6144 ushorts
    unsigned short* Wfs_c4 = (unsigned short*)(bufA + 20000);  // 3072 ushorts

    // Zero only d0's atomic-accumulation target.
    hipMemsetAsync(bufB, 0, (size_t)1287168 * sizeof(float), stream);

    // ---- input-only pre-conversions ----
    pad_e0_w_kernel<<<4, 256, 0, stream>>>(enc_w0, WpE0);
    pad_x4_kernel<<<5024, 256, 0, stream>>>(x_talking, xpad, 1286144);
    a_bf16_launch(D0, D0b, 1257, 5024, 1280, 5024, stream);
    a_bf16_launch(D1, D1b, 315, 1257, 320, 1280, stream);
    f32_to_bf16_kernel<<<3, 256, 0, stream>>>(enc_w1, Wb_e1, 768);
    f32_to_bf16_kernel<<<6, 256, 0, stream>>>(dec_w2, Wb_c2, 1536);
    f32_to_bf16_kernel<<<12, 256, 0, stream>>>(enc_w2, Wb_e2, 3072);
    f32_to_bf16_kernel<<<48, 256, 0, stream>>>(enc_w3, Wb_e3, 12288);
    f32_to_bf16_kernel<<<48, 256, 0, stream>>>(dec_w0, Wb_c0, 12288);
    f32_to_bf16_kernel<<<12, 256, 0, stream>>>(dec_w1, Wb_c1, 3072);

    // ---- encoder ----
    {   // e0: F=4(pad), KF=64 (KFr=48), O=16, fp32 (first-layer precision)
        dim3 grid(BATCH, (5024 + 255) / 256);
        conv_gemm_kernel<256, 16><<<grid, 256, 0, stream>>>(
            xpad, S0, WpE0, enc_b0, bufA, 5024, 2, 16, 64, 48, 1);
    }
    xpose_bf16_kernel<<<dim3(628, 4), 256, 0, stream>>>(bufA, Xt_e0, 5024, 5024, 4);
    dsamp_mfma3_launch(D0b, Xt_e0, bufB, 1257, 5024, 16, 8, stream);            // d0 [atomic ks=8, XCD-swz]
    f32_to_bf16_kernel<<<629, 256, 0, stream>>>(bufB, Xb_e1, 160896);           // d0-out -> bf16
    a_bf16_launch(U0, U0b, 5024, 1257, 5120, 1280, stream);
    a_bf16_launch(U1, U1b, 1257, 315, 1280, 320, stream);
    {   // e1: MFMA conv, F=16, O=32, ELU -> bufA [64,1257,32]
        dim3 grid(BATCH, (1257 + 255) / 256);
        conv_mfma32_kernel<4><<<grid, 256, 0, stream>>>(
            Xb_e1, S1, Wb_e1, enc_b1, bufA, 1257, 192, 1);
    }
    hipMemsetAsync(bufB, 0, (size_t)645120 * sizeof(float), stream);            // zero d1 target
    dsamp_mfma2_launch(D1b, bufA, bufB, 315, 1257, 1280, 32, 8, stream);        // d1 [atomic ks=8]
    f32_to_bf16_kernel<<<315, 256, 0, stream>>>(bufB, Xb_e2, 80640);            // d1-out -> bf16
    {   // e2: wave-MFMA conv, F=32, O=64 -> bufA fp32 [64,315,64]
        dim3 grid((315 + 15) / 16, 64 / 16, BATCH);
        conv_wmfma_kernel<5, 0><<<grid, 64, 0, stream>>>(
            Xb_e2, S2, Wb_e2, enc_b2, bufA, 315, 64, 1, 0);
    }
    dsamp_launch<1>(D2, bufA, bufB, 80, 315, 64, stream);                       // d2 -> bf16
    {   // e3: wave-MFMA conv, F=64, O=128 -> bufA fp32 [64,80,128]
        dim3 grid((80 + 15) / 16, 128 / 16, BATCH);
        conv_wmfma_kernel<6, 0><<<grid, 64, 0, stream>>>(
            (const unsigned short*)bufB, S3, Wb_e3, enc_b3, bufA, 80, 128, 1, 0);
    }
    dsamp_launch<0>(D3, bufA, bufB, 21, 80, 128, stream);                       // d3 fp32

    fc_wave_kernel<<<dim3((BATCH * 128) / 4), 256, 0, stream>>>(bufB, fc_enc_w, fc_enc_b, bufA, 2688, 128, 0);
    fc_wave_kernel<<<dim3((BATCH * 2688) / 4), 256, 0, stream>>>(bufA, fc_dec_w, fc_dec_b, bufB, 128, 2688, 1);

    // ---- decoder ----
    dsamp_launch<1>(U3, bufB, bufA, 80, 21, 128, stream);                       // u3 -> bf16
    {   // c0: wave-MFMA conv, F=128, O=64 -> bufB fp32 [64,80,64]
        dim3 grid((80 + 15) / 16, 64 / 16, BATCH);
        conv_wmfma_kernel<7, 0><<<grid, 64, 0, stream>>>(
            (const unsigned short*)bufA, S3, Wb_c0, dec_b0, bufB, 80, 64, 1, 0);
    }
    dsamp_launch<1>(U2, bufB, bufA, 315, 80, 64, stream);                       // u2 -> bf16
    {   // c1: wave-MFMA conv, F=64, O=32 -> bufB fp32 [64,315,32]
        dim3 grid((315 + 15) / 16, 32 / 16, BATCH);
        conv_wmfma_kernel<6, 0><<<grid, 64, 0, stream>>>(
            (const unsigned short*)bufA, S2, Wb_c1, dec_b1, bufB, 315, 32, 1, 0);
    }
    dsamp_mfma2_launch(U1b, bufB, bufA, 1257, 315, 320, 32, 1, stream);         // u1 -> bufA [64,1257,32]
    f32_to_bf16_kernel<<<1257, 256, 0, stream>>>(bufA, Xb_c2in, 321792);        // u1-out -> bf16
    {   // c2: MFMA conv, F=32, O=32, ELU -> bufA [64,1257,32]
        dim3 grid(BATCH, (1257 + 255) / 256);
        conv_mfma32_kernel<5><<<grid, 256, 0, stream>>>(
            Xb_c2in, S1, Wb_c2, dec_b2, bufA, 1257, 384, 1);
    }
    xpose_bf16_kernel<<<dim3(160, 8), 256, 0, stream>>>(bufA, Xt_c2, 1257, 1280, 5);
    dsamp_mfma3_launch(U0b, Xt_c2, bufA, 5024, 1280, 32, 1, stream);            // u0 [ks=1, plain stores]

    // u0-out (bufA fp32 [64,5024,32]) -> bf16 (all of bufB)
    f32_to_bf16_kernel<<<5024, 256, 0, stream>>>(bufA, Xb_c3, 1286144);
    // c3/c4 weight conversions + frag pre-swizzle (bufA low region dead)
    f32_to_bf16_kernel<<<3, 256, 0, stream>>>(dec_w3, Wb_c3, 768);
    w_frag16_kernel<<<24, 256, 0, stream>>>(Wb_c3, Wfs_c3, 384, 6144);
    pad_c4_w_kernel<<<12, 256, 0, stream>>>(dec_w4, dec_b4, WpC4, BpC4);
    f32_to_bf16_kernel<<<2, 256, 0, stream>>>(WpC4, Wb_c4, 384);
    w_frag16_kernel<<<12, 256, 0, stream>>>(Wb_c4, Wfs_c4, 192, 3072);
    {   // c3: coalesced-gather MFMA conv, F=32, O=16, ELU; bf16 out [XCD-swz]
        dim3 grid(5024 / 16, 1, BATCH);
        conv_cmfma_kernel<5, 1><<<grid, 64, 0, stream>>>(
            Xb_c3, S0, Wfs_c3, dec_b3, (void*)Xb_c4, 5024, 1, 1);
    }
    {   // c4: coalesced-gather MFMA conv, F=16, O=16(pad), identity [XCD-swz]
        dim3 grid(5024 / 16, 1, BATCH);
        conv_cmfma_kernel<4, 0><<<grid, 64, 0, stream>>>(
            Xb_c4, S0, Wfs_c4, BpC4, (void*)bufB, 5024, 0, 1);
    }
    extract_add_kernel<<<(964608 + 255) / 256, 256, 0, stream>>>(bufB, templ, out0, out1, 964608);
}

// Round 7
// 671.745 us; speedup vs baseline: 1.1126x; 1.0674x over previous
//
#include <hip/hip_runtime.h>
#include <cstddef>

// ---------------------------------------------------------------------------
// SpiralAutoencoder on MI355X — round 17:
//  * d0/d1: atomics eliminated — ks=4 K-chunks write per-chunk partial
//    buffers (plain stores), fused reduce4->bf16 kernel sums + converts.
//    (d0's 40MB of cross-XCD atomic RMW was the 52us pin; memsets gone too.)
//  * u0/u1: emit bf16 directly (OBF16 template) — deletes the two largest
//    standalone convert kernels and halves u0's write traffic. u0 gains the
//    bijective XCD swizzle (640 blocks % 8 == 0).
// ---------------------------------------------------------------------------

#define BATCH 64
#define SPK 12  // spiral length

typedef __attribute__((ext_vector_type(8))) short bf16x8;
typedef __attribute__((ext_vector_type(4))) short bf16x4;
typedef __attribute__((ext_vector_type(4))) float f32x4;

__device__ __forceinline__ unsigned short f2bf(float x) {
    union { float f; unsigned int u; } v; v.f = x;
    unsigned int r = v.u + 0x7FFF + ((v.u >> 16) & 1);  // RNE
    return (unsigned short)(r >> 16);
}

// ---------------------------------------------------------------------------
// Flat fp32 -> bf16 convert (8 elems/thread).
// ---------------------------------------------------------------------------
__global__ __launch_bounds__(256) void f32_to_bf16_kernel(
    const float* __restrict__ in, unsigned short* __restrict__ out, int n8)
{
    int i = blockIdx.x * 256 + threadIdx.x;
    if (i < n8) {
        const float* p = in + (size_t)i * 8;
        bf16x8 r;
#pragma unroll
        for (int j = 0; j < 8; ++j) r[j] = (short)f2bf(p[j]);
        *(bf16x8*)(out + (size_t)i * 8) = r;
    }
}

// ---------------------------------------------------------------------------
// Sum 4 fp32 partial buffers (stride ps) -> bf16.
// ---------------------------------------------------------------------------
__global__ __launch_bounds__(256) void reduce4_bf16_kernel(
    const float* __restrict__ P, size_t ps, unsigned short* __restrict__ out,
    int n8)
{
    int i = blockIdx.x * 256 + threadIdx.x;
    if (i < n8) {
        size_t base = (size_t)i * 8;
        bf16x8 r;
#pragma unroll
        for (int j = 0; j < 8; ++j) {
            float v = P[base + j] + P[ps + base + j]
                    + P[2 * ps + base + j] + P[3 * ps + base + j];
            r[j] = (short)f2bf(v);
        }
        *(bf16x8*)(out + base) = r;
    }
}

// ---------------------------------------------------------------------------
// fp32 [M][K] -> bf16 [Mp][Kp] with zero padding (rows >= M, cols >= K).
// ---------------------------------------------------------------------------
__global__ __launch_bounds__(256) void a_bf16_pad_kernel(
    const float* __restrict__ A, unsigned short* __restrict__ Ap,
    int M, int K, int Kp, int total)
{
    int i = blockIdx.x * 256 + threadIdx.x;
    if (i >= total) return;
    int kp8 = Kp >> 3;
    int m = i / kp8;
    int k0 = (i - m * kp8) * 8;
    bf16x8 r;
    if (m < M) {
        const float* src = A + (size_t)m * K + k0;
#pragma unroll
        for (int j = 0; j < 8; ++j) {
            float v = (k0 + j < K) ? src[j] : 0.f;
            r[j] = (short)f2bf(v);
        }
    } else {
#pragma unroll
        for (int j = 0; j < 8; ++j) r[j] = 0;
    }
    *(bf16x8*)(Ap + (size_t)m * Kp + k0) = r;
}

// ---------------------------------------------------------------------------
// W frag pre-swizzle for O=16 convs: Wfs[(s*64+lane)*8+j] =
// Wb[l15*KF + s*32 + quad*8 + j].
// ---------------------------------------------------------------------------
__global__ __launch_bounds__(256) void w_frag16_kernel(
    const unsigned short* __restrict__ Wb, unsigned short* __restrict__ Wfs,
    int KF, int total)
{
    int i = blockIdx.x * 256 + threadIdx.x;
    if (i >= total) return;
    int j    = i & 7;
    int lane = (i >> 3) & 63;
    int s    = i >> 9;
    int l15  = lane & 15;
    int quad = (lane >> 4) & 3;
    Wfs[i] = Wb[l15 * KF + s * 32 + quad * 8 + j];
}

// ---------------------------------------------------------------------------
// conv_cmfma: O=16 spiral conv, row-coalesced gather. c3/c4.
// ---------------------------------------------------------------------------
template<int LOGF, int OBF16>
__global__ __launch_bounds__(64, 4) void conv_cmfma_kernel(
    const unsigned short* __restrict__ x, const int* __restrict__ S,
    const unsigned short* __restrict__ Wfs, const float* __restrict__ bias,
    void* __restrict__ yv, int Nv, int elu_flag, int swz)
{
    constexpr int F     = 1 << LOGF;
    constexpr int KF    = SPK * F;
    constexpr int NS    = KF / 32;
    constexpr int RPADu = (LOGF == 5) ? 40 : 24;
    __shared__ unsigned short Gs[12 * 16 * RPADu];

    const int lane = threadIdx.x;
    const int l15  = lane & 15;
    const int quad = (lane >> 4) & 3;

    int bx = blockIdx.x, bz = blockIdx.z;
    if (swz) {
        const int gx = gridDim.x;
        const int total = gx * gridDim.z;
        int bid = bx + gx * bz;
        const int chunk = total >> 3;
        int sid = (bid & 7) * chunk + (bid >> 3);
        bx = sid % gx;
        bz = sid / gx;
    }
    const int n0 = bx * 16;
    const int b  = bz;
    const size_t xb = (size_t)b * Nv;

    int4 sv;
    {
        int g = lane >> 4; if (g > 2) g = 2;
        int n = n0 + l15; if (n >= Nv) n = 0;
        sv = *(const int4*)(S + n * SPK + g * 4);
    }

    if constexpr (LOGF == 5) {
        const int grow = lane >> 2, gchk = lane & 3;
#pragma unroll
        for (int k = 0; k < 12; ++k) {
            int sel = ((k >> 2) << 4) | grow;
            int comp = k & 3;
            int src = (comp == 0) ? __shfl(sv.x, sel)
                    : (comp == 1) ? __shfl(sv.y, sel)
                    : (comp == 2) ? __shfl(sv.z, sel)
                                  : __shfl(sv.w, sel);
            bf16x8 v = *(const bf16x8*)(x + ((xb + src) << 5) + gchk * 8);
            *(bf16x8*)&Gs[k * 16 * RPADu + grow * RPADu + gchk * 8] = v;
        }
    } else {
        const int khalf = lane >> 5, grow = (lane >> 1) & 15, gchk = lane & 1;
#pragma unroll
        for (int g = 0; g < 6; ++g) {
            int k0 = 2 * g;
            int sel0 = ((k0 >> 2) << 4) | grow;
            int sel1 = (((k0 + 1) >> 2) << 4) | grow;
            int s0 = ((k0 & 3) == 0) ? __shfl(sv.x, sel0) : __shfl(sv.z, sel0);
            int s1 = (((k0 + 1) & 3) == 1) ? __shfl(sv.y, sel1) : __shfl(sv.w, sel1);
            int src = khalf ? s1 : s0;
            int k   = k0 + khalf;
            bf16x8 v = *(const bf16x8*)(x + ((xb + src) << 4) + gchk * 8);
            *(bf16x8*)&Gs[k * 16 * RPADu + grow * RPADu + gchk * 8] = v;
        }
    }

    f32x4 acc0 = (f32x4){0.f, 0.f, 0.f, 0.f};
    f32x4 acc1 = (f32x4){0.f, 0.f, 0.f, 0.f};
#pragma unroll
    for (int s = 0; s < NS; ++s) {
        int kf = s * 32 + quad * 8;
        int k  = kf >> LOGF;
        int f  = kf & (F - 1);
        bf16x8 a = *(const bf16x8*)&Gs[k * 16 * RPADu + l15 * RPADu + f];
        bf16x8 w = *(const bf16x8*)(Wfs + (s * 64 + lane) * 8);
        if (s & 1) acc1 = __builtin_amdgcn_mfma_f32_16x16x32_bf16(a, w, acc1, 0, 0, 0);
        else       acc0 = __builtin_amdgcn_mfma_f32_16x16x32_bf16(a, w, acc0, 0, 0, 0);
    }

    float bv = bias[l15];
#pragma unroll
    for (int reg = 0; reg < 4; ++reg) {
        int nn = n0 + quad * 4 + reg;
        if (nn >= Nv) continue;
        float v = acc0[reg] + acc1[reg] + bv;
        if (elu_flag && v <= 0.f) v = expm1f(v);
        if (nn == Nv - 1) v = 0.f;
        size_t off = ((size_t)b * Nv + nn) * 16 + l15;
        if (OBF16) ((unsigned short*)yv)[off] = f2bf(v);
        else       ((float*)yv)[off] = v;
    }
}

// ---------------------------------------------------------------------------
// conv_wmfma: direct-gather wave kernel (small levels). e2/e3/c0/c1.
// ---------------------------------------------------------------------------
template<int LOGF, int OBF16>
__global__ __launch_bounds__(64) void conv_wmfma_kernel(
    const unsigned short* __restrict__ x, const int* __restrict__ S,
    const unsigned short* __restrict__ Wb, const float* __restrict__ bias,
    void* __restrict__ yv, int Nv, int O, int elu_flag, int swz)
{
    constexpr int F  = 1 << LOGF;
    constexpr int KF = SPK * F;
    constexpr int NS = KF / 32;
    const int lane = threadIdx.x;
    const int l15  = lane & 15;
    const int quad = lane >> 4;

    int bx = blockIdx.x, by = blockIdx.y, bz = blockIdx.z;
    if (swz) {
        const int gx = gridDim.x, gy = gridDim.y;
        const int total = gx * gy * gridDim.z;
        int bid = bx + gx * (by + gy * bz);
        const int chunk = total >> 3;
        int sid = (bid & 7) * chunk + (bid >> 3);
        bx = sid % gx; sid /= gx;
        by = sid % gy;
        bz = sid / gy;
    }

    const int n0   = bx * 16;
    const int o    = by * 16 + l15;
    const int b    = bz;
    const size_t xb = (size_t)b * Nv;

    const int n  = n0 + l15;
    const int ng = (n < Nv) ? n : 0;
    const unsigned short* wrow = Wb + (size_t)o * KF;

    f32x4 acc0 = (f32x4){0.f, 0.f, 0.f, 0.f};
    f32x4 acc1 = (f32x4){0.f, 0.f, 0.f, 0.f};
#pragma unroll
    for (int s = 0; s < NS; ++s) {
        int kf  = s * 32 + quad * 8;
        int k   = kf >> LOGF;
        int f   = kf & (F - 1);
        int src = S[ng * SPK + k];
        bf16x8 a = *(const bf16x8*)(x + ((xb + src) << LOGF) + f);
        bf16x8 w = *(const bf16x8*)(wrow + kf);
        if (s & 1) acc1 = __builtin_amdgcn_mfma_f32_16x16x32_bf16(a, w, acc1, 0, 0, 0);
        else       acc0 = __builtin_amdgcn_mfma_f32_16x16x32_bf16(a, w, acc0, 0, 0, 0);
    }
    float bv = bias[o];
#pragma unroll
    for (int reg = 0; reg < 4; ++reg) {
        int nn = n0 + quad * 4 + reg;
        if (nn >= Nv) continue;
        float v = acc0[reg] + acc1[reg] + bv;
        if (elu_flag && v <= 0.f) v = expm1f(v);
        if (nn == Nv - 1) v = 0.f;
        size_t off = ((size_t)b * Nv + nn) * O + o;
        if (OBF16) ((unsigned short*)yv)[off] = f2bf(v);
        else       ((float*)yv)[off] = v;
    }
}

// ---------------------------------------------------------------------------
// conv_mfma32: O=32 spiral conv via MFMA. W pre-converted bf16. e1/c2.
// ---------------------------------------------------------------------------
template<int LOGF>
__global__ __launch_bounds__(256) void conv_mfma32_kernel(
    const unsigned short* __restrict__ x, const int* __restrict__ S,
    const unsigned short* __restrict__ Wb, const float* __restrict__ bias,
    float* __restrict__ y, int Nv, int KF, int elu_flag)
{
    constexpr int PAD = 40;
    __shared__ unsigned short Gs[2][256 * PAD];

    const int b    = blockIdx.x;
    const int n0   = blockIdx.y * 256;
    const int tid  = threadIdx.x;
    const int lane = tid & 63;
    const int wave = tid >> 6;
    const int wm   = wave * 64;
    const int l15  = lane & 15;
    const int quad = lane >> 4;
    const size_t xb = (size_t)b * Nv;
    const int nslab = KF >> 5;

    f32x4 acc[4][2];
#pragma unroll
    for (int t = 0; t < 4; ++t)
#pragma unroll
        for (int o = 0; o < 2; ++o) acc[t][o] = (f32x4){0.f, 0.f, 0.f, 0.f};

    auto gath = [&](int k0, bf16x8* g) {
        int n = n0 + tid;
        if (n < Nv) {
#pragma unroll
            for (int j = 0; j < 4; ++j) {
                int kf  = k0 + j * 8;
                int k   = kf >> LOGF;
                int f   = kf & ((1 << LOGF) - 1);
                int src = S[n * SPK + k];
                g[j] = *(const bf16x8*)(x + ((xb + src) << LOGF) + f);
            }
        } else {
#pragma unroll
            for (int j = 0; j < 4; ++j)
#pragma unroll
                for (int e = 0; e < 8; ++e) g[j][e] = 0;
        }
    };
    auto put = [&](int buf, const bf16x8* g) {
#pragma unroll
        for (int j = 0; j < 4; ++j)
            *(bf16x8*)&Gs[buf][tid * PAD + j * 8] = g[j];
    };
    auto wfrag = [&](int k0, int o16) {
        return *(const bf16x8*)(Wb + (size_t)(o16 * 16 + l15) * KF + k0 + quad * 8);
    };

    bf16x8 gcur[4], gnext[4];
    gath(0, gcur);
    put(0, gcur);
    __syncthreads();

    for (int s = 0; s < nslab; ++s) {
        const int cur = s & 1;
        const bool more = (s + 1) < nslab;
        if (more) gath((s + 1) * 32, gnext);
        bf16x8 wf0 = wfrag(s * 32, 0);
        bf16x8 wf1 = wfrag(s * 32, 1);
#pragma unroll
        for (int t = 0; t < 4; ++t) {
            bf16x8 a = *(const bf16x8*)&Gs[cur][(wm + t * 16 + l15) * PAD + quad * 8];
            acc[t][0] = __builtin_amdgcn_mfma_f32_16x16x32_bf16(a, wf0, acc[t][0], 0, 0, 0);
            acc[t][1] = __builtin_amdgcn_mfma_f32_16x16x32_bf16(a, wf1, acc[t][1], 0, 0, 0);
        }
        if (more) {
            put(cur ^ 1, gnext);
            __syncthreads();
        }
    }

    float bv0 = bias[l15];
    float bv1 = bias[16 + l15];
#pragma unroll
    for (int t = 0; t < 4; ++t)
#pragma unroll
        for (int reg = 0; reg < 4; ++reg) {
            int n = n0 + wm + t * 16 + quad * 4 + reg;
            if (n >= Nv) continue;
            float v0 = acc[t][0][reg] + bv0;
            float v1 = acc[t][1][reg] + bv1;
            if (elu_flag) {
                if (v0 <= 0.f) v0 = expm1f(v0);
                if (v1 <= 0.f) v1 = expm1f(v1);
            }
            if (n == Nv - 1) { v0 = 0.f; v1 = 0.f; }
            size_t off = ((size_t)b * Nv + n) * 32 + l15;
            y[off]      = v0;
            y[off + 16] = v1;
        }
}

// ---------------------------------------------------------------------------
// dsamp_mfma3: 128x128 tile MFMA resample, both operands bf16 pre-padded.
// OBF16: bf16 output. pstride: per-z-chunk partial-buffer stride (elements);
// atomic_flag: atomicAdd mode. swz: chunked XCD swizzle. D0/U0.
// ---------------------------------------------------------------------------
template<int OBF16>
__global__ __launch_bounds__(256) void dsamp_mfma3_kernel(
    const unsigned short* __restrict__ Ab, const unsigned short* __restrict__ Xt,
    void* __restrict__ Yv, int M, int Kp, int logF, int kchunk,
    int atomic_flag, int swz, size_t pstride)
{
    constexpr int PAD = 40;
    __shared__ unsigned short As[2][128 * PAD];
    __shared__ unsigned short Bs[2][128 * PAD];

    int bx = blockIdx.x, by = blockIdx.y, bz = blockIdx.z;
    if (swz) {
        const int gx = gridDim.x, gy = gridDim.y;
        const int total = gx * gy * gridDim.z;
        int bid = bx + gx * (by + gy * bz);
        const int chunk = total >> 3;
        int sid = (bid & 7) * chunk + (bid >> 3);
        bx = sid % gx; sid /= gx;
        by = sid % gy;
        bz = sid / gy;
    }

    const int fmask = (1 << logF) - 1;
    const int m0   = bx * 128;
    const int c0   = by * 128;
    const int kbeg = bz * kchunk;
    int kend = kbeg + kchunk; if (kend > Kp) kend = Kp;
    const int nslab = (kend - kbeg + 31) >> 5;
    const size_t zoff = (size_t)bz * pstride;

    const int tid  = threadIdx.x;
    const int lane = tid & 63;
    const int wave = tid >> 6;
    const int wm   = (wave >> 1) * 64;
    const int wn   = (wave & 1) * 64;
    const int l15  = lane & 15;
    const int quad = lane >> 4;

    const int s_row = tid >> 2;
    const int s_k8  = (tid & 3) * 8;

    f32x4 acc[4][4];
#pragma unroll
    for (int i = 0; i < 4; ++i)
#pragma unroll
        for (int j = 0; j < 4; ++j) acc[i][j] = (f32x4){0.f, 0.f, 0.f, 0.f};

    bf16x8 apre[2], bpre[2];

    auto loadAB = [&](int ko) {
        apre[0] = *(const bf16x8*)(Ab + (size_t)(m0 + s_row)      * Kp + ko + s_k8);
        apre[1] = *(const bf16x8*)(Ab + (size_t)(m0 + s_row + 64) * Kp + ko + s_k8);
        bpre[0] = *(const bf16x8*)(Xt + (size_t)(c0 + s_row)      * Kp + ko + s_k8);
        bpre[1] = *(const bf16x8*)(Xt + (size_t)(c0 + s_row + 64) * Kp + ko + s_k8);
    };
    auto stage = [&](int buf) {
        *(bf16x8*)&As[buf][s_row * PAD + s_k8]        = apre[0];
        *(bf16x8*)&As[buf][(s_row + 64) * PAD + s_k8] = apre[1];
        *(bf16x8*)&Bs[buf][s_row * PAD + s_k8]        = bpre[0];
        *(bf16x8*)&Bs[buf][(s_row + 64) * PAD + s_k8] = bpre[1];
    };

    loadAB(kbeg);
    stage(0);
    __syncthreads();

    for (int s = 0; s < nslab; ++s) {
        const int cur = s & 1;
        const bool more = (s + 1) < nslab;
        if (more) loadAB(kbeg + (s + 1) * 32);

        bf16x8 af[4], bfr[4];
#pragma unroll
        for (int t = 0; t < 4; ++t) {
            af[t]  = *(const bf16x8*)&As[cur][(wm + t * 16 + l15) * PAD + quad * 8];
            bfr[t] = *(const bf16x8*)&Bs[cur][(wn + t * 16 + l15) * PAD + quad * 8];
        }
#pragma unroll
        for (int tm = 0; tm < 4; ++tm)
#pragma unroll
            for (int tn = 0; tn < 4; ++tn)
                acc[tm][tn] = __builtin_amdgcn_mfma_f32_16x16x32_bf16(af[tm], bfr[tn], acc[tm][tn], 0, 0, 0);

        if (more) { stage(cur ^ 1); __syncthreads(); }
    }

#pragma unroll
    for (int tm = 0; tm < 4; ++tm)
#pragma unroll
        for (int tn = 0; tn < 4; ++tn)
#pragma unroll
            for (int reg = 0; reg < 4; ++reg) {
                int m  = m0 + wm + tm * 16 + quad * 4 + reg;
                int cc = c0 + wn + tn * 16 + l15;
                if (m < M) {
                    int bb = cc >> logF, f = cc & fmask;
                    size_t off = zoff + (((size_t)bb * M + m) << logF) + f;
                    float v = acc[tm][tn][reg];
                    if (OBF16)            ((unsigned short*)Yv)[off] = f2bf(v);
                    else if (atomic_flag) atomicAdd((float*)Yv + off, v);
                    else                  ((float*)Yv)[off] = v;
                }
            }
}

// ---------------------------------------------------------------------------
// dsamp_mfma2: A pre-converted bf16 [Mp][Kp]; X fp32 staged to LDS. D1/U1.
// OBF16 / pstride semantics as dsamp_mfma3.
// ---------------------------------------------------------------------------
template<int OBF16>
__global__ __launch_bounds__(256) void dsamp_mfma2_kernel(
    const unsigned short* __restrict__ Ap, const float* __restrict__ X,
    void* __restrict__ Yv, int M, int K, int Kp, int logF, int kchunk,
    int atomic_flag, size_t pstride)
{
    constexpr int PAD = 40;
    __shared__ unsigned short Xs[2][64 * PAD];

    const int fmask = (1 << logF) - 1;
    const int m0   = blockIdx.x * 64;
    const int c0   = blockIdx.y * 64;
    const int kbeg = blockIdx.z * kchunk;
    int kend = kbeg + kchunk; if (kend > K) kend = K;
    const int nslab = (kend - kbeg + 31) >> 5;
    const size_t zoff = (size_t)blockIdx.z * pstride;

    const int tid  = threadIdx.x;
    const int lane = tid & 63;
    const int wave = tid >> 6;
    const int wm   = (wave >> 1) * 32;
    const int wn   = (wave & 1) * 32;
    const int l15  = lane & 15;
    const int quad = lane >> 4;

    const int skk  = tid >> 4;
    const int scg  = (tid & 15) * 4;
    const int cB   = c0 + scg;
    const int xbb  = cB >> logF;
    const int xf   = cB & fmask;
    const size_t xrowbase = (((size_t)xbb * K) << logF) + xf;

    const int mA0 = m0 + wm + l15;
    const int mA1 = mA0 + 16;
    const int kaoff = quad * 8;

    f32x4 acc[2][2];
    acc[0][0] = acc[0][1] = acc[1][0] = acc[1][1] = (f32x4){0.f, 0.f, 0.f, 0.f};

    float4 xn0, xn1;
    bf16x8 ac0, ac1, an0, an1;

    {
        int k = kbeg + skk;
        xn0 = make_float4(0.f, 0.f, 0.f, 0.f);
        if (k < kend) xn0 = *(const float4*)(X + xrowbase + ((size_t)k << logF));
        k = kbeg + 16 + skk;
        xn1 = make_float4(0.f, 0.f, 0.f, 0.f);
        if (k < kend) xn1 = *(const float4*)(X + xrowbase + ((size_t)k << logF));
        int ka = kbeg + kaoff;
        ac0 = *(const bf16x8*)(Ap + (size_t)mA0 * Kp + ka);
        ac1 = *(const bf16x8*)(Ap + (size_t)mA1 * Kp + ka);
        unsigned short* p = &Xs[0][0];
        p[(scg + 0) * PAD + skk] = f2bf(xn0.x);
        p[(scg + 1) * PAD + skk] = f2bf(xn0.y);
        p[(scg + 2) * PAD + skk] = f2bf(xn0.z);
        p[(scg + 3) * PAD + skk] = f2bf(xn0.w);
        int kk1 = 16 + skk;
        p[(scg + 0) * PAD + kk1] = f2bf(xn1.x);
        p[(scg + 1) * PAD + kk1] = f2bf(xn1.y);
        p[(scg + 2) * PAD + kk1] = f2bf(xn1.z);
        p[(scg + 3) * PAD + kk1] = f2bf(xn1.w);
    }
    __syncthreads();

    for (int s = 0; s < nslab; ++s) {
        const int cur = s & 1;
        const bool more = (s + 1 < nslab);
        if (more) {
            int k0 = kbeg + (s + 1) * 32;
            int k = k0 + skk;
            xn0 = make_float4(0.f, 0.f, 0.f, 0.f);
            if (k < kend) xn0 = *(const float4*)(X + xrowbase + ((size_t)k << logF));
            k = k0 + 16 + skk;
            xn1 = make_float4(0.f, 0.f, 0.f, 0.f);
            if (k < kend) xn1 = *(const float4*)(X + xrowbase + ((size_t)k << logF));
            int ka = k0 + kaoff;
            an0 = *(const bf16x8*)(Ap + (size_t)mA0 * Kp + ka);
            an1 = *(const bf16x8*)(Ap + (size_t)mA1 * Kp + ka);
        }
        {
            const unsigned short* p = &Xs[cur][0];
            bf16x8 b0 = *(const bf16x8*)&p[(wn +      l15) * PAD + quad * 8];
            bf16x8 b1 = *(const bf16x8*)&p[(wn + 16 + l15) * PAD + quad * 8];
            acc[0][0] = __builtin_amdgcn_mfma_f32_16x16x32_bf16(ac0, b0, acc[0][0], 0, 0, 0);
            acc[0][1] = __builtin_amdgcn_mfma_f32_16x16x32_bf16(ac0, b1, acc[0][1], 0, 0, 0);
            acc[1][0] = __builtin_amdgcn_mfma_f32_16x16x32_bf16(ac1, b0, acc[1][0], 0, 0, 0);
            acc[1][1] = __builtin_amdgcn_mfma_f32_16x16x32_bf16(ac1, b1, acc[1][1], 0, 0, 0);
        }
        if (more) {
            unsigned short* q = &Xs[cur ^ 1][0];
            q[(scg + 0) * PAD + skk] = f2bf(xn0.x);
            q[(scg + 1) * PAD + skk] = f2bf(xn0.y);
            q[(scg + 2) * PAD + skk] = f2bf(xn0.z);
            q[(scg + 3) * PAD + skk] = f2bf(xn0.w);
            int kk1 = 16 + skk;
            q[(scg + 0) * PAD + kk1] = f2bf(xn1.x);
            q[(scg + 1) * PAD + kk1] = f2bf(xn1.y);
            q[(scg + 2) * PAD + kk1] = f2bf(xn1.z);
            q[(scg + 3) * PAD + kk1] = f2bf(xn1.w);
            __syncthreads();
            ac0 = an0; ac1 = an1;
        }
    }

#pragma unroll
    for (int tm = 0; tm < 2; ++tm)
#pragma unroll
        for (int tn = 0; tn < 2; ++tn)
#pragma unroll
            for (int reg = 0; reg < 4; ++reg) {
                int m  = m0 + wm + tm * 16 + quad * 4 + reg;
                int cc = c0 + wn + tn * 16 + l15;
                if (m < M) {
                    int bb = cc >> logF, f = cc & fmask;
                    size_t off = zoff + (((size_t)bb * M + m) << logF) + f;
                    float v = acc[tm][tn][reg];
                    if (OBF16)            ((unsigned short*)Yv)[off] = f2bf(v);
                    else if (atomic_flag) atomicAdd((float*)Yv + off, v);
                    else                  ((float*)Yv)[off] = v;
                }
            }
}

// ---------------------------------------------------------------------------
// conv_gemm (fp32 gather). e0 only. Grid: (batch, mtile).
// ---------------------------------------------------------------------------
template<int MT, int OT>
__global__ __launch_bounds__(256) void conv_gemm_kernel(
    const float* __restrict__ x, const int* __restrict__ S,
    const float* __restrict__ W, const float* __restrict__ bias,
    float* __restrict__ y, int Nv, int logF, int O, int KF, int KFr,
    int elu_flag)
{
    constexpr int CT = OT / 4;
    constexpr int RT = 256 / CT;
    static_assert(RT * 4 == MT, "tile shape");
    __shared__ float Gs[32][MT];
    __shared__ float Ws[32][OT];

    const int b   = blockIdx.x;
    const int n0  = blockIdx.y * MT;
    const int tid = threadIdx.x;
    const int cx  = tid % CT;
    const int ry  = tid / CT;
    const int r0  = ry * 4;
    const int o0  = cx * 4;
    const int fmask = (1 << logF) - 1;
    const size_t xb = (size_t)b * Nv;

    float acc[4][4];
#pragma unroll
    for (int i = 0; i < 4; ++i)
#pragma unroll
        for (int j = 0; j < 4; ++j) acc[i][j] = 0.f;

    for (int k0 = 0; k0 < KF; k0 += 32) {
        constexpr int GSLOTS = MT * 8;
#pragma unroll
        for (int i = 0; i < GSLOTS / 256; ++i) {
            int idx = tid + i * 256;
            int r   = idx & (MT - 1);
            int jg  = idx / MT;
            int j0  = jg * 4;
            int n   = n0 + r;
            int kf  = k0 + j0;
            float4 v = make_float4(0.f, 0.f, 0.f, 0.f);
            if (n < Nv && kf < KFr) {
                int k   = kf >> logF;
                int f   = kf & fmask;
                int src = S[n * SPK + k];
                v = *(const float4*)(x + ((xb + src) << logF) + f);
            }
            Gs[j0 + 0][r] = v.x; Gs[j0 + 1][r] = v.y;
            Gs[j0 + 2][r] = v.z; Gs[j0 + 3][r] = v.w;
        }
        constexpr int WSLOTS = OT * 8;
#pragma unroll
        for (int i = 0; i < (WSLOTS + 255) / 256; ++i) {
            int idx = tid + i * 256;
            if (WSLOTS >= 256 || idx < WSLOTS) {
                int o  = idx & (OT - 1);
                int jg = idx / OT;
                int j0 = jg * 4;
                float4 v = *(const float4*)(W + (size_t)o * KF + k0 + j0);
                Ws[j0 + 0][o] = v.x; Ws[j0 + 1][o] = v.y;
                Ws[j0 + 2][o] = v.z; Ws[j0 + 3][o] = v.w;
            }
        }
        __syncthreads();
#pragma unroll
        for (int kk = 0; kk < 32; ++kk) {
            float4 g = *(const float4*)&Gs[kk][r0];
            float4 w = *(const float4*)&Ws[kk][o0];
            acc[0][0] += g.x * w.x; acc[0][1] += g.x * w.y; acc[0][2] += g.x * w.z; acc[0][3] += g.x * w.w;
            acc[1][0] += g.y * w.x; acc[1][1] += g.y * w.y; acc[1][2] += g.y * w.z; acc[1][3] += g.y * w.w;
            acc[2][0] += g.z * w.x; acc[2][1] += g.z * w.y; acc[2][2] += g.z * w.z; acc[2][3] += g.z * w.w;
            acc[3][0] += g.w * w.x; acc[3][1] += g.w * w.y; acc[3][2] += g.w * w.z; acc[3][3] += g.w * w.w;
        }
        __syncthreads();
    }

    float4 bv = *(const float4*)(bias + o0);
#pragma unroll
    for (int i = 0; i < 4; ++i) {
        int n = n0 + r0 + i;
        if (n >= Nv) continue;
        float v0 = acc[i][0] + bv.x;
        float v1 = acc[i][1] + bv.y;
        float v2 = acc[i][2] + bv.z;
        float v3 = acc[i][3] + bv.w;
        if (elu_flag) {
            v0 = v0 > 0.f ? v0 : expm1f(v0);
            v1 = v1 > 0.f ? v1 : expm1f(v1);
            v2 = v2 > 0.f ? v2 : expm1f(v2);
            v3 = v3 > 0.f ? v3 : expm1f(v3);
        }
        if (n == Nv - 1) { v0 = v1 = v2 = v3 = 0.f; }
        *(float4*)(y + ((size_t)b * Nv + n) * O + o0) = make_float4(v0, v1, v2, v3);
    }
}

// ---------------------------------------------------------------------------
// VALU down/up-sample (tiny levels 2-3 only). OBF16: emit bf16 output.
// ---------------------------------------------------------------------------
template<int OBF16>
__global__ __launch_bounds__(256) void dsamp_kernel(
    const float* __restrict__ A, const float* __restrict__ X,
    void* __restrict__ Yv, int M, int N, int F)
{
    __shared__ float As[16][68];
    __shared__ float Xs[16][64];

    const int m0  = blockIdx.x * 64;
    const int c0  = blockIdx.y * 64;
    const int tid = threadIdx.x;
    const int tx  = tid & 15;
    const int ty  = tid >> 4;

    float acc[4][4];
#pragma unroll
    for (int i = 0; i < 4; ++i)
#pragma unroll
        for (int j = 0; j < 4; ++j) acc[i][j] = 0.f;

    for (int k0 = 0; k0 < N; k0 += 16) {
#pragma unroll
        for (int p = 0; p < 4; ++p) {
            int r  = (tid >> 4) + p * 16;
            int kk = tid & 15;
            int m  = m0 + r;
            int n  = k0 + kk;
            float v = 0.f;
            if (m < M && n < N) v = A[(size_t)m * N + n];
            As[kk][r] = v;
        }
        {
            int kk = tid >> 4;
            int cc = (tid & 15) * 4;
            int n  = k0 + kk;
            float4 v = make_float4(0.f, 0.f, 0.f, 0.f);
            if (n < N) {
                int c  = c0 + cc;
                int bb = c / F;
                int f  = c - bb * F;
                v = *(const float4*)(X + ((size_t)bb * N + n) * F + f);
            }
            *(float4*)&Xs[kk][cc] = v;
        }
        __syncthreads();
#pragma unroll
        for (int kk = 0; kk < 16; ++kk) {
            float4 av = *(const float4*)&As[kk][ty * 4];
            float4 xv = *(const float4*)&Xs[kk][tx * 4];
            acc[0][0] += av.x * xv.x; acc[0][1] += av.x * xv.y; acc[0][2] += av.x * xv.z; acc[0][3] += av.x * xv.w;
            acc[1][0] += av.y * xv.x; acc[1][1] += av.y * xv.y; acc[1][2] += av.y * xv.z; acc[1][3] += av.y * xv.w;
            acc[2][0] += av.z * xv.x; acc[2][1] += av.z * xv.y; acc[2][2] += av.z * xv.z; acc[2][3] += av.z * xv.w;
            acc[3][0] += av.w * xv.x; acc[3][1] += av.w * xv.y; acc[3][2] += av.w * xv.z; acc[3][3] += av.w * xv.w;
        }
        __syncthreads();
    }

    const int cbase = c0 + tx * 4;
    const int bb = cbase / F;
    const int f  = cbase - bb * F;
#pragma unroll
    for (int i = 0; i < 4; ++i) {
        int m = m0 + ty * 4 + i;
        if (m < M) {
            size_t off = ((size_t)bb * M + m) * F + f;
            if (OBF16) {
                bf16x4 v;
                v[0] = (short)f2bf(acc[i][0]); v[1] = (short)f2bf(acc[i][1]);
                v[2] = (short)f2bf(acc[i][2]); v[3] = (short)f2bf(acc[i][3]);
                *(bf16x4*)((unsigned short*)Yv + off) = v;
            } else {
                *(float4*)((float*)Yv + off) =
                    make_float4(acc[i][0], acc[i][1], acc[i][2], acc[i][3]);
            }
        }
    }
}

// ---------------------------------------------------------------------------
// fc_wave: one 64-lane wave per output element.
// ---------------------------------------------------------------------------
__global__ __launch_bounds__(256) void fc_wave_kernel(
    const float* __restrict__ in, const float* __restrict__ W,
    const float* __restrict__ bias, float* __restrict__ out,
    int In, int O, int dup)
{
    const int gw   = blockIdx.x * 4 + (threadIdx.x >> 6);
    const int lane = threadIdx.x & 63;
    const int b = gw / O;
    const int o = gw - b * O;
    const float* xr = in + (size_t)b * In;
    float acc = 0.f;
    if (dup) {
        const float* wr = W + (size_t)o * (2 * In);
        for (int k = lane; k < In; k += 64)
            acc += xr[k] * (wr[k] + wr[In + k]);
    } else {
        const float* wr = W + (size_t)o * In;
        for (int k = lane; k < In; k += 64)
            acc += xr[k] * wr[k];
    }
#pragma unroll
    for (int off = 32; off > 0; off >>= 1)
        acc += __shfl_down(acc, off, 64);
    if (lane == 0) out[(size_t)b * O + o] = acc + bias[o];
}

// ---------------------------------------------------------------------------
// Transpose-convert: x [b][k][f] fp32 -> xt [c][k] bf16, c = b*F+f, stride Kp.
// ---------------------------------------------------------------------------
__global__ __launch_bounds__(256) void xpose_bf16_kernel(
    const float* __restrict__ x, unsigned short* __restrict__ xt,
    int K, int Kp, int logF)
{
    const int c  = blockIdx.y * 256 + threadIdx.x;
    const int k0 = blockIdx.x * 8;
    const int bb = c >> logF;
    const int f  = c & ((1 << logF) - 1);
    const float* src = x + (((size_t)bb * K) << logF) + f;
    bf16x8 r;
#pragma unroll
    for (int j = 0; j < 8; ++j) {
        int k = k0 + j;
        float v = (k < K) ? src[(size_t)k << logF] : 0.f;
        r[j] = (short)f2bf(v);
    }
    *(bf16x8*)(xt + (size_t)c * Kp + k0) = r;
}

// ---------------------------------------------------------------------------
// Padding / extraction helpers.
// ---------------------------------------------------------------------------
__global__ __launch_bounds__(256) void pad_e0_w_kernel(
    const float* __restrict__ w, float* __restrict__ wp)
{
    int i = blockIdx.x * 256 + threadIdx.x;
    if (i < 1024) {
        int o = i >> 6, kf = i & 63;
        int k = kf >> 2, f = kf & 3;
        wp[i] = (f < 3 && k < 12) ? w[o * 36 + k * 3 + f] : 0.f;
    }
}
__global__ __launch_bounds__(256) void pad_x4_kernel(
    const float* __restrict__ x, float* __restrict__ xp, int n)
{
    int i = blockIdx.x * 256 + threadIdx.x;
    if (i < n) {
        int f = i & 3, nb = i >> 2;
        xp[i] = (f < 3) ? x[nb * 3 + f] : 0.f;
    }
}
__global__ __launch_bounds__(256) void pad_c4_w_kernel(
    const float* __restrict__ w, const float* __restrict__ b,
    float* __restrict__ wp, float* __restrict__ bp)
{
    int i = blockIdx.x * 256 + threadIdx.x;
    if (i < 3072) {
        int o = i / 192;
        wp[i] = (o < 3) ? w[i] : 0.f;
    }
    if (i < 16) bp[i] = (i < 3) ? b[i] : 0.f;
}
__global__ __launch_bounds__(256) void extract_add_kernel(
    const float* __restrict__ cp, const float* __restrict__ t,
    float* __restrict__ o0, float* __restrict__ o1, int n)
{
    int i = blockIdx.x * 256 + threadIdx.x;
    if (i < n) {
        int f = i % 3, nb = i / 3;
        float v = cp[(size_t)nb * 16 + f];
        o0[i] = v;
        o1[i] = v + t[i];
    }
}

// ---------------------------------------------------------------------------

static inline int ilog2(int v) { int l = 0; while ((1 << l) < v) ++l; return l; }

static inline void a_bf16_launch(const float* A, unsigned short* Ap, int M, int K,
                                 int Mp, int Kp, hipStream_t s)
{
    int total = Mp * (Kp >> 3);
    a_bf16_pad_kernel<<<(total + 255) / 256, 256, 0, s>>>(A, Ap, M, K, Kp, total);
}

template<int OBF16>
static inline void dsamp_mfma2_launch(const unsigned short* Ap, const float* X,
                                      void* Y, int M, int K, int Kp, int F,
                                      int ks, int partial, hipStream_t s)
{
    int kchunk = (K + ks - 1) / ks;
    kchunk = (kchunk + 31) & ~31;
    int ksz = (K + kchunk - 1) / kchunk;
    int atomic = (ksz > 1 && !partial) ? 1 : 0;
    size_t pstride = (partial && ksz > 1) ? (size_t)BATCH * M * F : 0;
    dim3 grid((M + 63) / 64, F, ksz);
    dsamp_mfma2_kernel<OBF16><<<grid, 256, 0, s>>>(Ap, X, Y, M, K, Kp, ilog2(F),
                                                   kchunk, atomic, pstride);
}

template<int OBF16>
static inline void dsamp_mfma3_launch(const unsigned short* Ab, const unsigned short* Xt,
                                      void* Y, int M, int Kp, int F,
                                      int ks, int partial, hipStream_t s)
{
    int slabs = Kp >> 5;
    int kchunk = ((slabs + ks - 1) / ks) * 32;
    int ksz = (Kp + kchunk - 1) / kchunk;
    int gx = (M + 127) / 128, gy = (BATCH * F) / 128;
    int total = gx * gy * ksz;
    int swz = ((total & 7) == 0) ? 1 : 0;
    int atomic = (ksz > 1 && !partial) ? 1 : 0;
    size_t pstride = (partial && ksz > 1) ? (size_t)BATCH * M * F : 0;
    dim3 grid(gx, gy, ksz);
    dsamp_mfma3_kernel<OBF16><<<grid, 256, 0, s>>>(Ab, Xt, Y, M, Kp, ilog2(F),
                                                   kchunk, atomic, swz, pstride);
}

template<int OBF16>
static inline void dsamp_launch(const float* A, const float* X, void* Y,
                                int M, int N, int F, hipStream_t s)
{
    dim3 grid((M + 63) / 64, F);
    dsamp_kernel<OBF16><<<grid, 256, 0, s>>>(A, X, Y, M, N, F);
}

extern "C" void kernel_launch(void* const* d_in, const int* in_sizes, int n_in,
                              void* d_out, int out_size, void* d_ws, size_t ws_size,
                              hipStream_t stream)
{
    const float* x_talking = (const float*)d_in[0];
    const float* templ     = (const float*)d_in[1];
    const float* D0 = (const float*)d_in[2];
    const float* U0 = (const float*)d_in[3];
    const float* D1 = (const float*)d_in[4];
    const float* U1 = (const float*)d_in[5];
    const float* D2 = (const float*)d_in[6];
    const float* U2 = (const float*)d_in[7];
    const float* D3 = (const float*)d_in[8];
    const float* U3 = (const float*)d_in[9];
    const float* enc_w0 = (const float*)d_in[10]; const float* enc_b0 = (const float*)d_in[11];
    const float* enc_w1 = (const float*)d_in[12]; const float* enc_b1 = (const float*)d_in[13];
    const float* enc_w2 = (const float*)d_in[14]; const float* enc_b2 = (const float*)d_in[15];
    const float* enc_w3 = (const float*)d_in[16]; const float* enc_b3 = (const float*)d_in[17];
    const float* fc_enc_w = (const float*)d_in[18]; const float* fc_enc_b = (const float*)d_in[19];
    const float* fc_dec_w = (const float*)d_in[20]; const float* fc_dec_b = (const float*)d_in[21];
    const float* dec_w0 = (const float*)d_in[22]; const float* dec_b0 = (const float*)d_in[23];
    const float* dec_w1 = (const float*)d_in[24]; const float* dec_b1 = (const float*)d_in[25];
    const float* dec_w2 = (const float*)d_in[26]; const float* dec_b2 = (const float*)d_in[27];
    const float* dec_w3 = (const float*)d_in[28]; const float* dec_b3 = (const float*)d_in[29];
    const float* dec_w4 = (const float*)d_in[30]; const float* dec_b4 = (const float*)d_in[31];
    const int* S0 = (const int*)d_in[32];
    const int* S1 = (const int*)d_in[33];
    const int* S2 = (const int*)d_in[34];
    const int* S3 = (const int*)d_in[35];

    float* bufA = (float*)d_ws;            // 10,289,152 floats (41.2 MB)
    float* bufB = bufA + 10289152;         // 5,144,576 floats (20.6 MB)

    float* out0 = (float*)d_out;           // 964,608 floats
    float* out1 = out0 + 964608;

    // ---- workspace aliases (lifetimes audited per stream order) ----
    // Encoder:
    //   e0-out: bufA[0..5.14M) fp32 -> dead after xpose
    //   Pd0 (d0 partials, 4x1,287,168): bufA[0..5,148,672) -> dead after reduce
    //   Xb_e1: bufA+5,200,000 (bf16) -> dead after e1
    //   Pd1 (d1 partials, 4x645,120): bufA+5,200,000..7,780,480 -> dead after reduce
    //   Xb_e2: bufA+2,000,000 (bf16)
    // Decoder:
    //   Xb_c2in: bufA+2,600,000 (bf16, u1 direct out)
    //   u0-out (bf16 [64,5024,32]): bufA[0..5.14M) = Xb_c3n
    //   Xb_c4: bufA+5,200,000..7,772,288
    //   c3/c4 weights: bufA+7,800,000.. (D0b/Pd1 dead)
    unsigned short* Xt_e0 = (unsigned short*)(bufB + 1290240);
    unsigned short* Xt_c2 = (unsigned short*)bufB;
    unsigned short* U0b   = (unsigned short*)(bufB + 1400000);
    unsigned short* Wb_e2 = (unsigned short*)(bufB + 4700000);
    unsigned short* Wb_e3 = (unsigned short*)(bufB + 4715000);
    unsigned short* Wb_c0 = (unsigned short*)(bufB + 4765000);
    unsigned short* Wb_c1 = (unsigned short*)(bufB + 4815000);
    float* xpad   = bufA + 5200000;
    float* WpE0   = bufA + 6600000;
    unsigned short* D0b   = (unsigned short*)(bufA + 6700000);
    unsigned short* D1b   = (unsigned short*)(bufA + 9950000);
    unsigned short* U1b   = (unsigned short*)(bufA + 4000000);
    unsigned short* Wb_e1 = (unsigned short*)(bufA + 10160000);
    unsigned short* Wb_c2 = (unsigned short*)(bufA + 10170000);
    float*          Pd0   = bufA;                                // d0 partials
    unsigned short* Xb_e1 = (unsigned short*)(bufA + 5200000);
    float*          Pd1   = bufA + 5200000;                      // d1 partials
    unsigned short* Xb_e2   = (unsigned short*)(bufA + 2000000);
    unsigned short* Xb_c2in = (unsigned short*)(bufA + 2600000);
    unsigned short* Xb_c3n  = (unsigned short*)bufA;             // u0 bf16 out
    unsigned short* Xb_c4   = (unsigned short*)(bufA + 5200000);
    unsigned short* Wb_c3  = (unsigned short*)(bufA + 7800000);
    unsigned short* Wfs_c3 = (unsigned short*)(bufA + 7805000);
    float* WpC4   = bufA + 7810000;
    float* BpC4   = bufA + 7813500;
    unsigned short* Wb_c4  = (unsigned short*)(bufA + 7814000);
    unsigned short* Wfs_c4 = (unsigned short*)(bufA + 7818000);

    // ---- input-only pre-conversions ----
    pad_e0_w_kernel<<<4, 256, 0, stream>>>(enc_w0, WpE0);
    pad_x4_kernel<<<5024, 256, 0, stream>>>(x_talking, xpad, 1286144);
    a_bf16_launch(D0, D0b, 1257, 5024, 1280, 5024, stream);
    a_bf16_launch(D1, D1b, 315, 1257, 320, 1280, stream);
    f32_to_bf16_kernel<<<3, 256, 0, stream>>>(enc_w1, Wb_e1, 768);
    f32_to_bf16_kernel<<<6, 256, 0, stream>>>(dec_w2, Wb_c2, 1536);
    f32_to_bf16_kernel<<<12, 256, 0, stream>>>(enc_w2, Wb_e2, 3072);
    f32_to_bf16_kernel<<<48, 256, 0, stream>>>(enc_w3, Wb_e3, 12288);
    f32_to_bf16_kernel<<<48, 256, 0, stream>>>(dec_w0, Wb_c0, 12288);
    f32_to_bf16_kernel<<<12, 256, 0, stream>>>(dec_w1, Wb_c1, 3072);

    // ---- encoder ----
    {   // e0: F=4(pad), KF=64 (KFr=48), O=16, fp32 (first-layer precision)
        dim3 grid(BATCH, (5024 + 255) / 256);
        conv_gemm_kernel<256, 16><<<grid, 256, 0, stream>>>(
            xpad, S0, WpE0, enc_b0, bufA, 5024, 2, 16, 64, 48, 1);
    }
    xpose_bf16_kernel<<<dim3(628, 4), 256, 0, stream>>>(bufA, Xt_e0, 5024, 5024, 4);
    // d0: ks=4, partial buffers (no atomics, no memset) -> Pd0
    dsamp_mfma3_launch<0>(D0b, Xt_e0, Pd0, 1257, 5024, 16, 4, 1, stream);
    reduce4_bf16_kernel<<<629, 256, 0, stream>>>(Pd0, 1287168, Xb_e1, 160896);
    a_bf16_launch(U0, U0b, 5024, 1257, 5120, 1280, stream);
    a_bf16_launch(U1, U1b, 1257, 315, 1280, 320, stream);
    {   // e1: MFMA conv, F=16, O=32, ELU -> bufA [64,1257,32] fp32
        dim3 grid(BATCH, (1257 + 255) / 256);
        conv_mfma32_kernel<4><<<grid, 256, 0, stream>>>(
            Xb_e1, S1, Wb_e1, enc_b1, bufA, 1257, 192, 1);
    }
    // d1: ks=4, partial buffers -> Pd1; reduce -> Xb_e2
    dsamp_mfma2_launch<0>(D1b, bufA, Pd1, 315, 1257, 1280, 32, 4, 1, stream);
    reduce4_bf16_kernel<<<315, 256, 0, stream>>>(Pd1, 645120, Xb_e2, 80640);
    {   // e2: wave-MFMA conv, F=32, O=64 -> bufA fp32 [64,315,64]
        dim3 grid((315 + 15) / 16, 64 / 16, BATCH);
        conv_wmfma_kernel<5, 0><<<grid, 64, 0, stream>>>(
            Xb_e2, S2, Wb_e2, enc_b2, bufA, 315, 64, 1, 0);
    }
    dsamp_launch<1>(D2, bufA, bufB, 80, 315, 64, stream);                       // d2 -> bf16
    {   // e3: wave-MFMA conv, F=64, O=128 -> bufA fp32 [64,80,128]
        dim3 grid((80 + 15) / 16, 128 / 16, BATCH);
        conv_wmfma_kernel<6, 0><<<grid, 64, 0, stream>>>(
            (const unsigned short*)bufB, S3, Wb_e3, enc_b3, bufA, 80, 128, 1, 0);
    }
    dsamp_launch<0>(D3, bufA, bufB, 21, 80, 128, stream);                       // d3 fp32

    fc_wave_kernel<<<dim3((BATCH * 128) / 4), 256, 0, stream>>>(bufB, fc_enc_w, fc_enc_b, bufA, 2688, 128, 0);
    fc_wave_kernel<<<dim3((BATCH * 2688) / 4), 256, 0, stream>>>(bufA, fc_dec_w, fc_dec_b, bufB, 128, 2688, 1);

    // ---- decoder ----
    dsamp_launch<1>(U3, bufB, bufA, 80, 21, 128, stream);                       // u3 -> bf16
    {   // c0: wave-MFMA conv, F=128, O=64 -> bufB fp32 [64,80,64]
        dim3 grid((80 + 15) / 16, 64 / 16, BATCH);
        conv_wmfma_kernel<7, 0><<<grid, 64, 0, stream>>>(
            (const unsigned short*)bufA, S3, Wb_c0, dec_b0, bufB, 80, 64, 1, 0);
    }
    dsamp_launch<1>(U2, bufB, bufA, 315, 80, 64, stream);                       // u2 -> bf16
    {   // c1: wave-MFMA conv, F=64, O=32 -> bufB fp32 [64,315,32]
        dim3 grid((315 + 15) / 16, 32 / 16, BATCH);
        conv_wmfma_kernel<6, 0><<<grid, 64, 0, stream>>>(
            (const unsigned short*)bufA, S2, Wb_c1, dec_b1, bufB, 315, 32, 1, 0);
    }
    // u1: ks=1, bf16 direct out -> Xb_c2in (convert kernel eliminated)
    dsamp_mfma2_launch<1>(U1b, bufB, Xb_c2in, 1257, 315, 320, 32, 1, 0, stream);
    {   // c2: MFMA conv, F=32, O=32, ELU -> bufA [64,1257,32] fp32
        dim3 grid(BATCH, (1257 + 255) / 256);
        conv_mfma32_kernel<5><<<grid, 256, 0, stream>>>(
            Xb_c2in, S1, Wb_c2, dec_b2, bufA, 1257, 384, 1);
    }
    xpose_bf16_kernel<<<dim3(160, 8), 256, 0, stream>>>(bufA, Xt_c2, 1257, 1280, 5);
    // u0: ks=1, bf16 direct out -> Xb_c3n (convert eliminated), XCD-swz
    dsamp_mfma3_launch<1>(U0b, Xt_c2, Xb_c3n, 5024, 1280, 32, 1, 0, stream);

    // c3/c4 weight conversions + frag pre-swizzle (region dead)
    f32_to_bf16_kernel<<<3, 256, 0, stream>>>(dec_w3, Wb_c3, 768);
    w_frag16_kernel<<<24, 256, 0, stream>>>(Wb_c3, Wfs_c3, 384, 6144);
    pad_c4_w_kernel<<<12, 256, 0, stream>>>(dec_w4, dec_b4, WpC4, BpC4);
    f32_to_bf16_kernel<<<2, 256, 0, stream>>>(WpC4, Wb_c4, 384);
    w_frag16_kernel<<<12, 256, 0, stream>>>(Wb_c4, Wfs_c4, 192, 3072);
    {   // c3: coalesced-gather MFMA conv, F=32, O=16, ELU; bf16 out [XCD-swz]
        dim3 grid(5024 / 16, 1, BATCH);
        conv_cmfma_kernel<5, 1><<<grid, 64, 0, stream>>>(
            Xb_c3n, S0, Wfs_c3, dec_b3, (void*)Xb_c4, 5024, 1, 1);
    }
    {   // c4: coalesced-gather MFMA conv, F=16, O=16(pad), identity [XCD-swz]
        dim3 grid(5024 / 16, 1, BATCH);
        conv_cmfma_kernel<4, 0><<<grid, 64, 0, stream>>>(
            Xb_c4, S0, Wfs_c4, BpC4, (void*)bufB, 5024, 0, 1);
    }
    extract_add_kernel<<<(964608 + 255) / 256, 256, 0, stream>>>(bufB, templ, out0, out1, 964608);
}

// Round 8
// 646.997 us; speedup vs baseline: 1.1552x; 1.0383x over previous
//
#include <hip/hip_runtime.h>
#include <cstddef>

// ---------------------------------------------------------------------------
// SpiralAutoencoder on MI355X — round 18:
//  * d2/u2 (dsamp_kernel, d2 was 49us at 4% occupancy / 128 blocks) ->
//    dsamp_mfma2 MFMA path: d2 ks=4 partials (512 blocks) + reduceN->bf16;
//    u2 ks=1 bf16 direct. D2/U2 pre-padded to bf16.
//  * d0: ks=4 -> ks=5 (kchunk 1024): per-XCD L2 slice 4.6->3.9MB (fits),
//    400 blocks. reduceN generalized to 5 parts. Xb_e1 relocated to bufB[0]
//    (partial #5 would overlap its old slot).
// ---------------------------------------------------------------------------

#define BATCH 64
#define SPK 12  // spiral length

typedef __attribute__((ext_vector_type(8))) short bf16x8;
typedef __attribute__((ext_vector_type(4))) short bf16x4;
typedef __attribute__((ext_vector_type(4))) float f32x4;

__device__ __forceinline__ unsigned short f2bf(float x) {
    union { float f; unsigned int u; } v; v.f = x;
    unsigned int r = v.u + 0x7FFF + ((v.u >> 16) & 1);  // RNE
    return (unsigned short)(r >> 16);
}

// ---------------------------------------------------------------------------
// Flat fp32 -> bf16 convert (8 elems/thread).
// ---------------------------------------------------------------------------
__global__ __launch_bounds__(256) void f32_to_bf16_kernel(
    const float* __restrict__ in, unsigned short* __restrict__ out, int n8)
{
    int i = blockIdx.x * 256 + threadIdx.x;
    if (i < n8) {
        const float* p = in + (size_t)i * 8;
        bf16x8 r;
#pragma unroll
        for (int j = 0; j < 8; ++j) r[j] = (short)f2bf(p[j]);
        *(bf16x8*)(out + (size_t)i * 8) = r;
    }
}

// ---------------------------------------------------------------------------
// Sum nparts fp32 partial buffers (stride ps) -> bf16.
// ---------------------------------------------------------------------------
__global__ __launch_bounds__(256) void reducep_bf16_kernel(
    const float* __restrict__ P, size_t ps, unsigned short* __restrict__ out,
    int n8, int nparts)
{
    int i = blockIdx.x * 256 + threadIdx.x;
    if (i < n8) {
        size_t base = (size_t)i * 8;
        bf16x8 r;
#pragma unroll
        for (int j = 0; j < 8; ++j) {
            float v = P[base + j];
            for (int p = 1; p < nparts; ++p) v += P[(size_t)p * ps + base + j];
            r[j] = (short)f2bf(v);
        }
        *(bf16x8*)(out + base) = r;
    }
}

// ---------------------------------------------------------------------------
// fp32 [M][K] -> bf16 [Mp][Kp] with zero padding (rows >= M, cols >= K).
// ---------------------------------------------------------------------------
__global__ __launch_bounds__(256) void a_bf16_pad_kernel(
    const float* __restrict__ A, unsigned short* __restrict__ Ap,
    int M, int K, int Kp, int total)
{
    int i = blockIdx.x * 256 + threadIdx.x;
    if (i >= total) return;
    int kp8 = Kp >> 3;
    int m = i / kp8;
    int k0 = (i - m * kp8) * 8;
    bf16x8 r;
    if (m < M) {
        const float* src = A + (size_t)m * K + k0;
#pragma unroll
        for (int j = 0; j < 8; ++j) {
            float v = (k0 + j < K) ? src[j] : 0.f;
            r[j] = (short)f2bf(v);
        }
    } else {
#pragma unroll
        for (int j = 0; j < 8; ++j) r[j] = 0;
    }
    *(bf16x8*)(Ap + (size_t)m * Kp + k0) = r;
}

// ---------------------------------------------------------------------------
// W frag pre-swizzle for O=16 convs.
// ---------------------------------------------------------------------------
__global__ __launch_bounds__(256) void w_frag16_kernel(
    const unsigned short* __restrict__ Wb, unsigned short* __restrict__ Wfs,
    int KF, int total)
{
    int i = blockIdx.x * 256 + threadIdx.x;
    if (i >= total) return;
    int j    = i & 7;
    int lane = (i >> 3) & 63;
    int s    = i >> 9;
    int l15  = lane & 15;
    int quad = (lane >> 4) & 3;
    Wfs[i] = Wb[l15 * KF + s * 32 + quad * 8 + j];
}

// ---------------------------------------------------------------------------
// conv_cmfma: O=16 spiral conv, row-coalesced gather. c3/c4.
// ---------------------------------------------------------------------------
template<int LOGF, int OBF16>
__global__ __launch_bounds__(64, 4) void conv_cmfma_kernel(
    const unsigned short* __restrict__ x, const int* __restrict__ S,
    const unsigned short* __restrict__ Wfs, const float* __restrict__ bias,
    void* __restrict__ yv, int Nv, int elu_flag, int swz)
{
    constexpr int F     = 1 << LOGF;
    constexpr int KF    = SPK * F;
    constexpr int NS    = KF / 32;
    constexpr int RPADu = (LOGF == 5) ? 40 : 24;
    __shared__ unsigned short Gs[12 * 16 * RPADu];

    const int lane = threadIdx.x;
    const int l15  = lane & 15;
    const int quad = (lane >> 4) & 3;

    int bx = blockIdx.x, bz = blockIdx.z;
    if (swz) {
        const int gx = gridDim.x;
        const int total = gx * gridDim.z;
        int bid = bx + gx * bz;
        const int chunk = total >> 3;
        int sid = (bid & 7) * chunk + (bid >> 3);
        bx = sid % gx;
        bz = sid / gx;
    }
    const int n0 = bx * 16;
    const int b  = bz;
    const size_t xb = (size_t)b * Nv;

    int4 sv;
    {
        int g = lane >> 4; if (g > 2) g = 2;
        int n = n0 + l15; if (n >= Nv) n = 0;
        sv = *(const int4*)(S + n * SPK + g * 4);
    }

    if constexpr (LOGF == 5) {
        const int grow = lane >> 2, gchk = lane & 3;
#pragma unroll
        for (int k = 0; k < 12; ++k) {
            int sel = ((k >> 2) << 4) | grow;
            int comp = k & 3;
            int src = (comp == 0) ? __shfl(sv.x, sel)
                    : (comp == 1) ? __shfl(sv.y, sel)
                    : (comp == 2) ? __shfl(sv.z, sel)
                                  : __shfl(sv.w, sel);
            bf16x8 v = *(const bf16x8*)(x + ((xb + src) << 5) + gchk * 8);
            *(bf16x8*)&Gs[k * 16 * RPADu + grow * RPADu + gchk * 8] = v;
        }
    } else {
        const int khalf = lane >> 5, grow = (lane >> 1) & 15, gchk = lane & 1;
#pragma unroll
        for (int g = 0; g < 6; ++g) {
            int k0 = 2 * g;
            int sel0 = ((k0 >> 2) << 4) | grow;
            int sel1 = (((k0 + 1) >> 2) << 4) | grow;
            int s0 = ((k0 & 3) == 0) ? __shfl(sv.x, sel0) : __shfl(sv.z, sel0);
            int s1 = (((k0 + 1) & 3) == 1) ? __shfl(sv.y, sel1) : __shfl(sv.w, sel1);
            int src = khalf ? s1 : s0;
            int k   = k0 + khalf;
            bf16x8 v = *(const bf16x8*)(x + ((xb + src) << 4) + gchk * 8);
            *(bf16x8*)&Gs[k * 16 * RPADu + grow * RPADu + gchk * 8] = v;
        }
    }

    f32x4 acc0 = (f32x4){0.f, 0.f, 0.f, 0.f};
    f32x4 acc1 = (f32x4){0.f, 0.f, 0.f, 0.f};
#pragma unroll
    for (int s = 0; s < NS; ++s) {
        int kf = s * 32 + quad * 8;
        int k  = kf >> LOGF;
        int f  = kf & (F - 1);
        bf16x8 a = *(const bf16x8*)&Gs[k * 16 * RPADu + l15 * RPADu + f];
        bf16x8 w = *(const bf16x8*)(Wfs + (s * 64 + lane) * 8);
        if (s & 1) acc1 = __builtin_amdgcn_mfma_f32_16x16x32_bf16(a, w, acc1, 0, 0, 0);
        else       acc0 = __builtin_amdgcn_mfma_f32_16x16x32_bf16(a, w, acc0, 0, 0, 0);
    }

    float bv = bias[l15];
#pragma unroll
    for (int reg = 0; reg < 4; ++reg) {
        int nn = n0 + quad * 4 + reg;
        if (nn >= Nv) continue;
        float v = acc0[reg] + acc1[reg] + bv;
        if (elu_flag && v <= 0.f) v = expm1f(v);
        if (nn == Nv - 1) v = 0.f;
        size_t off = ((size_t)b * Nv + nn) * 16 + l15;
        if (OBF16) ((unsigned short*)yv)[off] = f2bf(v);
        else       ((float*)yv)[off] = v;
    }
}

// ---------------------------------------------------------------------------
// conv_wmfma: direct-gather wave kernel (small levels). e2/e3/c0/c1.
// ---------------------------------------------------------------------------
template<int LOGF, int OBF16>
__global__ __launch_bounds__(64) void conv_wmfma_kernel(
    const unsigned short* __restrict__ x, const int* __restrict__ S,
    const unsigned short* __restrict__ Wb, const float* __restrict__ bias,
    void* __restrict__ yv, int Nv, int O, int elu_flag, int swz)
{
    constexpr int F  = 1 << LOGF;
    constexpr int KF = SPK * F;
    constexpr int NS = KF / 32;
    const int lane = threadIdx.x;
    const int l15  = lane & 15;
    const int quad = lane >> 4;

    int bx = blockIdx.x, by = blockIdx.y, bz = blockIdx.z;
    if (swz) {
        const int gx = gridDim.x, gy = gridDim.y;
        const int total = gx * gy * gridDim.z;
        int bid = bx + gx * (by + gy * bz);
        const int chunk = total >> 3;
        int sid = (bid & 7) * chunk + (bid >> 3);
        bx = sid % gx; sid /= gx;
        by = sid % gy;
        bz = sid / gy;
    }

    const int n0   = bx * 16;
    const int o    = by * 16 + l15;
    const int b    = bz;
    const size_t xb = (size_t)b * Nv;

    const int n  = n0 + l15;
    const int ng = (n < Nv) ? n : 0;
    const unsigned short* wrow = Wb + (size_t)o * KF;

    f32x4 acc0 = (f32x4){0.f, 0.f, 0.f, 0.f};
    f32x4 acc1 = (f32x4){0.f, 0.f, 0.f, 0.f};
#pragma unroll
    for (int s = 0; s < NS; ++s) {
        int kf  = s * 32 + quad * 8;
        int k   = kf >> LOGF;
        int f   = kf & (F - 1);
        int src = S[ng * SPK + k];
        bf16x8 a = *(const bf16x8*)(x + ((xb + src) << LOGF) + f);
        bf16x8 w = *(const bf16x8*)(wrow + kf);
        if (s & 1) acc1 = __builtin_amdgcn_mfma_f32_16x16x32_bf16(a, w, acc1, 0, 0, 0);
        else       acc0 = __builtin_amdgcn_mfma_f32_16x16x32_bf16(a, w, acc0, 0, 0, 0);
    }
    float bv = bias[o];
#pragma unroll
    for (int reg = 0; reg < 4; ++reg) {
        int nn = n0 + quad * 4 + reg;
        if (nn >= Nv) continue;
        float v = acc0[reg] + acc1[reg] + bv;
        if (elu_flag && v <= 0.f) v = expm1f(v);
        if (nn == Nv - 1) v = 0.f;
        size_t off = ((size_t)b * Nv + nn) * O + o;
        if (OBF16) ((unsigned short*)yv)[off] = f2bf(v);
        else       ((float*)yv)[off] = v;
    }
}

// ---------------------------------------------------------------------------
// conv_mfma32: O=32 spiral conv via MFMA. W pre-converted bf16. e1/c2.
// ---------------------------------------------------------------------------
template<int LOGF>
__global__ __launch_bounds__(256) void conv_mfma32_kernel(
    const unsigned short* __restrict__ x, const int* __restrict__ S,
    const unsigned short* __restrict__ Wb, const float* __restrict__ bias,
    float* __restrict__ y, int Nv, int KF, int elu_flag)
{
    constexpr int PAD = 40;
    __shared__ unsigned short Gs[2][256 * PAD];

    const int b    = blockIdx.x;
    const int n0   = blockIdx.y * 256;
    const int tid  = threadIdx.x;
    const int lane = tid & 63;
    const int wave = tid >> 6;
    const int wm   = wave * 64;
    const int l15  = lane & 15;
    const int quad = lane >> 4;
    const size_t xb = (size_t)b * Nv;
    const int nslab = KF >> 5;

    f32x4 acc[4][2];
#pragma unroll
    for (int t = 0; t < 4; ++t)
#pragma unroll
        for (int o = 0; o < 2; ++o) acc[t][o] = (f32x4){0.f, 0.f, 0.f, 0.f};

    auto gath = [&](int k0, bf16x8* g) {
        int n = n0 + tid;
        if (n < Nv) {
#pragma unroll
            for (int j = 0; j < 4; ++j) {
                int kf  = k0 + j * 8;
                int k   = kf >> LOGF;
                int f   = kf & ((1 << LOGF) - 1);
                int src = S[n * SPK + k];
                g[j] = *(const bf16x8*)(x + ((xb + src) << LOGF) + f);
            }
        } else {
#pragma unroll
            for (int j = 0; j < 4; ++j)
#pragma unroll
                for (int e = 0; e < 8; ++e) g[j][e] = 0;
        }
    };
    auto put = [&](int buf, const bf16x8* g) {
#pragma unroll
        for (int j = 0; j < 4; ++j)
            *(bf16x8*)&Gs[buf][tid * PAD + j * 8] = g[j];
    };
    auto wfrag = [&](int k0, int o16) {
        return *(const bf16x8*)(Wb + (size_t)(o16 * 16 + l15) * KF + k0 + quad * 8);
    };

    bf16x8 gcur[4], gnext[4];
    gath(0, gcur);
    put(0, gcur);
    __syncthreads();

    for (int s = 0; s < nslab; ++s) {
        const int cur = s & 1;
        const bool more = (s + 1) < nslab;
        if (more) gath((s + 1) * 32, gnext);
        bf16x8 wf0 = wfrag(s * 32, 0);
        bf16x8 wf1 = wfrag(s * 32, 1);
#pragma unroll
        for (int t = 0; t < 4; ++t) {
            bf16x8 a = *(const bf16x8*)&Gs[cur][(wm + t * 16 + l15) * PAD + quad * 8];
            acc[t][0] = __builtin_amdgcn_mfma_f32_16x16x32_bf16(a, wf0, acc[t][0], 0, 0, 0);
            acc[t][1] = __builtin_amdgcn_mfma_f32_16x16x32_bf16(a, wf1, acc[t][1], 0, 0, 0);
        }
        if (more) {
            put(cur ^ 1, gnext);
            __syncthreads();
        }
    }

    float bv0 = bias[l15];
    float bv1 = bias[16 + l15];
#pragma unroll
    for (int t = 0; t < 4; ++t)
#pragma unroll
        for (int reg = 0; reg < 4; ++reg) {
            int n = n0 + wm + t * 16 + quad * 4 + reg;
            if (n >= Nv) continue;
            float v0 = acc[t][0][reg] + bv0;
            float v1 = acc[t][1][reg] + bv1;
            if (elu_flag) {
                if (v0 <= 0.f) v0 = expm1f(v0);
                if (v1 <= 0.f) v1 = expm1f(v1);
            }
            if (n == Nv - 1) { v0 = 0.f; v1 = 0.f; }
            size_t off = ((size_t)b * Nv + n) * 32 + l15;
            y[off]      = v0;
            y[off + 16] = v1;
        }
}

// ---------------------------------------------------------------------------
// dsamp_mfma3: 128x128 tile MFMA resample, both operands bf16 pre-padded.
// OBF16 / pstride / atomic_flag / swz as before. D0/U0.
// ---------------------------------------------------------------------------
template<int OBF16>
__global__ __launch_bounds__(256) void dsamp_mfma3_kernel(
    const unsigned short* __restrict__ Ab, const unsigned short* __restrict__ Xt,
    void* __restrict__ Yv, int M, int Kp, int logF, int kchunk,
    int atomic_flag, int swz, size_t pstride)
{
    constexpr int PAD = 40;
    __shared__ unsigned short As[2][128 * PAD];
    __shared__ unsigned short Bs[2][128 * PAD];

    int bx = blockIdx.x, by = blockIdx.y, bz = blockIdx.z;
    if (swz) {
        const int gx = gridDim.x, gy = gridDim.y;
        const int total = gx * gy * gridDim.z;
        int bid = bx + gx * (by + gy * bz);
        const int chunk = total >> 3;
        int sid = (bid & 7) * chunk + (bid >> 3);
        bx = sid % gx; sid /= gx;
        by = sid % gy;
        bz = sid / gy;
    }

    const int fmask = (1 << logF) - 1;
    const int m0   = bx * 128;
    const int c0   = by * 128;
    const int kbeg = bz * kchunk;
    int kend = kbeg + kchunk; if (kend > Kp) kend = Kp;
    const int nslab = (kend - kbeg + 31) >> 5;
    const size_t zoff = (size_t)bz * pstride;

    const int tid  = threadIdx.x;
    const int lane = tid & 63;
    const int wave = tid >> 6;
    const int wm   = (wave >> 1) * 64;
    const int wn   = (wave & 1) * 64;
    const int l15  = lane & 15;
    const int quad = lane >> 4;

    const int s_row = tid >> 2;
    const int s_k8  = (tid & 3) * 8;

    f32x4 acc[4][4];
#pragma unroll
    for (int i = 0; i < 4; ++i)
#pragma unroll
        for (int j = 0; j < 4; ++j) acc[i][j] = (f32x4){0.f, 0.f, 0.f, 0.f};

    bf16x8 apre[2], bpre[2];

    auto loadAB = [&](int ko) {
        apre[0] = *(const bf16x8*)(Ab + (size_t)(m0 + s_row)      * Kp + ko + s_k8);
        apre[1] = *(const bf16x8*)(Ab + (size_t)(m0 + s_row + 64) * Kp + ko + s_k8);
        bpre[0] = *(const bf16x8*)(Xt + (size_t)(c0 + s_row)      * Kp + ko + s_k8);
        bpre[1] = *(const bf16x8*)(Xt + (size_t)(c0 + s_row + 64) * Kp + ko + s_k8);
    };
    auto stage = [&](int buf) {
        *(bf16x8*)&As[buf][s_row * PAD + s_k8]        = apre[0];
        *(bf16x8*)&As[buf][(s_row + 64) * PAD + s_k8] = apre[1];
        *(bf16x8*)&Bs[buf][s_row * PAD + s_k8]        = bpre[0];
        *(bf16x8*)&Bs[buf][(s_row + 64) * PAD + s_k8] = bpre[1];
    };

    loadAB(kbeg);
    stage(0);
    __syncthreads();

    for (int s = 0; s < nslab; ++s) {
        const int cur = s & 1;
        const bool more = (s + 1) < nslab;
        if (more) loadAB(kbeg + (s + 1) * 32);

        bf16x8 af[4], bfr[4];
#pragma unroll
        for (int t = 0; t < 4; ++t) {
            af[t]  = *(const bf16x8*)&As[cur][(wm + t * 16 + l15) * PAD + quad * 8];
            bfr[t] = *(const bf16x8*)&Bs[cur][(wn + t * 16 + l15) * PAD + quad * 8];
        }
#pragma unroll
        for (int tm = 0; tm < 4; ++tm)
#pragma unroll
            for (int tn = 0; tn < 4; ++tn)
                acc[tm][tn] = __builtin_amdgcn_mfma_f32_16x16x32_bf16(af[tm], bfr[tn], acc[tm][tn], 0, 0, 0);

        if (more) { stage(cur ^ 1); __syncthreads(); }
    }

#pragma unroll
    for (int tm = 0; tm < 4; ++tm)
#pragma unroll
        for (int tn = 0; tn < 4; ++tn)
#pragma unroll
            for (int reg = 0; reg < 4; ++reg) {
                int m  = m0 + wm + tm * 16 + quad * 4 + reg;
                int cc = c0 + wn + tn * 16 + l15;
                if (m < M) {
                    int bb = cc >> logF, f = cc & fmask;
                    size_t off = zoff + (((size_t)bb * M + m) << logF) + f;
                    float v = acc[tm][tn][reg];
                    if (OBF16)            ((unsigned short*)Yv)[off] = f2bf(v);
                    else if (atomic_flag) atomicAdd((float*)Yv + off, v);
                    else                  ((float*)Yv)[off] = v;
                }
            }
}

// ---------------------------------------------------------------------------
// dsamp_mfma2: A pre-converted bf16 [Mp][Kp]; X fp32 staged to LDS.
// D1/U1/D2/U2.
// ---------------------------------------------------------------------------
template<int OBF16>
__global__ __launch_bounds__(256) void dsamp_mfma2_kernel(
    const unsigned short* __restrict__ Ap, const float* __restrict__ X,
    void* __restrict__ Yv, int M, int K, int Kp, int logF, int kchunk,
    int atomic_flag, size_t pstride)
{
    constexpr int PAD = 40;
    __shared__ unsigned short Xs[2][64 * PAD];

    const int fmask = (1 << logF) - 1;
    const int m0   = blockIdx.x * 64;
    const int c0   = blockIdx.y * 64;
    const int kbeg = blockIdx.z * kchunk;
    int kend = kbeg + kchunk; if (kend > K) kend = K;
    const int nslab = (kend - kbeg + 31) >> 5;
    const size_t zoff = (size_t)blockIdx.z * pstride;

    const int tid  = threadIdx.x;
    const int lane = tid & 63;
    const int wave = tid >> 6;
    const int wm   = (wave >> 1) * 32;
    const int wn   = (wave & 1) * 32;
    const int l15  = lane & 15;
    const int quad = lane >> 4;

    const int skk  = tid >> 4;
    const int scg  = (tid & 15) * 4;
    const int cB   = c0 + scg;
    const int xbb  = cB >> logF;
    const int xf   = cB & fmask;
    const size_t xrowbase = (((size_t)xbb * K) << logF) + xf;

    const int mA0 = m0 + wm + l15;
    const int mA1 = mA0 + 16;
    const int kaoff = quad * 8;

    f32x4 acc[2][2];
    acc[0][0] = acc[0][1] = acc[1][0] = acc[1][1] = (f32x4){0.f, 0.f, 0.f, 0.f};

    float4 xn0, xn1;
    bf16x8 ac0, ac1, an0, an1;

    {
        int k = kbeg + skk;
        xn0 = make_float4(0.f, 0.f, 0.f, 0.f);
        if (k < kend) xn0 = *(const float4*)(X + xrowbase + ((size_t)k << logF));
        k = kbeg + 16 + skk;
        xn1 = make_float4(0.f, 0.f, 0.f, 0.f);
        if (k < kend) xn1 = *(const float4*)(X + xrowbase + ((size_t)k << logF));
        int ka = kbeg + kaoff;
        ac0 = *(const bf16x8*)(Ap + (size_t)mA0 * Kp + ka);
        ac1 = *(const bf16x8*)(Ap + (size_t)mA1 * Kp + ka);
        unsigned short* p = &Xs[0][0];
        p[(scg + 0) * PAD + skk] = f2bf(xn0.x);
        p[(scg + 1) * PAD + skk] = f2bf(xn0.y);
        p[(scg + 2) * PAD + skk] = f2bf(xn0.z);
        p[(scg + 3) * PAD + skk] = f2bf(xn0.w);
        int kk1 = 16 + skk;
        p[(scg + 0) * PAD + kk1] = f2bf(xn1.x);
        p[(scg + 1) * PAD + kk1] = f2bf(xn1.y);
        p[(scg + 2) * PAD + kk1] = f2bf(xn1.z);
        p[(scg + 3) * PAD + kk1] = f2bf(xn1.w);
    }
    __syncthreads();

    for (int s = 0; s < nslab; ++s) {
        const int cur = s & 1;
        const bool more = (s + 1 < nslab);
        if (more) {
            int k0 = kbeg + (s + 1) * 32;
            int k = k0 + skk;
            xn0 = make_float4(0.f, 0.f, 0.f, 0.f);
            if (k < kend) xn0 = *(const float4*)(X + xrowbase + ((size_t)k << logF));
            k = k0 + 16 + skk;
            xn1 = make_float4(0.f, 0.f, 0.f, 0.f);
            if (k < kend) xn1 = *(const float4*)(X + xrowbase + ((size_t)k << logF));
            int ka = k0 + kaoff;
            an0 = *(const bf16x8*)(Ap + (size_t)mA0 * Kp + ka);
            an1 = *(const bf16x8*)(Ap + (size_t)mA1 * Kp + ka);
        }
        {
            const unsigned short* p = &Xs[cur][0];
            bf16x8 b0 = *(const bf16x8*)&p[(wn +      l15) * PAD + quad * 8];
            bf16x8 b1 = *(const bf16x8*)&p[(wn + 16 + l15) * PAD + quad * 8];
            acc[0][0] = __builtin_amdgcn_mfma_f32_16x16x32_bf16(ac0, b0, acc[0][0], 0, 0, 0);
            acc[0][1] = __builtin_amdgcn_mfma_f32_16x16x32_bf16(ac0, b1, acc[0][1], 0, 0, 0);
            acc[1][0] = __builtin_amdgcn_mfma_f32_16x16x32_bf16(ac1, b0, acc[1][0], 0, 0, 0);
            acc[1][1] = __builtin_amdgcn_mfma_f32_16x16x32_bf16(ac1, b1, acc[1][1], 0, 0, 0);
        }
        if (more) {
            unsigned short* q = &Xs[cur ^ 1][0];
            q[(scg + 0) * PAD + skk] = f2bf(xn0.x);
            q[(scg + 1) * PAD + skk] = f2bf(xn0.y);
            q[(scg + 2) * PAD + skk] = f2bf(xn0.z);
            q[(scg + 3) * PAD + skk] = f2bf(xn0.w);
            int kk1 = 16 + skk;
            q[(scg + 0) * PAD + kk1] = f2bf(xn1.x);
            q[(scg + 1) * PAD + kk1] = f2bf(xn1.y);
            q[(scg + 2) * PAD + kk1] = f2bf(xn1.z);
            q[(scg + 3) * PAD + kk1] = f2bf(xn1.w);
            __syncthreads();
            ac0 = an0; ac1 = an1;
        }
    }

#pragma unroll
    for (int tm = 0; tm < 2; ++tm)
#pragma unroll
        for (int tn = 0; tn < 2; ++tn)
#pragma unroll
            for (int reg = 0; reg < 4; ++reg) {
                int m  = m0 + wm + tm * 16 + quad * 4 + reg;
                int cc = c0 + wn + tn * 16 + l15;
                if (m < M) {
                    int bb = cc >> logF, f = cc & fmask;
                    size_t off = zoff + (((size_t)bb * M + m) << logF) + f;
                    float v = acc[tm][tn][reg];
                    if (OBF16)            ((unsigned short*)Yv)[off] = f2bf(v);
                    else if (atomic_flag) atomicAdd((float*)Yv + off, v);
                    else                  ((float*)Yv)[off] = v;
                }
            }
}

// ---------------------------------------------------------------------------
// conv_gemm (fp32 gather). e0 only. Grid: (batch, mtile).
// ---------------------------------------------------------------------------
template<int MT, int OT>
__global__ __launch_bounds__(256) void conv_gemm_kernel(
    const float* __restrict__ x, const int* __restrict__ S,
    const float* __restrict__ W, const float* __restrict__ bias,
    float* __restrict__ y, int Nv, int logF, int O, int KF, int KFr,
    int elu_flag)
{
    constexpr int CT = OT / 4;
    constexpr int RT = 256 / CT;
    static_assert(RT * 4 == MT, "tile shape");
    __shared__ float Gs[32][MT];
    __shared__ float Ws[32][OT];

    const int b   = blockIdx.x;
    const int n0  = blockIdx.y * MT;
    const int tid = threadIdx.x;
    const int cx  = tid % CT;
    const int ry  = tid / CT;
    const int r0  = ry * 4;
    const int o0  = cx * 4;
    const int fmask = (1 << logF) - 1;
    const size_t xb = (size_t)b * Nv;

    float acc[4][4];
#pragma unroll
    for (int i = 0; i < 4; ++i)
#pragma unroll
        for (int j = 0; j < 4; ++j) acc[i][j] = 0.f;

    for (int k0 = 0; k0 < KF; k0 += 32) {
        constexpr int GSLOTS = MT * 8;
#pragma unroll
        for (int i = 0; i < GSLOTS / 256; ++i) {
            int idx = tid + i * 256;
            int r   = idx & (MT - 1);
            int jg  = idx / MT;
            int j0  = jg * 4;
            int n   = n0 + r;
            int kf  = k0 + j0;
            float4 v = make_float4(0.f, 0.f, 0.f, 0.f);
            if (n < Nv && kf < KFr) {
                int k   = kf >> logF;
                int f   = kf & fmask;
                int src = S[n * SPK + k];
                v = *(const float4*)(x + ((xb + src) << logF) + f);
            }
            Gs[j0 + 0][r] = v.x; Gs[j0 + 1][r] = v.y;
            Gs[j0 + 2][r] = v.z; Gs[j0 + 3][r] = v.w;
        }
        constexpr int WSLOTS = OT * 8;
#pragma unroll
        for (int i = 0; i < (WSLOTS + 255) / 256; ++i) {
            int idx = tid + i * 256;
            if (WSLOTS >= 256 || idx < WSLOTS) {
                int o  = idx & (OT - 1);
                int jg = idx / OT;
                int j0 = jg * 4;
                float4 v = *(const float4*)(W + (size_t)o * KF + k0 + j0);
                Ws[j0 + 0][o] = v.x; Ws[j0 + 1][o] = v.y;
                Ws[j0 + 2][o] = v.z; Ws[j0 + 3][o] = v.w;
            }
        }
        __syncthreads();
#pragma unroll
        for (int kk = 0; kk < 32; ++kk) {
            float4 g = *(const float4*)&Gs[kk][r0];
            float4 w = *(const float4*)&Ws[kk][o0];
            acc[0][0] += g.x * w.x; acc[0][1] += g.x * w.y; acc[0][2] += g.x * w.z; acc[0][3] += g.x * w.w;
            acc[1][0] += g.y * w.x; acc[1][1] += g.y * w.y; acc[1][2] += g.y * w.z; acc[1][3] += g.y * w.w;
            acc[2][0] += g.z * w.x; acc[2][1] += g.z * w.y; acc[2][2] += g.z * w.z; acc[2][3] += g.z * w.w;
            acc[3][0] += g.w * w.x; acc[3][1] += g.w * w.y; acc[3][2] += g.w * w.z; acc[3][3] += g.w * w.w;
        }
        __syncthreads();
    }

    float4 bv = *(const float4*)(bias + o0);
#pragma unroll
    for (int i = 0; i < 4; ++i) {
        int n = n0 + r0 + i;
        if (n >= Nv) continue;
        float v0 = acc[i][0] + bv.x;
        float v1 = acc[i][1] + bv.y;
        float v2 = acc[i][2] + bv.z;
        float v3 = acc[i][3] + bv.w;
        if (elu_flag) {
            v0 = v0 > 0.f ? v0 : expm1f(v0);
            v1 = v1 > 0.f ? v1 : expm1f(v1);
            v2 = v2 > 0.f ? v2 : expm1f(v2);
            v3 = v3 > 0.f ? v3 : expm1f(v3);
        }
        if (n == Nv - 1) { v0 = v1 = v2 = v3 = 0.f; }
        *(float4*)(y + ((size_t)b * Nv + n) * O + o0) = make_float4(v0, v1, v2, v3);
    }
}

// ---------------------------------------------------------------------------
// VALU down/up-sample (d3/u3 only now). OBF16: emit bf16 output.
// ---------------------------------------------------------------------------
template<int OBF16>
__global__ __launch_bounds__(256) void dsamp_kernel(
    const float* __restrict__ A, const float* __restrict__ X,
    void* __restrict__ Yv, int M, int N, int F)
{
    __shared__ float As[16][68];
    __shared__ float Xs[16][64];

    const int m0  = blockIdx.x * 64;
    const int c0  = blockIdx.y * 64;
    const int tid = threadIdx.x;
    const int tx  = tid & 15;
    const int ty  = tid >> 4;

    float acc[4][4];
#pragma unroll
    for (int i = 0; i < 4; ++i)
#pragma unroll
        for (int j = 0; j < 4; ++j) acc[i][j] = 0.f;

    for (int k0 = 0; k0 < N; k0 += 16) {
#pragma unroll
        for (int p = 0; p < 4; ++p) {
            int r  = (tid >> 4) + p * 16;
            int kk = tid & 15;
            int m  = m0 + r;
            int n  = k0 + kk;
            float v = 0.f;
            if (m < M && n < N) v = A[(size_t)m * N + n];
            As[kk][r] = v;
        }
        {
            int kk = tid >> 4;
            int cc = (tid & 15) * 4;
            int n  = k0 + kk;
            float4 v = make_float4(0.f, 0.f, 0.f, 0.f);
            if (n < N) {
                int c  = c0 + cc;
                int bb = c / F;
                int f  = c - bb * F;
                v = *(const float4*)(X + ((size_t)bb * N + n) * F + f);
            }
            *(float4*)&Xs[kk][cc] = v;
        }
        __syncthreads();
#pragma unroll
        for (int kk = 0; kk < 16; ++kk) {
            float4 av = *(const float4*)&As[kk][ty * 4];
            float4 xv = *(const float4*)&Xs[kk][tx * 4];
            acc[0][0] += av.x * xv.x; acc[0][1] += av.x * xv.y; acc[0][2] += av.x * xv.z; acc[0][3] += av.x * xv.w;
            acc[1][0] += av.y * xv.x; acc[1][1] += av.y * xv.y; acc[1][2] += av.y * xv.z; acc[1][3] += av.y * xv.w;
            acc[2][0] += av.z * xv.x; acc[2][1] += av.z * xv.y; acc[2][2] += av.z * xv.z; acc[2][3] += av.z * xv.w;
            acc[3][0] += av.w * xv.x; acc[3][1] += av.w * xv.y; acc[3][2] += av.w * xv.z; acc[3][3] += av.w * xv.w;
        }
        __syncthreads();
    }

    const int cbase = c0 + tx * 4;
    const int bb = cbase / F;
    const int f  = cbase - bb * F;
#pragma unroll
    for (int i = 0; i < 4; ++i) {
        int m = m0 + ty * 4 + i;
        if (m < M) {
            size_t off = ((size_t)bb * M + m) * F + f;
            if (OBF16) {
                bf16x4 v;
                v[0] = (short)f2bf(acc[i][0]); v[1] = (short)f2bf(acc[i][1]);
                v[2] = (short)f2bf(acc[i][2]); v[3] = (short)f2bf(acc[i][3]);
                *(bf16x4*)((unsigned short*)Yv + off) = v;
            } else {
                *(float4*)((float*)Yv + off) =
                    make_float4(acc[i][0], acc[i][1], acc[i][2], acc[i][3]);
            }
        }
    }
}

// ---------------------------------------------------------------------------
// fc_wave: one 64-lane wave per output element.
// ---------------------------------------------------------------------------
__global__ __launch_bounds__(256) void fc_wave_kernel(
    const float* __restrict__ in, const float* __restrict__ W,
    const float* __restrict__ bias, float* __restrict__ out,
    int In, int O, int dup)
{
    const int gw   = blockIdx.x * 4 + (threadIdx.x >> 6);
    const int lane = threadIdx.x & 63;
    const int b = gw / O;
    const int o = gw - b * O;
    const float* xr = in + (size_t)b * In;
    float acc = 0.f;
    if (dup) {
        const float* wr = W + (size_t)o * (2 * In);
        for (int k = lane; k < In; k += 64)
            acc += xr[k] * (wr[k] + wr[In + k]);
    } else {
        const float* wr = W + (size_t)o * In;
        for (int k = lane; k < In; k += 64)
            acc += xr[k] * wr[k];
    }
#pragma unroll
    for (int off = 32; off > 0; off >>= 1)
        acc += __shfl_down(acc, off, 64);
    if (lane == 0) out[(size_t)b * O + o] = acc + bias[o];
}

// ---------------------------------------------------------------------------
// Transpose-convert: x [b][k][f] fp32 -> xt [c][k] bf16, c = b*F+f, stride Kp.
// ---------------------------------------------------------------------------
__global__ __launch_bounds__(256) void xpose_bf16_kernel(
    const float* __restrict__ x, unsigned short* __restrict__ xt,
    int K, int Kp, int logF)
{
    const int c  = blockIdx.y * 256 + threadIdx.x;
    const int k0 = blockIdx.x * 8;
    const int bb = c >> logF;
    const int f  = c & ((1 << logF) - 1);
    const float* src = x + (((size_t)bb * K) << logF) + f;
    bf16x8 r;
#pragma unroll
    for (int j = 0; j < 8; ++j) {
        int k = k0 + j;
        float v = (k < K) ? src[(size_t)k << logF] : 0.f;
        r[j] = (short)f2bf(v);
    }
    *(bf16x8*)(xt + (size_t)c * Kp + k0) = r;
}

// ---------------------------------------------------------------------------
// Padding / extraction helpers.
// ---------------------------------------------------------------------------
__global__ __launch_bounds__(256) void pad_e0_w_kernel(
    const float* __restrict__ w, float* __restrict__ wp)
{
    int i = blockIdx.x * 256 + threadIdx.x;
    if (i < 1024) {
        int o = i >> 6, kf = i & 63;
        int k = kf >> 2, f = kf & 3;
        wp[i] = (f < 3 && k < 12) ? w[o * 36 + k * 3 + f] : 0.f;
    }
}
__global__ __launch_bounds__(256) void pad_x4_kernel(
    const float* __restrict__ x, float* __restrict__ xp, int n)
{
    int i = blockIdx.x * 256 + threadIdx.x;
    if (i < n) {
        int f = i & 3, nb = i >> 2;
        xp[i] = (f < 3) ? x[nb * 3 + f] : 0.f;
    }
}
__global__ __launch_bounds__(256) void pad_c4_w_kernel(
    const float* __restrict__ w, const float* __restrict__ b,
    float* __restrict__ wp, float* __restrict__ bp)
{
    int i = blockIdx.x * 256 + threadIdx.x;
    if (i < 3072) {
        int o = i / 192;
        wp[i] = (o < 3) ? w[i] : 0.f;
    }
    if (i < 16) bp[i] = (i < 3) ? b[i] : 0.f;
}
__global__ __launch_bounds__(256) void extract_add_kernel(
    const float* __restrict__ cp, const float* __restrict__ t,
    float* __restrict__ o0, float* __restrict__ o1, int n)
{
    int i = blockIdx.x * 256 + threadIdx.x;
    if (i < n) {
        int f = i % 3, nb = i / 3;
        float v = cp[(size_t)nb * 16 + f];
        o0[i] = v;
        o1[i] = v + t[i];
    }
}

// ---------------------------------------------------------------------------

static inline int ilog2(int v) { int l = 0; while ((1 << l) < v) ++l; return l; }

static inline void a_bf16_launch(const float* A, unsigned short* Ap, int M, int K,
                                 int Mp, int Kp, hipStream_t s)
{
    int total = Mp * (Kp >> 3);
    a_bf16_pad_kernel<<<(total + 255) / 256, 256, 0, s>>>(A, Ap, M, K, Kp, total);
}

template<int OBF16>
static inline void dsamp_mfma2_launch(const unsigned short* Ap, const float* X,
                                      void* Y, int M, int K, int Kp, int F,
                                      int ks, int partial, hipStream_t s)
{
    int kchunk = (K + ks - 1) / ks;
    kchunk = (kchunk + 31) & ~31;
    int ksz = (K + kchunk - 1) / kchunk;
    int atomic = (ksz > 1 && !partial) ? 1 : 0;
    size_t pstride = (partial && ksz > 1) ? (size_t)BATCH * M * F : 0;
    dim3 grid((M + 63) / 64, F, ksz);
    dsamp_mfma2_kernel<OBF16><<<grid, 256, 0, s>>>(Ap, X, Y, M, K, Kp, ilog2(F),
                                                   kchunk, atomic, pstride);
}

template<int OBF16>
static inline void dsamp_mfma3_launch(const unsigned short* Ab, const unsigned short* Xt,
                                      void* Y, int M, int Kp, int F,
                                      int ks, int partial, hipStream_t s)
{
    int slabs = Kp >> 5;
    int kchunk = ((slabs + ks - 1) / ks) * 32;
    int ksz = (Kp + kchunk - 1) / kchunk;
    int gx = (M + 127) / 128, gy = (BATCH * F) / 128;
    int total = gx * gy * ksz;
    int swz = ((total & 7) == 0) ? 1 : 0;
    int atomic = (ksz > 1 && !partial) ? 1 : 0;
    size_t pstride = (partial && ksz > 1) ? (size_t)BATCH * M * F : 0;
    dim3 grid(gx, gy, ksz);
    dsamp_mfma3_kernel<OBF16><<<grid, 256, 0, s>>>(Ab, Xt, Y, M, Kp, ilog2(F),
                                                   kchunk, atomic, swz, pstride);
}

template<int OBF16>
static inline void dsamp_launch(const float* A, const float* X, void* Y,
                                int M, int N, int F, hipStream_t s)
{
    dim3 grid((M + 63) / 64, F);
    dsamp_kernel<OBF16><<<grid, 256, 0, s>>>(A, X, Y, M, N, F);
}

extern "C" void kernel_launch(void* const* d_in, const int* in_sizes, int n_in,
                              void* d_out, int out_size, void* d_ws, size_t ws_size,
                              hipStream_t stream)
{
    const float* x_talking = (const float*)d_in[0];
    const float* templ     = (const float*)d_in[1];
    const float* D0 = (const float*)d_in[2];
    const float* U0 = (const float*)d_in[3];
    const float* D1 = (const float*)d_in[4];
    const float* U1 = (const float*)d_in[5];
    const float* D2 = (const float*)d_in[6];
    const float* U2 = (const float*)d_in[7];
    const float* D3 = (const float*)d_in[8];
    const float* U3 = (const float*)d_in[9];
    const float* enc_w0 = (const float*)d_in[10]; const float* enc_b0 = (const float*)d_in[11];
    const float* enc_w1 = (const float*)d_in[12]; const float* enc_b1 = (const float*)d_in[13];
    const float* enc_w2 = (const float*)d_in[14]; const float* enc_b2 = (const float*)d_in[15];
    const float* enc_w3 = (const float*)d_in[16]; const float* enc_b3 = (const float*)d_in[17];
    const float* fc_enc_w = (const float*)d_in[18]; const float* fc_enc_b = (const float*)d_in[19];
    const float* fc_dec_w = (const float*)d_in[20]; const float* fc_dec_b = (const float*)d_in[21];
    const float* dec_w0 = (const float*)d_in[22]; const float* dec_b0 = (const float*)d_in[23];
    const float* dec_w1 = (const float*)d_in[24]; const float* dec_b1 = (const float*)d_in[25];
    const float* dec_w2 = (const float*)d_in[26]; const float* dec_b2 = (const float*)d_in[27];
    const float* dec_w3 = (const float*)d_in[28]; const float* dec_b3 = (const float*)d_in[29];
    const float* dec_w4 = (const float*)d_in[30]; const float* dec_b4 = (const float*)d_in[31];
    const int* S0 = (const int*)d_in[32];
    const int* S1 = (const int*)d_in[33];
    const int* S2 = (const int*)d_in[34];
    const int* S3 = (const int*)d_in[35];

    float* bufA = (float*)d_ws;            // 10,289,152 floats (41.2 MB)
    float* bufB = bufA + 10289152;         // 5,144,576 floats (20.6 MB)

    float* out0 = (float*)d_out;           // 964,608 floats
    float* out1 = out0 + 964608;

    // ---- workspace aliases (lifetimes audited per stream order) ----
    // Encoder:
    //   e0-out bufA[0..5.14M) -> dead after xpose
    //   Pd0 (5x1,287,168) bufA[0..6,435,840) -> dead after reduce (D0b @6.7M safe)
    //   Xb_e1: bufB[0..160,896 fl) -> dead after e1 (clobbered by Pd2 later)
    //   e1-out bufA[0..2,574,336) fp32
    //   Pd1 (4x645,120) bufA[5,200,000..7,780,480) (D0b dead) -> reduce -> Xb_e2
    //   Xb_e2 bufA+2,000,000 -> e2 -> e2-out bufA[0..1,290,240)
    //   Pd2 (4x327,680) bufB[0..1,310,720) (Xt_e0/Xb_e1 dead) -> reduce -> Xb_e3
    //   Xb_e3 bufA+2,000,000 -> e3 -> e3-out bufA[0..655,360)
    //   d3 -> bufB[0..172,032) fp32
    // Decoder: as before; u2 now bf16-direct to bufA.
    unsigned short* Xt_e0 = (unsigned short*)(bufB + 1290240);
    unsigned short* Xt_c2 = (unsigned short*)bufB;
    unsigned short* U0b   = (unsigned short*)(bufB + 1400000);
    unsigned short* Wb_e2 = (unsigned short*)(bufB + 4700000);
    unsigned short* Wb_e3 = (unsigned short*)(bufB + 4715000);
    unsigned short* Wb_c0 = (unsigned short*)(bufB + 4765000);
    unsigned short* Wb_c1 = (unsigned short*)(bufB + 4815000);
    unsigned short* D2b   = (unsigned short*)(bufB + 4830000);  // [128][320]
    unsigned short* U2b   = (unsigned short*)(bufB + 4860000);  // [320][96]
    float* xpad   = bufA + 5200000;
    float* WpE0   = bufA + 6600000;
    unsigned short* D0b   = (unsigned short*)(bufA + 6700000);
    unsigned short* D1b   = (unsigned short*)(bufA + 9950000);
    unsigned short* U1b   = (unsigned short*)(bufA + 4000000);
    unsigned short* Wb_e1 = (unsigned short*)(bufA + 10160000);
    unsigned short* Wb_c2 = (unsigned short*)(bufA + 10170000);
    float*          Pd0   = bufA;                                // 5 partials
    unsigned short* Xb_e1 = (unsigned short*)bufB;               // d0-out bf16
    float*          Pd1   = bufA + 5200000;                      // 4 partials
    unsigned short* Xb_e2   = (unsigned short*)(bufA + 2000000);
    float*          Pd2   = bufB;                                // 4 partials
    unsigned short* Xb_e3   = (unsigned short*)(bufA + 2000000);
    unsigned short* Xb_c2in = (unsigned short*)(bufA + 2600000);
    unsigned short* Xb_c3n  = (unsigned short*)bufA;             // u0 bf16 out
    unsigned short* Xb_c4   = (unsigned short*)(bufA + 5200000);
    unsigned short* Wb_c3  = (unsigned short*)(bufA + 7800000);
    unsigned short* Wfs_c3 = (unsigned short*)(bufA + 7805000);
    float* WpC4   = bufA + 7810000;
    float* BpC4   = bufA + 7813500;
    unsigned short* Wb_c4  = (unsigned short*)(bufA + 7814000);
    unsigned short* Wfs_c4 = (unsigned short*)(bufA + 7818000);

    // ---- input-only pre-conversions ----
    pad_e0_w_kernel<<<4, 256, 0, stream>>>(enc_w0, WpE0);
    pad_x4_kernel<<<5024, 256, 0, stream>>>(x_talking, xpad, 1286144);
    a_bf16_launch(D0, D0b, 1257, 5024, 1280, 5024, stream);
    a_bf16_launch(D1, D1b, 315, 1257, 320, 1280, stream);
    a_bf16_launch(D2, D2b, 80, 315, 128, 320, stream);
    a_bf16_launch(U2, U2b, 315, 80, 320, 96, stream);
    f32_to_bf16_kernel<<<3, 256, 0, stream>>>(enc_w1, Wb_e1, 768);
    f32_to_bf16_kernel<<<6, 256, 0, stream>>>(dec_w2, Wb_c2, 1536);
    f32_to_bf16_kernel<<<12, 256, 0, stream>>>(enc_w2, Wb_e2, 3072);
    f32_to_bf16_kernel<<<48, 256, 0, stream>>>(enc_w3, Wb_e3, 12288);
    f32_to_bf16_kernel<<<48, 256, 0, stream>>>(dec_w0, Wb_c0, 12288);
    f32_to_bf16_kernel<<<12, 256, 0, stream>>>(dec_w1, Wb_c1, 3072);

    // ---- encoder ----
    {   // e0: F=4(pad), KF=64 (KFr=48), O=16, fp32 (first-layer precision)
        dim3 grid(BATCH, (5024 + 255) / 256);
        conv_gemm_kernel<256, 16><<<grid, 256, 0, stream>>>(
            xpad, S0, WpE0, enc_b0, bufA, 5024, 2, 16, 64, 48, 1);
    }
    xpose_bf16_kernel<<<dim3(628, 4), 256, 0, stream>>>(bufA, Xt_e0, 5024, 5024, 4);
    // d0: ks=5 partials (per-XCD slice 3.9MB, L2-fit) -> Pd0; reduce -> Xb_e1
    dsamp_mfma3_launch<0>(D0b, Xt_e0, Pd0, 1257, 5024, 16, 5, 1, stream);
    reducep_bf16_kernel<<<629, 256, 0, stream>>>(Pd0, 1287168, Xb_e1, 160896, 5);
    a_bf16_launch(U0, U0b, 5024, 1257, 5120, 1280, stream);
    a_bf16_launch(U1, U1b, 1257, 315, 1280, 320, stream);
    {   // e1: MFMA conv, F=16, O=32, ELU -> bufA [64,1257,32] fp32
        dim3 grid(BATCH, (1257 + 255) / 256);
        conv_mfma32_kernel<4><<<grid, 256, 0, stream>>>(
            Xb_e1, S1, Wb_e1, enc_b1, bufA, 1257, 192, 1);
    }
    // d1: ks=4 partials -> Pd1; reduce -> Xb_e2
    dsamp_mfma2_launch<0>(D1b, bufA, Pd1, 315, 1257, 1280, 32, 4, 1, stream);
    reducep_bf16_kernel<<<315, 256, 0, stream>>>(Pd1, 645120, Xb_e2, 80640, 4);
    {   // e2: wave-MFMA conv, F=32, O=64 -> bufA fp32 [64,315,64]
        dim3 grid((315 + 15) / 16, 64 / 16, BATCH);
        conv_wmfma_kernel<5, 0><<<grid, 64, 0, stream>>>(
            Xb_e2, S2, Wb_e2, enc_b2, bufA, 315, 64, 1, 0);
    }
    // d2: MFMA path, ks=4 partials (512 blocks) -> Pd2; reduce -> Xb_e3
    dsamp_mfma2_launch<0>(D2b, bufA, Pd2, 80, 315, 320, 64, 4, 1, stream);
    reducep_bf16_kernel<<<160, 256, 0, stream>>>(Pd2, 327680, Xb_e3, 40960, 4);
    {   // e3: wave-MFMA conv, F=64, O=128 -> bufA fp32 [64,80,128]
        dim3 grid((80 + 15) / 16, 128 / 16, BATCH);
        conv_wmfma_kernel<6, 0><<<grid, 64, 0, stream>>>(
            Xb_e3, S3, Wb_e3, enc_b3, bufA, 80, 128, 1, 0);
    }
    dsamp_launch<0>(D3, bufA, bufB, 21, 80, 128, stream);                       // d3 fp32

    fc_wave_kernel<<<dim3((BATCH * 128) / 4), 256, 0, stream>>>(bufB, fc_enc_w, fc_enc_b, bufA, 2688, 128, 0);
    fc_wave_kernel<<<dim3((BATCH * 2688) / 4), 256, 0, stream>>>(bufA, fc_dec_w, fc_dec_b, bufB, 128, 2688, 1);

    // ---- decoder ----
    dsamp_launch<1>(U3, bufB, bufA, 80, 21, 128, stream);                       // u3 -> bf16
    {   // c0: wave-MFMA conv, F=128, O=64 -> bufB fp32 [64,80,64]
        dim3 grid((80 + 15) / 16, 64 / 16, BATCH);
        conv_wmfma_kernel<7, 0><<<grid, 64, 0, stream>>>(
            (const unsigned short*)bufA, S3, Wb_c0, dec_b0, bufB, 80, 64, 1, 0);
    }
    // u2: MFMA path, ks=1, bf16 direct -> bufA [64,315,64] bf16
    dsamp_mfma2_launch<1>(U2b, bufB, bufA, 315, 80, 96, 64, 1, 0, stream);
    {   // c1: wave-MFMA conv, F=64, O=32 -> bufB fp32 [64,315,32]
        dim3 grid((315 + 15) / 16, 32 / 16, BATCH);
        conv_wmfma_kernel<6, 0><<<grid, 64, 0, stream>>>(
            (const unsigned short*)bufA, S2, Wb_c1, dec_b1, bufB, 315, 32, 1, 0);
    }
    // u1: ks=1, bf16 direct out -> Xb_c2in
    dsamp_mfma2_launch<1>(U1b, bufB, Xb_c2in, 1257, 315, 320, 32, 1, 0, stream);
    {   // c2: MFMA conv, F=32, O=32, ELU -> bufA [64,1257,32] fp32
        dim3 grid(BATCH, (1257 + 255) / 256);
        conv_mfma32_kernel<5><<<grid, 256, 0, stream>>>(
            Xb_c2in, S1, Wb_c2, dec_b2, bufA, 1257, 384, 1);
    }
    xpose_bf16_kernel<<<dim3(160, 8), 256, 0, stream>>>(bufA, Xt_c2, 1257, 1280, 5);
    // u0: ks=1, bf16 direct out -> Xb_c3n, XCD-swz
    dsamp_mfma3_launch<1>(U0b, Xt_c2, Xb_c3n, 5024, 1280, 32, 1, 0, stream);

    // c3/c4 weight conversions + frag pre-swizzle (region dead)
    f32_to_bf16_kernel<<<3, 256, 0, stream>>>(dec_w3, Wb_c3, 768);
    w_frag16_kernel<<<24, 256, 0, stream>>>(Wb_c3, Wfs_c3, 384, 6144);
    pad_c4_w_kernel<<<12, 256, 0, stream>>>(dec_w4, dec_b4, WpC4, BpC4);
    f32_to_bf16_kernel<<<2, 256, 0, stream>>>(WpC4, Wb_c4, 384);
    w_frag16_kernel<<<12, 256, 0, stream>>>(Wb_c4, Wfs_c4, 192, 3072);
    {   // c3: coalesced-gather MFMA conv, F=32, O=16, ELU; bf16 out [XCD-swz]
        dim3 grid(5024 / 16, 1, BATCH);
        conv_cmfma_kernel<5, 1><<<grid, 64, 0, stream>>>(
            Xb_c3n, S0, Wfs_c3, dec_b3, (void*)Xb_c4, 5024, 1, 1);
    }
    {   // c4: coalesced-gather MFMA conv, F=16, O=16(pad), identity [XCD-swz]
        dim3 grid(5024 / 16, 1, BATCH);
        conv_cmfma_kernel<4, 0><<<grid, 64, 0, stream>>>(
            Xb_c4, S0, Wfs_c4, BpC4, (void*)bufB, 5024, 0, 1);
    }
    extract_add_kernel<<<(964608 + 255) / 256, 256, 0, stream>>>(bufB, templ, out0, out1, 964608);
}